// Round 8
// baseline (20026.129 us; speedup 1.0000x reference)
//
#include <hip/hip_runtime.h>
#include <math.h>

// ---------------------------------------------------------------------------
// NetGIN forward on MI355X — round 8: fully DETERMINISTIC pipeline.
// R7 failed the post-timing recheck: fp32 atomicAdd ordering (BN stats) and
// atomic CSR fill order made outputs vary per run. This round removes every
// fp32 atomic and every order-dependence:
//   * BN stats: per-block partials -> pstats[block][256]; bnfin_det reduces
//     all blocks in a FIXED order (no atomics anywhere).
//   * CSR neighbor lists sorted by value after fill -> aggregate sum order
//     is input-determined.
// Everything else as R7: fp16 activation store, bf16 2-term-split MFMA GEMM
// (reg-streaming, no K-loop barriers), 4 blocks/CU, unrolled gather.
// ---------------------------------------------------------------------------

#define DEV_INLINE __device__ __forceinline__
typedef unsigned short u16;

union F16U { _Float16 h; u16 u; };
DEV_INLINE float h2f(u16 v){ F16U t; t.u = v; return (float)t.h; }
DEV_INLINE u16 f2h(float f){ F16U t; t.h = (_Float16)f; return t.u; }
DEV_INLINE float bf2f(u16 h){ return __uint_as_float(((unsigned)h)<<16); }
DEV_INLINE u16 f2bf(float f){
  unsigned u = __float_as_uint(f);
  unsigned r = (u + 0x7FFFu + ((u>>16)&1u)) >> 16;
  return (u16)r;
}
DEV_INLINE float sigmoidf_(float x){ return 1.0f/(1.0f+expf(-x)); }
struct __align__(4) us2 { u16 x, y; };
struct __align__(8) us4 { u16 x, y, z, w; };

typedef __attribute__((ext_vector_type(8))) short s8v;   // 8 bf16/fp16 (4 VGPRs)
typedef __attribute__((ext_vector_type(4))) float f4v;   // 4 fp32 acc

// ---------------- utility ----------------
__global__ void zero_k(float* __restrict__ p, int n){
  int i = blockIdx.x*256 + threadIdx.x;
  if (i < n) p[i] = 0.f;
}

// ---------------- weight pre-transpose + bf16 split ----------------
__global__ __launch_bounds__(256) void split_transpose(
  const float* __restrict__ src, u16* __restrict__ dh, u16* __restrict__ dl,
  int K, int count)
{
  int tot = count*K*128;
  for (int i = blockIdx.x*256 + threadIdx.x; i < tot; i += gridDim.x*256){
    int k = i % K;
    int n = (i / K) & 127;
    int c = i / (K*128);
    float w = src[(size_t)c*K*128 + (size_t)k*128 + n];
    u16 hi = f2bf(w);
    u16 lo = f2bf(w - bf2f(hi));
    dh[i] = hi; dl[i] = lo;
  }
}

// ---------------- CSR build ----------------
__global__ void count_deg(const int* __restrict__ dst, int* __restrict__ cnt, int E){
  int e = blockIdx.x*256 + threadIdx.x;
  if (e < E) atomicAdd(&cnt[dst[e]], 1);      // int atomics: exact, order-free
}

__global__ void scan_excl(const int* __restrict__ cnt, int* __restrict__ offs, int N){
  const int* c = cnt + (size_t)blockIdx.x * N;
  int* o = offs + (size_t)blockIdx.x * (N+1);
  __shared__ int ps[1024];
  int t = threadIdx.x;
  int chunk = (N + 1023) >> 10;
  int lo = t*chunk, hi = min(lo+chunk, N);
  int s = 0;
  for (int i=lo;i<hi;++i) s += c[i];
  ps[t] = s; __syncthreads();
  for (int d=1; d<1024; d<<=1){
    int v = (t>=d) ? ps[t-d] : 0;
    __syncthreads();
    ps[t] += v;
    __syncthreads();
  }
  int pre = (t==0) ? 0 : ps[t-1];
  for (int i=lo;i<hi;++i){ o[i]=pre; pre += c[i]; }
  if (t==1023) o[N] = ps[1023];
}

__global__ void fill_csr(const int* __restrict__ src, const int* __restrict__ dst,
                         const int* __restrict__ offs, int* __restrict__ cur,
                         int* __restrict__ out, int E){
  int e = blockIdx.x*256 + threadIdx.x;
  if (e >= E) return;
  int d = dst[e];
  int pos = offs[d] + atomicAdd(&cur[d], 1);  // placement order varies ...
  out[pos] = src[e];
}

// ... so sort each node's segment by value -> deterministic sum order.
__global__ void sort_csr(const int* __restrict__ offs, int* __restrict__ srcs, int N){
  int i = blockIdx.x*256 + threadIdx.x;
  if (i >= N) return;
  int lo = offs[i], hi = offs[i+1];
  for (int a = lo+1; a < hi; ++a){
    int v = srcs[a];
    int b = a-1;
    while (b >= lo && srcs[b] > v){ srcs[b+1] = srcs[b]; --b; }
    srcs[b+1] = v;
  }
}

__global__ void graph_offsets(const int* __restrict__ batch, int* __restrict__ goff, int N, int G){
  int g = blockIdx.x*blockDim.x + threadIdx.x;
  if (g > G) return;
  int lo=0, hi=N;
  while (lo<hi){ int mid=(lo+hi)>>1; if (batch[mid] < g) lo=mid+1; else hi=mid; }
  goff[g]=lo;
}

// ---------------- deterministic BN finalize ----------------
// pstats: [nb][256] per-block partials (sum | sumsq). Fixed-order reduce:
// 4 fixed chunks, fixed order within chunk, fixed combine order.
__global__ __launch_bounds__(1024) void bnfin_det(
  const float* __restrict__ pstats, int nb,
  const float* __restrict__ g, const float* __restrict__ be,
  float* __restrict__ S, float invN)
{
  __shared__ float part[4][256];
  int t = threadIdx.x;
  int col = t & 255, grp = t >> 8;
  int chunk = (nb + 3) >> 2;
  int b0 = grp*chunk, b1 = min(b0+chunk, nb);
  float s = 0.f;
  for (int b=b0; b<b1; ++b) s += pstats[(size_t)b*256 + col];
  part[grp][col] = s;
  __syncthreads();
  if (t < 256){
    float tot = ((part[0][t] + part[1][t]) + part[2][t]) + part[3][t];
    part[0][t] = tot;
  }
  __syncthreads();
  if (t < 128){
    float m = part[0][t]*invN;
    float v = part[0][128+t]*invN - m*m;
    float sc = g[t]*rsqrtf(v + 1e-5f);
    S[t] = sc;
    S[128+t] = be[t] - m*sc;
  }
}

// ---------------- register-streaming MFMA GEMM (deterministic stats) -------
// C(N,128) = bnrelu(A)(N,K) @ W(K,128) + bias;  K = npart*128.
// Block 256 thr / 4 waves; wave tile = 32 rows x 128 cols (mt=2, nt=8).
__global__ __launch_bounds__(256, 4) void gemm_rs(
  const u16* __restrict__ A0, const u16* __restrict__ A1,
  const u16* __restrict__ A2, const u16* __restrict__ A3,
  const float* __restrict__ S0, const float* __restrict__ S1,
  const float* __restrict__ S2, const float* __restrict__ S3,
  const u16* __restrict__ wt_hi, const u16* __restrict__ wt_lo,
  const float* __restrict__ bias,
  u16* __restrict__ C, float* __restrict__ pstats,
  int N, int npart)
{
  __shared__ u16 cst[4][2][16*136];   // per-wave C transpose slices (pad 136)
  __shared__ float pw[4][256];        // per-wave stat partials
  const int t = threadIdx.x;
  const int lane = t & 63;
  const int wid = t >> 6;
  const int m16 = lane & 15;
  const int kg = lane >> 4;
  const int wrow0 = blockIdx.x*128 + wid*32;
  const int K = npart << 7;

  f4v acc[2][8];
  #pragma unroll
  for (int i=0;i<2;++i)
    #pragma unroll
    for (int j=0;j<8;++j) acc[i][j] = (f4v){0.f,0.f,0.f,0.f};

  const u16* Ap[4] = {A0,A1,A2,A3};
  const float* Sp[4] = {S0,S1,S2,S3};

  for (int part=0; part<npart; ++part){
    const u16* A = Ap[part];
    const float* S = Sp[part];

    // ---- X fragments: global->reg, bn+relu, bf16 hi/lo split ----
    s8v xh[2][4], xl[2][4];
    #pragma unroll
    for (int mt=0; mt<2; ++mt){
      int row = wrow0 + mt*16 + m16;
      const u16* Arow = A + (size_t)row*128;
      #pragma unroll
      for (int ks=0; ks<4; ++ks){
        int koff = ks*32 + kg*8;
        s8v xr = (row < N) ? *(const s8v*)(Arow + koff)
                           : (s8v){0,0,0,0,0,0,0,0};
        float sc[8], sh[8];
        if (S){
          float4 a0 = *(const float4*)(S + koff);
          float4 a1 = *(const float4*)(S + koff + 4);
          float4 b0 = *(const float4*)(S + 128 + koff);
          float4 b1 = *(const float4*)(S + 128 + koff + 4);
          sc[0]=a0.x; sc[1]=a0.y; sc[2]=a0.z; sc[3]=a0.w;
          sc[4]=a1.x; sc[5]=a1.y; sc[6]=a1.z; sc[7]=a1.w;
          sh[0]=b0.x; sh[1]=b0.y; sh[2]=b0.z; sh[3]=b0.w;
          sh[4]=b1.x; sh[5]=b1.y; sh[6]=b1.z; sh[7]=b1.w;
        }
        s8v h, l;
        #pragma unroll
        for (int j=0;j<8;++j){
          float f = h2f((u16)xr[j]);
          if (S) f = fmaxf(fmaf(f, sc[j], sh[j]), 0.f);
          u16 hb = f2bf(f);
          u16 lb = f2bf(f - bf2f(hb));
          h[j] = (short)hb; l[j] = (short)lb;
        }
        xh[mt][ks] = h; xl[mt][ks] = l;
      }
    }

    // ---- K loop: W fragments global->reg (L2-hot), MFMA ----
    const u16* WHp = wt_hi + part*128;
    const u16* WLp = wt_lo + part*128;
    #pragma unroll
    for (int ks=0; ks<4; ++ks){
      int koff = ks*32 + kg*8;
      #pragma unroll
      for (int nh=0; nh<2; ++nh){
        s8v wh[4], wl[4];
        #pragma unroll
        for (int n4=0;n4<4;++n4){
          int n = (nh*4+n4)*16 + m16;
          size_t wa = (size_t)n*K + koff;
          wh[n4] = *(const s8v*)(WHp + wa);
          wl[n4] = *(const s8v*)(WLp + wa);
        }
        #pragma unroll
        for (int mt=0;mt<2;++mt){
          #pragma unroll
          for (int n4=0;n4<4;++n4){
            acc[mt][nh*4+n4] = __builtin_amdgcn_mfma_f32_16x16x32_bf16(wh[n4], xh[mt][ks], acc[mt][nh*4+n4], 0,0,0);
            acc[mt][nh*4+n4] = __builtin_amdgcn_mfma_f32_16x16x32_bf16(wl[n4], xh[mt][ks], acc[mt][nh*4+n4], 0,0,0);
            acc[mt][nh*4+n4] = __builtin_amdgcn_mfma_f32_16x16x32_bf16(wh[n4], xl[mt][ks], acc[mt][nh*4+n4], 0,0,0);
          }
        }
      }
    }
  }

  // ---- epilogue: +bias, fp16 round, cst write, DETERMINISTIC stats ----
  // Per (nt): accumulate s1/s2 over mt in-thread (fixed order), one 16-lane
  // shfl_xor tree (fixed pairing), lane m16==0 writes pw[wid] (one writer
  // per entry). No atomics.
  #pragma unroll
  for (int nt=0;nt<8;++nt){
    int n0 = nt*16 + kg*4;
    float4 b4 = *(const float4*)(bias + n0);
    float s1a=0.f,s1b=0.f,s1c=0.f,s1d=0.f;
    float s2a=0.f,s2b=0.f,s2c=0.f,s2d=0.f;
    #pragma unroll
    for (int mt=0;mt<2;++mt){
      int row = wrow0 + mt*16 + m16;
      us4 o;
      o.x = f2h(acc[mt][nt][0] + b4.x);
      o.y = f2h(acc[mt][nt][1] + b4.y);
      o.z = f2h(acc[mt][nt][2] + b4.z);
      o.w = f2h(acc[mt][nt][3] + b4.w);
      *(us4*)(&cst[wid][mt][m16*136 + n0]) = o;
      if (row < N){
        float r0=h2f(o.x), r1=h2f(o.y), r2=h2f(o.z), r3=h2f(o.w);
        s1a+=r0; s1b+=r1; s1c+=r2; s1d+=r3;
        s2a+=r0*r0; s2b+=r1*r1; s2c+=r2*r2; s2d+=r3*r3;
      }
    }
    #pragma unroll
    for (int off=1; off<16; off<<=1){
      s1a += __shfl_xor(s1a, off, 64); s1b += __shfl_xor(s1b, off, 64);
      s1c += __shfl_xor(s1c, off, 64); s1d += __shfl_xor(s1d, off, 64);
      s2a += __shfl_xor(s2a, off, 64); s2b += __shfl_xor(s2b, off, 64);
      s2c += __shfl_xor(s2c, off, 64); s2d += __shfl_xor(s2d, off, 64);
    }
    if (m16 == 0){
      pw[wid][n0+0] = s1a; pw[wid][n0+1] = s1b;
      pw[wid][n0+2] = s1c; pw[wid][n0+3] = s1d;
      pw[wid][128+n0+0] = s2a; pw[wid][128+n0+1] = s2b;
      pw[wid][128+n0+2] = s2c; pw[wid][128+n0+3] = s2d;
    }
  }
  __syncthreads();
  if (t < 256){
    float tot = ((pw[0][t] + pw[1][t]) + pw[2][t]) + pw[3][t];  // fixed order
    pstats[(size_t)blockIdx.x*256 + t] = tot;
  }
  // full-line C stores: all 16 16-byte chunks per 256 B row covered.
  #pragma unroll
  for (int mt=0;mt<2;++mt){
    #pragma unroll
    for (int it=0; it<4; ++it){
      int idx = it*64 + lane;
      int r = idx >> 4;
      int c8 = (idx & 15) * 8;
      int row = wrow0 + mt*16 + r;
      if (row < N){
        s8v v = *(const s8v*)(&cst[wid][mt][r*136 + c8]);
        *(s8v*)(C + (size_t)row*128 + c8) = v;
      }
    }
  }
}

// ---------------- small-K encoder GEMM (fp32 inputs, K <= 26) ----------------
// Deterministic stats: per-block partials via LDS fixed-order combine.
__global__ __launch_bounds__(256) void gemm_enc(
  const float* __restrict__ X0, int w0, const float* __restrict__ X1, int w1,
  const float* __restrict__ W, const float* __restrict__ bias,
  u16* __restrict__ C, float* __restrict__ pstats, int N)
{
  __shared__ float Ws[26*128];
  __shared__ float red[256];
  int K = w0 + w1;
  int t = threadIdx.x;
  for (int i=t;i<K*128;i+=256) Ws[i] = W[i];
  __syncthreads();
  int c = t & 127, rh = t >> 7;
  float b = bias[c];
  float s1=0.f, s2=0.f;
  for (int r0 = blockIdx.x*2; r0 < N; r0 += gridDim.x*2){
    int r = r0 + rh;
    if (r < N){
      float acc = b;
      for (int k=0;k<w0;++k) acc = fmaf(X0[(size_t)r*w0+k], Ws[k*128+c], acc);
      for (int k=0;k<w1;++k) acc = fmaf(X1[(size_t)r*w1+k], Ws[(w0+k)*128+c], acc);
      u16 o = f2h(acc);
      C[(size_t)r*128+c] = o;
      float rv = h2f(o);
      s1 += rv; s2 += rv*rv;
    }
  }
  red[t] = s1; __syncthreads();
  float t1 = (t < 128) ? (red[t] + red[t+128]) : 0.f;   // fixed order
  __syncthreads();
  red[t] = s2; __syncthreads();
  float t2 = (t < 128) ? (red[t] + red[t+128]) : 0.f;
  if (t < 128){
    pstats[(size_t)blockIdx.x*256 + t] = t1;
    pstats[(size_t)blockIdx.x*256 + 128 + t] = t2;
  }
}

// ---------------- GIN aggregation (4x unrolled gather, in-order adds) ------
__global__ __launch_bounds__(256) void aggregate_hf(
  const u16* __restrict__ X, const float* __restrict__ S,
  const int* __restrict__ srcs, const int* __restrict__ offs,
  const float* __restrict__ geps, int gi, u16* __restrict__ Z, int N)
{
  int i = blockIdx.x*4 + (threadIdx.x>>6);
  int ln = threadIdx.x & 63;
  int c = ln*2;
  if (i >= N) return;
  float sca = S[c], sha = S[128+c];
  float scb = S[c+1], shb = S[128+c+1];
  float eps1 = 1.0f + geps[gi];
  us2 x0 = *(const us2*)(X + (size_t)i*128 + c);
  float acca = eps1 * fmaxf(fmaf(h2f(x0.x), sca, sha), 0.f);
  float accb = eps1 * fmaxf(fmaf(h2f(x0.y), scb, shb), 0.f);
  int e0 = offs[i], e1 = offs[i+1];
  int e = e0;
  for (; e+4 <= e1; e += 4){
    int s0 = srcs[e], s1 = srcs[e+1], s2 = srcs[e+2], s3 = srcs[e+3];
    us2 v0 = *(const us2*)(X + (size_t)s0*128 + c);
    us2 v1 = *(const us2*)(X + (size_t)s1*128 + c);
    us2 v2 = *(const us2*)(X + (size_t)s2*128 + c);
    us2 v3 = *(const us2*)(X + (size_t)s3*128 + c);
    acca += fmaxf(fmaf(h2f(v0.x), sca, sha), 0.f);
    accb += fmaxf(fmaf(h2f(v0.y), scb, shb), 0.f);
    acca += fmaxf(fmaf(h2f(v1.x), sca, sha), 0.f);
    accb += fmaxf(fmaf(h2f(v1.y), scb, shb), 0.f);
    acca += fmaxf(fmaf(h2f(v2.x), sca, sha), 0.f);
    accb += fmaxf(fmaf(h2f(v2.y), scb, shb), 0.f);
    acca += fmaxf(fmaf(h2f(v3.x), sca, sha), 0.f);
    accb += fmaxf(fmaf(h2f(v3.y), scb, shb), 0.f);
  }
  for (; e < e1; ++e){
    int s = srcs[e];
    us2 xv = *(const us2*)(X + (size_t)s*128 + c);
    acca += fmaxf(fmaf(h2f(xv.x), sca, sha), 0.f);
    accb += fmaxf(fmaf(h2f(xv.y), scb, shb), 0.f);
  }
  us2 o; o.x = f2h(acca); o.y = f2h(accb);
  *(us2*)(Z + (size_t)i*128 + c) = o;
}

// ---------------- Set2Set ----------------
__global__ __launch_bounds__(256) void lstm_step(
  float* __restrict__ q_star, float* __restrict__ h, float* __restrict__ cst,
  const float* __restrict__ Wih, const float* __restrict__ Whh,
  const float* __restrict__ bih, const float* __restrict__ bhh, int G)
{
  __shared__ float q[256], hh[128], z[512];
  int t = threadIdx.x;
  for (int g = blockIdx.x; g < G; g += gridDim.x){
    q[t] = q_star[(size_t)g*256 + t];
    if (t < 128) hh[t] = h[(size_t)g*128 + t];
    __syncthreads();
    #pragma unroll
    for (int p=0;p<2;++p){
      int j = t + 256*p;
      float acc = bih[j] + bhh[j];
      const float* wi = Wih + (size_t)j*256;
      const float* wh = Whh + (size_t)j*128;
      for (int k=0;k<256;++k) acc = fmaf(q[k], wi[k], acc);
      for (int k=0;k<128;++k) acc = fmaf(hh[k], wh[k], acc);
      z[j] = acc;
    }
    __syncthreads();
    if (t < 128){
      float i_ = z[t], f_ = z[128+t], g_ = z[256+t], o_ = z[384+t];
      float cc = sigmoidf_(f_)*cst[(size_t)g*128+t] + sigmoidf_(i_)*tanhf(g_);
      float hn = sigmoidf_(o_)*tanhf(cc);
      cst[(size_t)g*128+t] = cc;
      h[(size_t)g*128+t]  = hn;
      q_star[(size_t)g*256+t] = hn;
    }
    __syncthreads();
  }
}

__global__ __launch_bounds__(256) void dot_h_hf(
  const u16* __restrict__ X, const float* __restrict__ S,
  const float* __restrict__ h, const int* __restrict__ batch,
  float* __restrict__ e, int N)
{
  int wv = threadIdx.x >> 6, ln = threadIdx.x & 63;
  int i = blockIdx.x*4 + wv;
  if (i >= N) return;
  int g = batch[i];
  int c = ln*2;
  us2 x2 = *(const us2*)(X + (size_t)i*128 + c);
  float2 h2 = *(const float2*)(h + (size_t)g*128 + c);
  float xa = fmaxf(fmaf(h2f(x2.x), S[c],   S[128+c]),   0.f);
  float xb = fmaxf(fmaf(h2f(x2.y), S[c+1], S[128+c+1]), 0.f);
  float p = xa*h2.x + xb*h2.y;
  #pragma unroll
  for (int off=32; off; off>>=1) p += __shfl_down(p, off, 64);
  if (ln==0) e[i] = p;
}

__global__ __launch_bounds__(256) void seg_reduce(
  const float* __restrict__ e, const int* __restrict__ goff,
  float* __restrict__ emax, float* __restrict__ invden, int G)
{
  int g = blockIdx.x;
  int lo = goff[g], hi = goff[g+1];
  int t = threadIdx.x;
  __shared__ float red[256];
  float m = -3.4e38f;
  for (int i=lo+t; i<hi; i+=256) m = fmaxf(m, e[i]);
  red[t] = m; __syncthreads();
  for (int d=128; d; d>>=1){ if (t<d) red[t] = fmaxf(red[t], red[t+d]); __syncthreads(); }
  m = red[0]; __syncthreads();
  float s = 0.f;
  for (int i=lo+t; i<hi; i+=256) s += expf(e[i]-m);
  red[t] = s; __syncthreads();
  for (int d=128; d; d>>=1){ if (t<d) red[t] += red[t+d]; __syncthreads(); }
  if (t==0){
    emax[g] = m;
    invden[g] = (hi>lo && red[0]>0.f) ? 1.f/red[0] : 0.f;
  }
}

__global__ __launch_bounds__(128) void r_kernel_hf(
  const u16* __restrict__ X, const float* __restrict__ S,
  const float* __restrict__ e, const int* __restrict__ goff,
  const float* __restrict__ emax, const float* __restrict__ invden,
  float* __restrict__ q_star, int G)
{
  int g = blockIdx.x, c = threadIdx.x;
  int lo = goff[g], hi = goff[g+1];
  float m = emax[g], inv = invden[g];
  float sc = S[c], sh = S[128+c];
  float r = 0.f;
  for (int i=lo; i<hi; ++i){
    float w = expf(e[i]-m);
    r = fmaf(w, fmaxf(fmaf(h2f(X[(size_t)i*128+c]), sc, sh), 0.f), r);
  }
  q_star[(size_t)g*256 + 128 + c] = r*inv;
}

__global__ __launch_bounds__(128) void final_k(
  const float* __restrict__ q_star, const float* __restrict__ fc1W,
  const float* __restrict__ fc1b, const float* __restrict__ fc4W,
  const float* __restrict__ fc4b, float* __restrict__ out, int G)
{
  __shared__ float q[256];
  __shared__ float h1[128];
  int g = blockIdx.x, t = threadIdx.x;
  q[t]     = q_star[(size_t)g*256 + t];
  q[128+t] = q_star[(size_t)g*256 + 128 + t];
  __syncthreads();
  float acc = fc1b[t];
  for (int k=0;k<256;++k) acc = fmaf(q[k], fc1W[(size_t)k*128+t], acc);
  h1[t] = fmaxf(acc, 0.f);
  __syncthreads();
  if (t < 12){
    float o = fc4b[t];
    for (int d=0; d<128; ++d) o = fmaf(h1[d], fc4W[(size_t)d*12+t], o);
    out[(size_t)g*12+t] = o;
  }
}

// ---------------------------------------------------------------------------
extern "C" void kernel_launch(void* const* d_in, const int* in_sizes, int n_in,
                              void* d_out, int out_size, void* d_ws, size_t ws_size,
                              hipStream_t stream)
{
  (void)n_in; (void)ws_size;
  const int N = in_sizes[0] / 3;
  const int E = in_sizes[62] / 2;
  const int G = out_size / 12;

  auto P = [&](int i){ return (const float*)d_in[i]; };
  const float* gb1 = P(38); const float* gg1 = P(39); const float* gbe1 = P(40);
  const float* gb2 = P(42); const float* gg2 = P(43); const float* gbe2 = P(44);
  const float* geps = P(45);
  const float* mb1 = P(47); const float* mg1 = P(48); const float* mbe1 = P(49);
  const float* mb2 = P(51); const float* mg2 = P(52); const float* mbe2 = P(53);
  const int* ei[4] = {(const int*)d_in[62], (const int*)d_in[63],
                      (const int*)d_in[64], (const int*)d_in[65]};
  const int* batch = (const int*)d_in[66];

  const int ggrid = (N + 127)/128;
  const int ENC_GRID = 1024;
  const int NB_MAX = (ggrid > ENC_GRID) ? ggrid : ENC_GRID;

  char* ws = (char*)d_ws;
  size_t off = 0;
  auto alloc = [&](size_t bytes)->char*{
    char* p = ws + off;
    off = (off + bytes + 255) & ~(size_t)255;
    return p;
  };
  u16* X = (u16*)alloc((size_t)N*128*2);              // also the MLP intermediate
  u16* Z[4]; for (int k=0;k<4;++k) Z[k] = (u16*)alloc((size_t)N*128*2);
  float* ebuf  = (float*)alloc((size_t)N*4);
  float* pstats= (float*)alloc((size_t)NB_MAX*256*4); // per-block stat partials
  float* Sb    = (float*)alloc(6*256*4);
  int* offs4 = (int*)alloc((size_t)4*(N+1)*4);
  int* srcs4 = (int*)alloc((size_t)4*E*4);
  int* cnt4  = (int*)alloc((size_t)4*N*4);
  int* goff  = (int*)alloc((size_t)(G+1)*4);
  float* qstar = (float*)alloc((size_t)G*256*4);
  float* hbuf  = (float*)alloc((size_t)G*128*4);
  float* cbuf  = (float*)alloc((size_t)G*128*4);
  float* emax  = (float*)alloc((size_t)G*4);
  float* invden= (float*)alloc((size_t)G*4);
  const size_t WT_ELEMS = 1392640;
  u16* WTh = (u16*)alloc(WT_ELEMS*2);
  u16* WTl = (u16*)alloc(WT_ELEMS*2);

  // W^T plane offsets (elems)
  const size_t oEnc0=0, oEnc1=16384, oEnc2=32768, oM0W1=49152, oM0W2=98304;
  const size_t oGW1=114688, oGW2=507904, oMW1=901120, oMW2=1294336;

  const float invN = 1.0f / (float)N;
  const int ST = 0, SX = 1, SZ0 = 2;
  auto Sl = [&](int i){ return Sb + (size_t)i*256; };

  // ---- weight preprocessing (transpose + bf16 split) ----
  auto prep = [&](const float* src, size_t o, int K, int count){
    int tot = count*K*128;
    split_transpose<<<(tot+255)/256,256,0,stream>>>(src, WTh+o, WTl+o, K, count);
  };
  prep(P(9),  oEnc0, 128, 1);
  prep(P(17), oEnc1, 128, 1);
  prep(P(25), oEnc2, 128, 1);
  prep(P(29), oM0W1, 384, 1);
  prep(P(33), oM0W2, 128, 1);
  prep(P(37), oGW1,  128, 24);
  prep(P(41), oGW2,  128, 24);
  prep(P(46), oMW1,  512, 6);
  prep(P(50), oMW2,  128, 6);

  // ---- CSR build (+ per-node value sort for deterministic sums) ----
  int zgrid = (4*N + 255)/256;
  zero_k<<<zgrid,256,0,stream>>>((float*)cnt4, 4*N);
  int egrid = (E + 255)/256;
  for (int l=0;l<4;++l)
    count_deg<<<egrid,256,0,stream>>>(ei[l]+E, cnt4 + (size_t)l*N, E);
  scan_excl<<<4,1024,0,stream>>>(cnt4, offs4, N);
  zero_k<<<zgrid,256,0,stream>>>((float*)cnt4, 4*N);
  for (int l=0;l<4;++l)
    fill_csr<<<egrid,256,0,stream>>>(ei[l], ei[l]+E, offs4 + (size_t)l*(N+1),
                                     cnt4 + (size_t)l*N, srcs4 + (size_t)l*E, E);
  int ngrid = (N + 255)/256;
  for (int l=0;l<4;++l)
    sort_csr<<<ngrid,256,0,stream>>>(offs4 + (size_t)l*(N+1), srcs4 + (size_t)l*E, N);
  graph_offsets<<<(G+1+255)/256,256,0,stream>>>(batch, goff, N, G);

  auto run_bnfin = [&](int nb, const float* g, const float* be, float* S){
    bnfin_det<<<1,1024,0,stream>>>(pstats, nb, g, be, S, invN);
  };
  auto run_gemm1 = [&](const u16* A, const float* S, size_t wo, const float* b, u16* Cc){
    gemm_rs<<<ggrid,256,0,stream>>>(A,nullptr,nullptr,nullptr, S,nullptr,nullptr,nullptr,
                                    WTh+wo, WTl+wo, b, Cc, pstats, N, 1);
  };

  // ---- encoders (X doubles as the intermediate T) ----
  gemm_enc<<<ENC_GRID,256,0,stream>>>(P(0),3, nullptr,0, P(5), P(6), X, pstats, N);
  run_bnfin(ENC_GRID, P(7), P(8), Sl(ST));
  run_gemm1(X, Sl(ST), oEnc0, P(10), Z[0]);
  run_bnfin(ggrid, P(11), P(12), Sl(SZ0+0));

  gemm_enc<<<ENC_GRID,256,0,stream>>>(P(1),13, P(2),13, P(13), P(14), X, pstats, N);
  run_bnfin(ENC_GRID, P(15), P(16), Sl(ST));
  run_gemm1(X, Sl(ST), oEnc1, P(18), Z[1]);
  run_bnfin(ggrid, P(19), P(20), Sl(SZ0+1));

  gemm_enc<<<ENC_GRID,256,0,stream>>>(P(3),4, P(4),1, P(21), P(22), X, pstats, N);
  run_bnfin(ENC_GRID, P(23), P(24), Sl(ST));
  run_gemm1(X, Sl(ST), oEnc2, P(26), Z[2]);
  run_bnfin(ggrid, P(27), P(28), Sl(SZ0+2));

  // m0: concat [nl, na, ea] = Z0,Z1,Z2  (K=384)
  gemm_rs<<<ggrid,256,0,stream>>>(Z[0],Z[1],Z[2],nullptr,
                                  Sl(SZ0+0),Sl(SZ0+1),Sl(SZ0+2),nullptr,
                                  WTh+oM0W1, WTl+oM0W1, P(30), X, pstats, N, 3);
  run_bnfin(ggrid, P(31), P(32), Sl(ST));
  run_gemm1(X, Sl(ST), oM0W2, P(34), X);        // in-place (row-exclusive)
  run_bnfin(ggrid, P(35), P(36), Sl(SX));

  // ---- 6 GIN layers ----
  int agrid = (N + 3)/4;
  for (int L=0; L<6; ++L){
    for (int k=0;k<4;++k){
      int gi = 4*L + k;
      aggregate_hf<<<agrid,256,0,stream>>>(X, Sl(SX), srcs4 + (size_t)k*E,
                                           offs4 + (size_t)k*(N+1), geps, gi, Z[k], N);
    }
    for (int k=0;k<4;++k){
      int gi = 4*L + k;
      run_gemm1(Z[k], nullptr, oGW1 + (size_t)gi*16384, gb1 + (size_t)gi*128, X);
      run_bnfin(ggrid, gg1 + (size_t)gi*128, gbe1 + (size_t)gi*128, Sl(ST));
      run_gemm1(X, Sl(ST), oGW2 + (size_t)gi*16384, gb2 + (size_t)gi*128, Z[k]);
      run_bnfin(ggrid, gg2 + (size_t)gi*128, gbe2 + (size_t)gi*128, Sl(SZ0+k));
    }
    // fusion: concat [x1, x3, x2, x4] = Z0, Z2, Z1, Z3  (K=512)
    gemm_rs<<<ggrid,256,0,stream>>>(Z[0],Z[2],Z[1],Z[3],
                                    Sl(SZ0+0),Sl(SZ0+2),Sl(SZ0+1),Sl(SZ0+3),
                                    WTh+oMW1+(size_t)L*65536, WTl+oMW1+(size_t)L*65536,
                                    mb1 + (size_t)L*128, X, pstats, N, 4);
    run_bnfin(ggrid, mg1 + (size_t)L*128, mbe1 + (size_t)L*128, Sl(ST));
    run_gemm1(X, Sl(ST), oMW2 + (size_t)L*16384, mb2 + (size_t)L*128, X);  // in-place
    run_bnfin(ggrid, mg2 + (size_t)L*128, mbe2 + (size_t)L*128, Sl(SX));
  }

  // ---- Set2Set (6 steps) ----
  zero_k<<<(G*256+255)/256,256,0,stream>>>(qstar, G*256);
  zero_k<<<(G*128+255)/256,256,0,stream>>>(hbuf, G*128);
  zero_k<<<(G*128+255)/256,256,0,stream>>>(cbuf, G*128);
  int dgrid = (N + 3)/4;
  for (int s=0;s<6;++s){
    lstm_step<<<64,256,0,stream>>>(qstar, hbuf, cbuf, P(54), P(55), P(56), P(57), G);
    dot_h_hf<<<dgrid,256,0,stream>>>(X, Sl(SX), hbuf, batch, ebuf, N);
    seg_reduce<<<G,256,0,stream>>>(ebuf, goff, emax, invden, G);
    r_kernel_hf<<<G,128,0,stream>>>(X, Sl(SX), ebuf, goff, emax, invden, qstar, G);
  }

  final_k<<<G,128,0,stream>>>(qstar, P(58), P(59), P(60), P(61), (float*)d_out, G);
}

// Round 9
// 13870.363 us; speedup vs baseline: 1.4438x; 1.4438x over previous
//
#include <hip/hip_runtime.h>
#include <math.h>

// ---------------------------------------------------------------------------
// NetGIN forward on MI355X — round 9: register-lean deterministic MFMA GEMM.
// R8 was correct+deterministic but __launch_bounds__(256,4) capped VGPRs at
// 64 -> ~1.6 GB/dispatch scratch spill traffic. This round: X fragments are
// loaded/split INSIDE the ks loop (16 transient VGPRs instead of 64
// persistent; same ops, same order -> bitwise-identical output) and launch
// bounds (256,3): cap ~170 VGPRs >= ~145 live -> no spills, 3 blocks/CU.
// Everything else as R8: fp16 activations, BN-on-read, bf16 2-term split,
// deterministic per-block stats + fixed-order bnfin, sorted CSR.
// ---------------------------------------------------------------------------

#define DEV_INLINE __device__ __forceinline__
typedef unsigned short u16;

union F16U { _Float16 h; u16 u; };
DEV_INLINE float h2f(u16 v){ F16U t; t.u = v; return (float)t.h; }
DEV_INLINE u16 f2h(float f){ F16U t; t.h = (_Float16)f; return t.u; }
DEV_INLINE float bf2f(u16 h){ return __uint_as_float(((unsigned)h)<<16); }
DEV_INLINE u16 f2bf(float f){
  unsigned u = __float_as_uint(f);
  unsigned r = (u + 0x7FFFu + ((u>>16)&1u)) >> 16;
  return (u16)r;
}
DEV_INLINE float sigmoidf_(float x){ return 1.0f/(1.0f+expf(-x)); }
struct __align__(4) us2 { u16 x, y; };
struct __align__(8) us4 { u16 x, y, z, w; };

typedef __attribute__((ext_vector_type(8))) short s8v;   // 8 bf16/fp16 (4 VGPRs)
typedef __attribute__((ext_vector_type(4))) float f4v;   // 4 fp32 acc

// ---------------- utility ----------------
__global__ void zero_k(float* __restrict__ p, int n){
  int i = blockIdx.x*256 + threadIdx.x;
  if (i < n) p[i] = 0.f;
}

// ---------------- weight pre-transpose + bf16 split ----------------
__global__ __launch_bounds__(256) void split_transpose(
  const float* __restrict__ src, u16* __restrict__ dh, u16* __restrict__ dl,
  int K, int count)
{
  int tot = count*K*128;
  for (int i = blockIdx.x*256 + threadIdx.x; i < tot; i += gridDim.x*256){
    int k = i % K;
    int n = (i / K) & 127;
    int c = i / (K*128);
    float w = src[(size_t)c*K*128 + (size_t)k*128 + n];
    u16 hi = f2bf(w);
    u16 lo = f2bf(w - bf2f(hi));
    dh[i] = hi; dl[i] = lo;
  }
}

// ---------------- CSR build ----------------
__global__ void count_deg(const int* __restrict__ dst, int* __restrict__ cnt, int E){
  int e = blockIdx.x*256 + threadIdx.x;
  if (e < E) atomicAdd(&cnt[dst[e]], 1);      // int atomics: exact, order-free
}

__global__ void scan_excl(const int* __restrict__ cnt, int* __restrict__ offs, int N){
  const int* c = cnt + (size_t)blockIdx.x * N;
  int* o = offs + (size_t)blockIdx.x * (N+1);
  __shared__ int ps[1024];
  int t = threadIdx.x;
  int chunk = (N + 1023) >> 10;
  int lo = t*chunk, hi = min(lo+chunk, N);
  int s = 0;
  for (int i=lo;i<hi;++i) s += c[i];
  ps[t] = s; __syncthreads();
  for (int d=1; d<1024; d<<=1){
    int v = (t>=d) ? ps[t-d] : 0;
    __syncthreads();
    ps[t] += v;
    __syncthreads();
  }
  int pre = (t==0) ? 0 : ps[t-1];
  for (int i=lo;i<hi;++i){ o[i]=pre; pre += c[i]; }
  if (t==1023) o[N] = ps[1023];
}

__global__ void fill_csr(const int* __restrict__ src, const int* __restrict__ dst,
                         const int* __restrict__ offs, int* __restrict__ cur,
                         int* __restrict__ out, int E){
  int e = blockIdx.x*256 + threadIdx.x;
  if (e >= E) return;
  int d = dst[e];
  int pos = offs[d] + atomicAdd(&cur[d], 1);  // placement order varies ...
  out[pos] = src[e];
}

// ... so sort each node's segment by value -> deterministic sum order.
__global__ void sort_csr(const int* __restrict__ offs, int* __restrict__ srcs, int N){
  int i = blockIdx.x*256 + threadIdx.x;
  if (i >= N) return;
  int lo = offs[i], hi = offs[i+1];
  for (int a = lo+1; a < hi; ++a){
    int v = srcs[a];
    int b = a-1;
    while (b >= lo && srcs[b] > v){ srcs[b+1] = srcs[b]; --b; }
    srcs[b+1] = v;
  }
}

__global__ void graph_offsets(const int* __restrict__ batch, int* __restrict__ goff, int N, int G){
  int g = blockIdx.x*blockDim.x + threadIdx.x;
  if (g > G) return;
  int lo=0, hi=N;
  while (lo<hi){ int mid=(lo+hi)>>1; if (batch[mid] < g) lo=mid+1; else hi=mid; }
  goff[g]=lo;
}

// ---------------- deterministic BN finalize ----------------
__global__ __launch_bounds__(1024) void bnfin_det(
  const float* __restrict__ pstats, int nb,
  const float* __restrict__ g, const float* __restrict__ be,
  float* __restrict__ S, float invN)
{
  __shared__ float part[4][256];
  int t = threadIdx.x;
  int col = t & 255, grp = t >> 8;
  int chunk = (nb + 3) >> 2;
  int b0 = grp*chunk, b1 = min(b0+chunk, nb);
  float s = 0.f;
  for (int b=b0; b<b1; ++b) s += pstats[(size_t)b*256 + col];
  part[grp][col] = s;
  __syncthreads();
  if (t < 256){
    float tot = ((part[0][t] + part[1][t]) + part[2][t]) + part[3][t];
    part[0][t] = tot;
  }
  __syncthreads();
  if (t < 128){
    float m = part[0][t]*invN;
    float v = part[0][128+t]*invN - m*m;
    float sc = g[t]*rsqrtf(v + 1e-5f);
    S[t] = sc;
    S[128+t] = be[t] - m*sc;
  }
}

// ---------------- register-lean streaming MFMA GEMM ----------------
// C(N,128) = bnrelu(A)(N,K) @ W(K,128) + bias;  K = npart*128.
// Block 256 thr / 4 waves; wave tile = 32 rows x 128 cols (mt=2, nt=8).
// X fragments loaded+split per ks (transient) -> ~145 live VGPRs, no spill.
__global__ __launch_bounds__(256, 3) void gemm_rs(
  const u16* __restrict__ A0, const u16* __restrict__ A1,
  const u16* __restrict__ A2, const u16* __restrict__ A3,
  const float* __restrict__ S0, const float* __restrict__ S1,
  const float* __restrict__ S2, const float* __restrict__ S3,
  const u16* __restrict__ wt_hi, const u16* __restrict__ wt_lo,
  const float* __restrict__ bias,
  u16* __restrict__ C, float* __restrict__ pstats,
  int N, int npart)
{
  __shared__ u16 cst[4][2][16*136];   // per-wave C transpose slices (pad 136)
  __shared__ float pw[4][256];        // per-wave stat partials
  const int t = threadIdx.x;
  const int lane = t & 63;
  const int wid = t >> 6;
  const int m16 = lane & 15;
  const int kg = lane >> 4;
  const int wrow0 = blockIdx.x*128 + wid*32;
  const int K = npart << 7;

  f4v acc[2][8];
  #pragma unroll
  for (int i=0;i<2;++i)
    #pragma unroll
    for (int j=0;j<8;++j) acc[i][j] = (f4v){0.f,0.f,0.f,0.f};

  const u16* Ap[4] = {A0,A1,A2,A3};
  const float* Sp[4] = {S0,S1,S2,S3};

  for (int part=0; part<npart; ++part){
    const u16* A = Ap[part];
    const float* S = Sp[part];
    const u16* WHp = wt_hi + part*128;
    const u16* WLp = wt_lo + part*128;

    #pragma unroll
    for (int ks=0; ks<4; ++ks){
      int koff = ks*32 + kg*8;

      // ---- X fragments for THIS ks: global->reg, bn+relu, bf16 split ----
      s8v xh[2], xl[2];
      float sc[8], sh[8];
      if (S){
        float4 a0 = *(const float4*)(S + koff);
        float4 a1 = *(const float4*)(S + koff + 4);
        float4 b0 = *(const float4*)(S + 128 + koff);
        float4 b1 = *(const float4*)(S + 128 + koff + 4);
        sc[0]=a0.x; sc[1]=a0.y; sc[2]=a0.z; sc[3]=a0.w;
        sc[4]=a1.x; sc[5]=a1.y; sc[6]=a1.z; sc[7]=a1.w;
        sh[0]=b0.x; sh[1]=b0.y; sh[2]=b0.z; sh[3]=b0.w;
        sh[4]=b1.x; sh[5]=b1.y; sh[6]=b1.z; sh[7]=b1.w;
      }
      #pragma unroll
      for (int mt=0; mt<2; ++mt){
        int row = wrow0 + mt*16 + m16;
        s8v xr = (row < N) ? *(const s8v*)(A + (size_t)row*128 + koff)
                           : (s8v){0,0,0,0,0,0,0,0};
        s8v h, l;
        #pragma unroll
        for (int j=0;j<8;++j){
          float f = h2f((u16)xr[j]);
          if (S) f = fmaxf(fmaf(f, sc[j], sh[j]), 0.f);
          u16 hb = f2bf(f);
          u16 lb = f2bf(f - bf2f(hb));
          h[j] = (short)hb; l[j] = (short)lb;
        }
        xh[mt] = h; xl[mt] = l;
      }

      // ---- W fragments (L2-hot) + MFMA ----
      #pragma unroll
      for (int nh=0; nh<2; ++nh){
        s8v wh[4], wl[4];
        #pragma unroll
        for (int n4=0;n4<4;++n4){
          int n = (nh*4+n4)*16 + m16;
          size_t wa = (size_t)n*K + koff;
          wh[n4] = *(const s8v*)(WHp + wa);
          wl[n4] = *(const s8v*)(WLp + wa);
        }
        #pragma unroll
        for (int mt=0;mt<2;++mt){
          #pragma unroll
          for (int n4=0;n4<4;++n4){
            acc[mt][nh*4+n4] = __builtin_amdgcn_mfma_f32_16x16x32_bf16(wh[n4], xh[mt], acc[mt][nh*4+n4], 0,0,0);
            acc[mt][nh*4+n4] = __builtin_amdgcn_mfma_f32_16x16x32_bf16(wl[n4], xh[mt], acc[mt][nh*4+n4], 0,0,0);
            acc[mt][nh*4+n4] = __builtin_amdgcn_mfma_f32_16x16x32_bf16(wh[n4], xl[mt], acc[mt][nh*4+n4], 0,0,0);
          }
        }
      }
    }
  }

  // ---- epilogue: +bias, fp16 round, cst write, DETERMINISTIC stats ----
  #pragma unroll
  for (int nt=0;nt<8;++nt){
    int n0 = nt*16 + kg*4;
    float4 b4 = *(const float4*)(bias + n0);
    float s1a=0.f,s1b=0.f,s1c=0.f,s1d=0.f;
    float s2a=0.f,s2b=0.f,s2c=0.f,s2d=0.f;
    #pragma unroll
    for (int mt=0;mt<2;++mt){
      int row = wrow0 + mt*16 + m16;
      us4 o;
      o.x = f2h(acc[mt][nt][0] + b4.x);
      o.y = f2h(acc[mt][nt][1] + b4.y);
      o.z = f2h(acc[mt][nt][2] + b4.z);
      o.w = f2h(acc[mt][nt][3] + b4.w);
      *(us4*)(&cst[wid][mt][m16*136 + n0]) = o;
      if (row < N){
        float r0=h2f(o.x), r1=h2f(o.y), r2=h2f(o.z), r3=h2f(o.w);
        s1a+=r0; s1b+=r1; s1c+=r2; s1d+=r3;
        s2a+=r0*r0; s2b+=r1*r1; s2c+=r2*r2; s2d+=r3*r3;
      }
    }
    #pragma unroll
    for (int off=1; off<16; off<<=1){
      s1a += __shfl_xor(s1a, off, 64); s1b += __shfl_xor(s1b, off, 64);
      s1c += __shfl_xor(s1c, off, 64); s1d += __shfl_xor(s1d, off, 64);
      s2a += __shfl_xor(s2a, off, 64); s2b += __shfl_xor(s2b, off, 64);
      s2d += __shfl_xor(s2d, off, 64); s2c += __shfl_xor(s2c, off, 64);
    }
    if (m16 == 0){
      pw[wid][n0+0] = s1a; pw[wid][n0+1] = s1b;
      pw[wid][n0+2] = s1c; pw[wid][n0+3] = s1d;
      pw[wid][128+n0+0] = s2a; pw[wid][128+n0+1] = s2b;
      pw[wid][128+n0+2] = s2c; pw[wid][128+n0+3] = s2d;
    }
  }
  __syncthreads();
  if (t < 256){
    float tot = ((pw[0][t] + pw[1][t]) + pw[2][t]) + pw[3][t];  // fixed order
    pstats[(size_t)blockIdx.x*256 + t] = tot;
  }
  // full-line C stores: all 16 16-byte chunks per 256 B row covered.
  #pragma unroll
  for (int mt=0;mt<2;++mt){
    #pragma unroll
    for (int it=0; it<4; ++it){
      int idx = it*64 + lane;
      int r = idx >> 4;
      int c8 = (idx & 15) * 8;
      int row = wrow0 + mt*16 + r;
      if (row < N){
        s8v v = *(const s8v*)(&cst[wid][mt][r*136 + c8]);
        *(s8v*)(C + (size_t)row*128 + c8) = v;
      }
    }
  }
}

// ---------------- small-K encoder GEMM (fp32 inputs, K <= 26) ----------------
__global__ __launch_bounds__(256) void gemm_enc(
  const float* __restrict__ X0, int w0, const float* __restrict__ X1, int w1,
  const float* __restrict__ W, const float* __restrict__ bias,
  u16* __restrict__ C, float* __restrict__ pstats, int N)
{
  __shared__ float Ws[26*128];
  __shared__ float red[256];
  int K = w0 + w1;
  int t = threadIdx.x;
  for (int i=t;i<K*128;i+=256) Ws[i] = W[i];
  __syncthreads();
  int c = t & 127, rh = t >> 7;
  float b = bias[c];
  float s1=0.f, s2=0.f;
  for (int r0 = blockIdx.x*2; r0 < N; r0 += gridDim.x*2){
    int r = r0 + rh;
    if (r < N){
      float acc = b;
      for (int k=0;k<w0;++k) acc = fmaf(X0[(size_t)r*w0+k], Ws[k*128+c], acc);
      for (int k=0;k<w1;++k) acc = fmaf(X1[(size_t)r*w1+k], Ws[(w0+k)*128+c], acc);
      u16 o = f2h(acc);
      C[(size_t)r*128+c] = o;
      float rv = h2f(o);
      s1 += rv; s2 += rv*rv;
    }
  }
  red[t] = s1; __syncthreads();
  float t1 = (t < 128) ? (red[t] + red[t+128]) : 0.f;   // fixed order
  __syncthreads();
  red[t] = s2; __syncthreads();
  float t2 = (t < 128) ? (red[t] + red[t+128]) : 0.f;
  if (t < 128){
    pstats[(size_t)blockIdx.x*256 + t] = t1;
    pstats[(size_t)blockIdx.x*256 + 128 + t] = t2;
  }
}

// ---------------- GIN aggregation (4x unrolled gather, in-order adds) ------
__global__ __launch_bounds__(256) void aggregate_hf(
  const u16* __restrict__ X, const float* __restrict__ S,
  const int* __restrict__ srcs, const int* __restrict__ offs,
  const float* __restrict__ geps, int gi, u16* __restrict__ Z, int N)
{
  int i = blockIdx.x*4 + (threadIdx.x>>6);
  int ln = threadIdx.x & 63;
  int c = ln*2;
  if (i >= N) return;
  float sca = S[c], sha = S[128+c];
  float scb = S[c+1], shb = S[128+c+1];
  float eps1 = 1.0f + geps[gi];
  us2 x0 = *(const us2*)(X + (size_t)i*128 + c);
  float acca = eps1 * fmaxf(fmaf(h2f(x0.x), sca, sha), 0.f);
  float accb = eps1 * fmaxf(fmaf(h2f(x0.y), scb, shb), 0.f);
  int e0 = offs[i], e1 = offs[i+1];
  int e = e0;
  for (; e+4 <= e1; e += 4){
    int s0 = srcs[e], s1 = srcs[e+1], s2 = srcs[e+2], s3 = srcs[e+3];
    us2 v0 = *(const us2*)(X + (size_t)s0*128 + c);
    us2 v1 = *(const us2*)(X + (size_t)s1*128 + c);
    us2 v2 = *(const us2*)(X + (size_t)s2*128 + c);
    us2 v3 = *(const us2*)(X + (size_t)s3*128 + c);
    acca += fmaxf(fmaf(h2f(v0.x), sca, sha), 0.f);
    accb += fmaxf(fmaf(h2f(v0.y), scb, shb), 0.f);
    acca += fmaxf(fmaf(h2f(v1.x), sca, sha), 0.f);
    accb += fmaxf(fmaf(h2f(v1.y), scb, shb), 0.f);
    acca += fmaxf(fmaf(h2f(v2.x), sca, sha), 0.f);
    accb += fmaxf(fmaf(h2f(v2.y), scb, shb), 0.f);
    acca += fmaxf(fmaf(h2f(v3.x), sca, sha), 0.f);
    accb += fmaxf(fmaf(h2f(v3.y), scb, shb), 0.f);
  }
  for (; e < e1; ++e){
    int s = srcs[e];
    us2 xv = *(const us2*)(X + (size_t)s*128 + c);
    acca += fmaxf(fmaf(h2f(xv.x), sca, sha), 0.f);
    accb += fmaxf(fmaf(h2f(xv.y), scb, shb), 0.f);
  }
  us2 o; o.x = f2h(acca); o.y = f2h(accb);
  *(us2*)(Z + (size_t)i*128 + c) = o;
}

// ---------------- Set2Set ----------------
__global__ __launch_bounds__(256) void lstm_step(
  float* __restrict__ q_star, float* __restrict__ h, float* __restrict__ cst,
  const float* __restrict__ Wih, const float* __restrict__ Whh,
  const float* __restrict__ bih, const float* __restrict__ bhh, int G)
{
  __shared__ float q[256], hh[128], z[512];
  int t = threadIdx.x;
  for (int g = blockIdx.x; g < G; g += gridDim.x){
    q[t] = q_star[(size_t)g*256 + t];
    if (t < 128) hh[t] = h[(size_t)g*128 + t];
    __syncthreads();
    #pragma unroll
    for (int p=0;p<2;++p){
      int j = t + 256*p;
      float acc = bih[j] + bhh[j];
      const float* wi = Wih + (size_t)j*256;
      const float* wh = Whh + (size_t)j*128;
      for (int k=0;k<256;++k) acc = fmaf(q[k], wi[k], acc);
      for (int k=0;k<128;++k) acc = fmaf(hh[k], wh[k], acc);
      z[j] = acc;
    }
    __syncthreads();
    if (t < 128){
      float i_ = z[t], f_ = z[128+t], g_ = z[256+t], o_ = z[384+t];
      float cc = sigmoidf_(f_)*cst[(size_t)g*128+t] + sigmoidf_(i_)*tanhf(g_);
      float hn = sigmoidf_(o_)*tanhf(cc);
      cst[(size_t)g*128+t] = cc;
      h[(size_t)g*128+t]  = hn;
      q_star[(size_t)g*256+t] = hn;
    }
    __syncthreads();
  }
}

__global__ __launch_bounds__(256) void dot_h_hf(
  const u16* __restrict__ X, const float* __restrict__ S,
  const float* __restrict__ h, const int* __restrict__ batch,
  float* __restrict__ e, int N)
{
  int wv = threadIdx.x >> 6, ln = threadIdx.x & 63;
  int i = blockIdx.x*4 + wv;
  if (i >= N) return;
  int g = batch[i];
  int c = ln*2;
  us2 x2 = *(const us2*)(X + (size_t)i*128 + c);
  float2 h2 = *(const float2*)(h + (size_t)g*128 + c);
  float xa = fmaxf(fmaf(h2f(x2.x), S[c],   S[128+c]),   0.f);
  float xb = fmaxf(fmaf(h2f(x2.y), S[c+1], S[128+c+1]), 0.f);
  float p = xa*h2.x + xb*h2.y;
  #pragma unroll
  for (int off=32; off; off>>=1) p += __shfl_down(p, off, 64);
  if (ln==0) e[i] = p;
}

__global__ __launch_bounds__(256) void seg_reduce(
  const float* __restrict__ e, const int* __restrict__ goff,
  float* __restrict__ emax, float* __restrict__ invden, int G)
{
  int g = blockIdx.x;
  int lo = goff[g], hi = goff[g+1];
  int t = threadIdx.x;
  __shared__ float red[256];
  float m = -3.4e38f;
  for (int i=lo+t; i<hi; i+=256) m = fmaxf(m, e[i]);
  red[t] = m; __syncthreads();
  for (int d=128; d; d>>=1){ if (t<d) red[t] = fmaxf(red[t], red[t+d]); __syncthreads(); }
  m = red[0]; __syncthreads();
  float s = 0.f;
  for (int i=lo+t; i<hi; i+=256) s += expf(e[i]-m);
  red[t] = s; __syncthreads();
  for (int d=128; d; d>>=1){ if (t<d) red[t] += red[t+d]; __syncthreads(); }
  if (t==0){
    emax[g] = m;
    invden[g] = (hi>lo && red[0]>0.f) ? 1.f/red[0] : 0.f;
  }
}

__global__ __launch_bounds__(128) void r_kernel_hf(
  const u16* __restrict__ X, const float* __restrict__ S,
  const float* __restrict__ e, const int* __restrict__ goff,
  const float* __restrict__ emax, const float* __restrict__ invden,
  float* __restrict__ q_star, int G)
{
  int g = blockIdx.x, c = threadIdx.x;
  int lo = goff[g], hi = goff[g+1];
  float m = emax[g], inv = invden[g];
  float sc = S[c], sh = S[128+c];
  float r = 0.f;
  for (int i=lo; i<hi; ++i){
    float w = expf(e[i]-m);
    r = fmaf(w, fmaxf(fmaf(h2f(X[(size_t)i*128+c]), sc, sh), 0.f), r);
  }
  q_star[(size_t)g*256 + 128 + c] = r*inv;
}

__global__ __launch_bounds__(128) void final_k(
  const float* __restrict__ q_star, const float* __restrict__ fc1W,
  const float* __restrict__ fc1b, const float* __restrict__ fc4W,
  const float* __restrict__ fc4b, float* __restrict__ out, int G)
{
  __shared__ float q[256];
  __shared__ float h1[128];
  int g = blockIdx.x, t = threadIdx.x;
  q[t]     = q_star[(size_t)g*256 + t];
  q[128+t] = q_star[(size_t)g*256 + 128 + t];
  __syncthreads();
  float acc = fc1b[t];
  for (int k=0;k<256;++k) acc = fmaf(q[k], fc1W[(size_t)k*128+t], acc);
  h1[t] = fmaxf(acc, 0.f);
  __syncthreads();
  if (t < 12){
    float o = fc4b[t];
    for (int d=0; d<128; ++d) o = fmaf(h1[d], fc4W[(size_t)d*12+t], o);
    out[(size_t)g*12+t] = o;
  }
}

// ---------------------------------------------------------------------------
extern "C" void kernel_launch(void* const* d_in, const int* in_sizes, int n_in,
                              void* d_out, int out_size, void* d_ws, size_t ws_size,
                              hipStream_t stream)
{
  (void)n_in; (void)ws_size;
  const int N = in_sizes[0] / 3;
  const int E = in_sizes[62] / 2;
  const int G = out_size / 12;

  auto P = [&](int i){ return (const float*)d_in[i]; };
  const float* gb1 = P(38); const float* gg1 = P(39); const float* gbe1 = P(40);
  const float* gb2 = P(42); const float* gg2 = P(43); const float* gbe2 = P(44);
  const float* geps = P(45);
  const float* mb1 = P(47); const float* mg1 = P(48); const float* mbe1 = P(49);
  const float* mb2 = P(51); const float* mg2 = P(52); const float* mbe2 = P(53);
  const int* ei[4] = {(const int*)d_in[62], (const int*)d_in[63],
                      (const int*)d_in[64], (const int*)d_in[65]};
  const int* batch = (const int*)d_in[66];

  const int ggrid = (N + 127)/128;
  const int ENC_GRID = 1024;
  const int NB_MAX = (ggrid > ENC_GRID) ? ggrid : ENC_GRID;

  char* ws = (char*)d_ws;
  size_t off = 0;
  auto alloc = [&](size_t bytes)->char*{
    char* p = ws + off;
    off = (off + bytes + 255) & ~(size_t)255;
    return p;
  };
  u16* X = (u16*)alloc((size_t)N*128*2);              // also the MLP intermediate
  u16* Z[4]; for (int k=0;k<4;++k) Z[k] = (u16*)alloc((size_t)N*128*2);
  float* ebuf  = (float*)alloc((size_t)N*4);
  float* pstats= (float*)alloc((size_t)NB_MAX*256*4); // per-block stat partials
  float* Sb    = (float*)alloc(6*256*4);
  int* offs4 = (int*)alloc((size_t)4*(N+1)*4);
  int* srcs4 = (int*)alloc((size_t)4*E*4);
  int* cnt4  = (int*)alloc((size_t)4*N*4);
  int* goff  = (int*)alloc((size_t)(G+1)*4);
  float* qstar = (float*)alloc((size_t)G*256*4);
  float* hbuf  = (float*)alloc((size_t)G*128*4);
  float* cbuf  = (float*)alloc((size_t)G*128*4);
  float* emax  = (float*)alloc((size_t)G*4);
  float* invden= (float*)alloc((size_t)G*4);
  const size_t WT_ELEMS = 1392640;
  u16* WTh = (u16*)alloc(WT_ELEMS*2);
  u16* WTl = (u16*)alloc(WT_ELEMS*2);

  // W^T plane offsets (elems)
  const size_t oEnc0=0, oEnc1=16384, oEnc2=32768, oM0W1=49152, oM0W2=98304;
  const size_t oGW1=114688, oGW2=507904, oMW1=901120, oMW2=1294336;

  const float invN = 1.0f / (float)N;
  const int ST = 0, SX = 1, SZ0 = 2;
  auto Sl = [&](int i){ return Sb + (size_t)i*256; };

  // ---- weight preprocessing (transpose + bf16 split) ----
  auto prep = [&](const float* src, size_t o, int K, int count){
    int tot = count*K*128;
    split_transpose<<<(tot+255)/256,256,0,stream>>>(src, WTh+o, WTl+o, K, count);
  };
  prep(P(9),  oEnc0, 128, 1);
  prep(P(17), oEnc1, 128, 1);
  prep(P(25), oEnc2, 128, 1);
  prep(P(29), oM0W1, 384, 1);
  prep(P(33), oM0W2, 128, 1);
  prep(P(37), oGW1,  128, 24);
  prep(P(41), oGW2,  128, 24);
  prep(P(46), oMW1,  512, 6);
  prep(P(50), oMW2,  128, 6);

  // ---- CSR build (+ per-node value sort for deterministic sums) ----
  int zgrid = (4*N + 255)/256;
  zero_k<<<zgrid,256,0,stream>>>((float*)cnt4, 4*N);
  int egrid = (E + 255)/256;
  for (int l=0;l<4;++l)
    count_deg<<<egrid,256,0,stream>>>(ei[l]+E, cnt4 + (size_t)l*N, E);
  scan_excl<<<4,1024,0,stream>>>(cnt4, offs4, N);
  zero_k<<<zgrid,256,0,stream>>>((float*)cnt4, 4*N);
  for (int l=0;l<4;++l)
    fill_csr<<<egrid,256,0,stream>>>(ei[l], ei[l]+E, offs4 + (size_t)l*(N+1),
                                     cnt4 + (size_t)l*N, srcs4 + (size_t)l*E, E);
  int ngrid = (N + 255)/256;
  for (int l=0;l<4;++l)
    sort_csr<<<ngrid,256,0,stream>>>(offs4 + (size_t)l*(N+1), srcs4 + (size_t)l*E, N);
  graph_offsets<<<(G+1+255)/256,256,0,stream>>>(batch, goff, N, G);

  auto run_bnfin = [&](int nb, const float* g, const float* be, float* S){
    bnfin_det<<<1,1024,0,stream>>>(pstats, nb, g, be, S, invN);
  };
  auto run_gemm1 = [&](const u16* A, const float* S, size_t wo, const float* b, u16* Cc){
    gemm_rs<<<ggrid,256,0,stream>>>(A,nullptr,nullptr,nullptr, S,nullptr,nullptr,nullptr,
                                    WTh+wo, WTl+wo, b, Cc, pstats, N, 1);
  };

  // ---- encoders (X doubles as the intermediate T) ----
  gemm_enc<<<ENC_GRID,256,0,stream>>>(P(0),3, nullptr,0, P(5), P(6), X, pstats, N);
  run_bnfin(ENC_GRID, P(7), P(8), Sl(ST));
  run_gemm1(X, Sl(ST), oEnc0, P(10), Z[0]);
  run_bnfin(ggrid, P(11), P(12), Sl(SZ0+0));

  gemm_enc<<<ENC_GRID,256,0,stream>>>(P(1),13, P(2),13, P(13), P(14), X, pstats, N);
  run_bnfin(ENC_GRID, P(15), P(16), Sl(ST));
  run_gemm1(X, Sl(ST), oEnc1, P(18), Z[1]);
  run_bnfin(ggrid, P(19), P(20), Sl(SZ0+1));

  gemm_enc<<<ENC_GRID,256,0,stream>>>(P(3),4, P(4),1, P(21), P(22), X, pstats, N);
  run_bnfin(ENC_GRID, P(23), P(24), Sl(ST));
  run_gemm1(X, Sl(ST), oEnc2, P(26), Z[2]);
  run_bnfin(ggrid, P(27), P(28), Sl(SZ0+2));

  // m0: concat [nl, na, ea] = Z0,Z1,Z2  (K=384)
  gemm_rs<<<ggrid,256,0,stream>>>(Z[0],Z[1],Z[2],nullptr,
                                  Sl(SZ0+0),Sl(SZ0+1),Sl(SZ0+2),nullptr,
                                  WTh+oM0W1, WTl+oM0W1, P(30), X, pstats, N, 3);
  run_bnfin(ggrid, P(31), P(32), Sl(ST));
  run_gemm1(X, Sl(ST), oM0W2, P(34), X);        // in-place (row-exclusive)
  run_bnfin(ggrid, P(35), P(36), Sl(SX));

  // ---- 6 GIN layers ----
  int agrid = (N + 3)/4;
  for (int L=0; L<6; ++L){
    for (int k=0;k<4;++k){
      int gi = 4*L + k;
      aggregate_hf<<<agrid,256,0,stream>>>(X, Sl(SX), srcs4 + (size_t)k*E,
                                           offs4 + (size_t)k*(N+1), geps, gi, Z[k], N);
    }
    for (int k=0;k<4;++k){
      int gi = 4*L + k;
      run_gemm1(Z[k], nullptr, oGW1 + (size_t)gi*16384, gb1 + (size_t)gi*128, X);
      run_bnfin(ggrid, gg1 + (size_t)gi*128, gbe1 + (size_t)gi*128, Sl(ST));
      run_gemm1(X, Sl(ST), oGW2 + (size_t)gi*16384, gb2 + (size_t)gi*128, Z[k]);
      run_bnfin(ggrid, gg2 + (size_t)gi*128, gbe2 + (size_t)gi*128, Sl(SZ0+k));
    }
    // fusion: concat [x1, x3, x2, x4] = Z0, Z2, Z1, Z3  (K=512)
    gemm_rs<<<ggrid,256,0,stream>>>(Z[0],Z[2],Z[1],Z[3],
                                    Sl(SZ0+0),Sl(SZ0+2),Sl(SZ0+1),Sl(SZ0+3),
                                    WTh+oMW1+(size_t)L*65536, WTl+oMW1+(size_t)L*65536,
                                    mb1 + (size_t)L*128, X, pstats, N, 4);
    run_bnfin(ggrid, mg1 + (size_t)L*128, mbe1 + (size_t)L*128, Sl(ST));
    run_gemm1(X, Sl(ST), oMW2 + (size_t)L*16384, mb2 + (size_t)L*128, X);  // in-place
    run_bnfin(ggrid, mg2 + (size_t)L*128, mbe2 + (size_t)L*128, Sl(SX));
  }

  // ---- Set2Set (6 steps) ----
  zero_k<<<(G*256+255)/256,256,0,stream>>>(qstar, G*256);
  zero_k<<<(G*128+255)/256,256,0,stream>>>(hbuf, G*128);
  zero_k<<<(G*128+255)/256,256,0,stream>>>(cbuf, G*128);
  int dgrid = (N + 3)/4;
  for (int s=0;s<6;++s){
    lstm_step<<<64,256,0,stream>>>(qstar, hbuf, cbuf, P(54), P(55), P(56), P(57), G);
    dot_h_hf<<<dgrid,256,0,stream>>>(X, Sl(SX), hbuf, batch, ebuf, N);
    seg_reduce<<<G,256,0,stream>>>(ebuf, goff, emax, invden, G);
    r_kernel_hf<<<G,128,0,stream>>>(X, Sl(SX), ebuf, goff, emax, invden, qstar, G);
  }

  final_k<<<G,128,0,stream>>>(qstar, P(58), P(59), P(60), P(61), (float*)d_out, G);
}

// Round 10
// 8695.464 us; speedup vs baseline: 2.3031x; 1.5951x over previous
//
#include <hip/hip_runtime.h>
#include <math.h>

// ---------------------------------------------------------------------------
// NetGIN forward on MI355X — round 10.
// vs R9: (1) two-stage deterministic BN-stats reduce (32-block stage1 + tiny
// stage2) replacing the single-block 800KB bnfin_det; (2) the 4 independent
// GIN convs per stage fused into one dispatch via blockIdx.y (aggregate,
// W1-gemm, W2-gemm; gemms run IN-PLACE on Z[k] — row-exclusive blocks);
// (3) GEMM spill diet: no runtime-indexed pointer/float arrays.
// Numerics unchanged: fp16 activations, BN-on-read, bf16 2-term-split MFMA,
// fixed-order reductions, sorted CSR -> fully deterministic.
// ---------------------------------------------------------------------------

#define DEV_INLINE __device__ __forceinline__
typedef unsigned short u16;

union F16U { _Float16 h; u16 u; };
DEV_INLINE float h2f(u16 v){ F16U t; t.u = v; return (float)t.h; }
DEV_INLINE u16 f2h(float f){ F16U t; t.h = (_Float16)f; return t.u; }
DEV_INLINE float bf2f(u16 h){ return __uint_as_float(((unsigned)h)<<16); }
DEV_INLINE u16 f2bf(float f){
  unsigned u = __float_as_uint(f);
  unsigned r = (u + 0x7FFFu + ((u>>16)&1u)) >> 16;
  return (u16)r;
}
DEV_INLINE float sigmoidf_(float x){ return 1.0f/(1.0f+expf(-x)); }
struct __align__(4) us2 { u16 x, y; };
struct __align__(8) us4 { u16 x, y, z, w; };

typedef __attribute__((ext_vector_type(8))) short s8v;   // 8 bf16/fp16
typedef __attribute__((ext_vector_type(4))) float f4v;   // 4 fp32 acc

// BN+ReLU one fp32 value, split to bf16 hi/lo — all scalar regs.
DEV_INLINE void bnsplit1(float f, u16& hb, u16& lb){
  hb = f2bf(f); lb = f2bf(f - bf2f(hb));
}

// ---------------- utility ----------------
__global__ void zero_k(float* __restrict__ p, int n){
  int i = blockIdx.x*256 + threadIdx.x;
  if (i < n) p[i] = 0.f;
}

// ---------------- weight pre-transpose + bf16 split ----------------
__global__ __launch_bounds__(256) void split_transpose(
  const float* __restrict__ src, u16* __restrict__ dh, u16* __restrict__ dl,
  int K, int count)
{
  int tot = count*K*128;
  for (int i = blockIdx.x*256 + threadIdx.x; i < tot; i += gridDim.x*256){
    int k = i % K;
    int n = (i / K) & 127;
    int c = i / (K*128);
    float w = src[(size_t)c*K*128 + (size_t)k*128 + n];
    u16 hi = f2bf(w);
    u16 lo = f2bf(w - bf2f(hi));
    dh[i] = hi; dl[i] = lo;
  }
}

// ---------------- CSR build ----------------
__global__ void count_deg(const int* __restrict__ dst, int* __restrict__ cnt, int E){
  int e = blockIdx.x*256 + threadIdx.x;
  if (e < E) atomicAdd(&cnt[dst[e]], 1);
}

__global__ void scan_excl(const int* __restrict__ cnt, int* __restrict__ offs, int N){
  const int* c = cnt + (size_t)blockIdx.x * N;
  int* o = offs + (size_t)blockIdx.x * (N+1);
  __shared__ int ps[1024];
  int t = threadIdx.x;
  int chunk = (N + 1023) >> 10;
  int lo = t*chunk, hi = min(lo+chunk, N);
  int s = 0;
  for (int i=lo;i<hi;++i) s += c[i];
  ps[t] = s; __syncthreads();
  for (int d=1; d<1024; d<<=1){
    int v = (t>=d) ? ps[t-d] : 0;
    __syncthreads();
    ps[t] += v;
    __syncthreads();
  }
  int pre = (t==0) ? 0 : ps[t-1];
  for (int i=lo;i<hi;++i){ o[i]=pre; pre += c[i]; }
  if (t==1023) o[N] = ps[1023];
}

__global__ void fill_csr(const int* __restrict__ src, const int* __restrict__ dst,
                         const int* __restrict__ offs, int* __restrict__ cur,
                         int* __restrict__ out, int E){
  int e = blockIdx.x*256 + threadIdx.x;
  if (e >= E) return;
  int d = dst[e];
  int pos = offs[d] + atomicAdd(&cur[d], 1);
  out[pos] = src[e];
}

__global__ void sort_csr(const int* __restrict__ offs, int* __restrict__ srcs, int N){
  int i = blockIdx.x*256 + threadIdx.x;
  if (i >= N) return;
  int lo = offs[i], hi = offs[i+1];
  for (int a = lo+1; a < hi; ++a){
    int v = srcs[a];
    int b = a-1;
    while (b >= lo && srcs[b] > v){ srcs[b+1] = srcs[b]; --b; }
    srcs[b+1] = v;
  }
}

__global__ void graph_offsets(const int* __restrict__ batch, int* __restrict__ goff, int N, int G){
  int g = blockIdx.x*blockDim.x + threadIdx.x;
  if (g > G) return;
  int lo=0, hi=N;
  while (lo<hi){ int mid=(lo+hi)>>1; if (batch[mid] < g) lo=mid+1; else hi=mid; }
  goff[g]=lo;
}

// ---------------- two-stage deterministic BN stats ----------------
// stage1: grid (32, nbank). pstats bank layout [bank][PB][256].
__global__ __launch_bounds__(256) void stats_reduce1(
  const float* __restrict__ pstats, int PB, float* __restrict__ out2, int nb)
{
  int c = threadIdx.x, grp = blockIdx.x, bank = blockIdx.y;
  int chunk = (nb + 31) >> 5;
  int b0 = grp*chunk, b1 = min(b0+chunk, nb);
  const float* base = pstats + (size_t)bank*PB*256;
  float s = 0.f;
  for (int b=b0; b<b1; ++b) s += base[(size_t)b*256 + c];
  out2[((size_t)bank*32 + grp)*256 + c] = s;
}
// stage2: grid (nbank), 256 thr. g/be stride 128 per bank; S stride 256.
__global__ __launch_bounds__(256) void bnfin2(
  const float* __restrict__ out2, const float* __restrict__ g,
  const float* __restrict__ be, float* __restrict__ Sb, float invN)
{
  __shared__ float tot[256];
  int t = threadIdx.x, bank = blockIdx.x;
  const float* src = out2 + (size_t)bank*32*256;
  float s = 0.f;
  #pragma unroll
  for (int j=0;j<32;++j) s += src[j*256 + t];   // fixed order
  tot[t] = s; __syncthreads();
  if (t < 128){
    float m = tot[t]*invN;
    float v = tot[128+t]*invN - m*m;
    float sc = g[bank*128 + t]*rsqrtf(v + 1e-5f);
    Sb[bank*256 + t] = sc;
    Sb[bank*256 + 128 + t] = be[bank*128 + t] - m*sc;
  }
}

// ======== GEMM core macros (shared by gemm_rs and gemm_gin) ========
// Per-(part,ks) body: X load+bn+split (scalar regs), W frags, 3 MFMAs.
#define GEMM_KS_BODY(A_, S_, WHp_, WLp_, Kel_)                                \
  {                                                                           \
    float4 sa0, sa1, sb0, sb1;                                                \
    if (S_){                                                                  \
      sa0 = *(const float4*)(S_ + koff);                                      \
      sa1 = *(const float4*)(S_ + koff + 4);                                  \
      sb0 = *(const float4*)(S_ + 128 + koff);                                \
      sb1 = *(const float4*)(S_ + 128 + koff + 4);                            \
    }                                                                         \
    s8v xh0, xl0, xh1, xl1;                                                   \
    _Pragma("unroll")                                                         \
    for (int mt=0; mt<2; ++mt){                                               \
      int row = wrow0 + mt*16 + m16;                                          \
      s8v xr = (row < N) ? *(const s8v*)(A_ + (size_t)row*128 + koff)         \
                         : (s8v){0,0,0,0,0,0,0,0};                            \
      float f0 = h2f((u16)xr[0]), f1 = h2f((u16)xr[1]);                       \
      float f2 = h2f((u16)xr[2]), f3 = h2f((u16)xr[3]);                       \
      float f4 = h2f((u16)xr[4]), f5 = h2f((u16)xr[5]);                       \
      float f6 = h2f((u16)xr[6]), f7 = h2f((u16)xr[7]);                       \
      if (S_){                                                                \
        f0 = fmaxf(fmaf(f0, sa0.x, sb0.x), 0.f);                              \
        f1 = fmaxf(fmaf(f1, sa0.y, sb0.y), 0.f);                              \
        f2 = fmaxf(fmaf(f2, sa0.z, sb0.z), 0.f);                              \
        f3 = fmaxf(fmaf(f3, sa0.w, sb0.w), 0.f);                              \
        f4 = fmaxf(fmaf(f4, sa1.x, sb1.x), 0.f);                              \
        f5 = fmaxf(fmaf(f5, sa1.y, sb1.y), 0.f);                              \
        f6 = fmaxf(fmaf(f6, sa1.z, sb1.z), 0.f);                              \
        f7 = fmaxf(fmaf(f7, sa1.w, sb1.w), 0.f);                              \
      }                                                                       \
      s8v h, l; u16 hb, lb;                                                   \
      bnsplit1(f0,hb,lb); h[0]=(short)hb; l[0]=(short)lb;                     \
      bnsplit1(f1,hb,lb); h[1]=(short)hb; l[1]=(short)lb;                     \
      bnsplit1(f2,hb,lb); h[2]=(short)hb; l[2]=(short)lb;                     \
      bnsplit1(f3,hb,lb); h[3]=(short)hb; l[3]=(short)lb;                     \
      bnsplit1(f4,hb,lb); h[4]=(short)hb; l[4]=(short)lb;                     \
      bnsplit1(f5,hb,lb); h[5]=(short)hb; l[5]=(short)lb;                     \
      bnsplit1(f6,hb,lb); h[6]=(short)hb; l[6]=(short)lb;                     \
      bnsplit1(f7,hb,lb); h[7]=(short)hb; l[7]=(short)lb;                     \
      if (mt==0){ xh0=h; xl0=l; } else { xh1=h; xl1=l; }                      \
    }                                                                         \
    _Pragma("unroll")                                                         \
    for (int nh=0; nh<2; ++nh){                                               \
      s8v wh0, wl0, wh1, wl1, wh2, wl2, wh3, wl3;                             \
      {                                                                       \
        int n = (nh*4+0)*16 + m16; size_t wa = (size_t)n*Kel_ + koff;         \
        wh0 = *(const s8v*)(WHp_ + wa); wl0 = *(const s8v*)(WLp_ + wa);       \
        n = (nh*4+1)*16 + m16; wa = (size_t)n*Kel_ + koff;                    \
        wh1 = *(const s8v*)(WHp_ + wa); wl1 = *(const s8v*)(WLp_ + wa);       \
        n = (nh*4+2)*16 + m16; wa = (size_t)n*Kel_ + koff;                    \
        wh2 = *(const s8v*)(WHp_ + wa); wl2 = *(const s8v*)(WLp_ + wa);       \
        n = (nh*4+3)*16 + m16; wa = (size_t)n*Kel_ + koff;                    \
        wh3 = *(const s8v*)(WHp_ + wa); wl3 = *(const s8v*)(WLp_ + wa);       \
      }                                                                       \
      _Pragma("unroll")                                                       \
      for (int mt=0;mt<2;++mt){                                               \
        s8v xh_ = mt ? xh1 : xh0;                                             \
        s8v xl_ = mt ? xl1 : xl0;                                             \
        acc[mt][nh*4+0] = __builtin_amdgcn_mfma_f32_16x16x32_bf16(wh0, xh_, acc[mt][nh*4+0], 0,0,0); \
        acc[mt][nh*4+0] = __builtin_amdgcn_mfma_f32_16x16x32_bf16(wl0, xh_, acc[mt][nh*4+0], 0,0,0); \
        acc[mt][nh*4+0] = __builtin_amdgcn_mfma_f32_16x16x32_bf16(wh0, xl_, acc[mt][nh*4+0], 0,0,0); \
        acc[mt][nh*4+1] = __builtin_amdgcn_mfma_f32_16x16x32_bf16(wh1, xh_, acc[mt][nh*4+1], 0,0,0); \
        acc[mt][nh*4+1] = __builtin_amdgcn_mfma_f32_16x16x32_bf16(wl1, xh_, acc[mt][nh*4+1], 0,0,0); \
        acc[mt][nh*4+1] = __builtin_amdgcn_mfma_f32_16x16x32_bf16(wh1, xl_, acc[mt][nh*4+1], 0,0,0); \
        acc[mt][nh*4+2] = __builtin_amdgcn_mfma_f32_16x16x32_bf16(wh2, xh_, acc[mt][nh*4+2], 0,0,0); \
        acc[mt][nh*4+2] = __builtin_amdgcn_mfma_f32_16x16x32_bf16(wl2, xh_, acc[mt][nh*4+2], 0,0,0); \
        acc[mt][nh*4+2] = __builtin_amdgcn_mfma_f32_16x16x32_bf16(wh2, xl_, acc[mt][nh*4+2], 0,0,0); \
        acc[mt][nh*4+3] = __builtin_amdgcn_mfma_f32_16x16x32_bf16(wh3, xh_, acc[mt][nh*4+3], 0,0,0); \
        acc[mt][nh*4+3] = __builtin_amdgcn_mfma_f32_16x16x32_bf16(wl3, xh_, acc[mt][nh*4+3], 0,0,0); \
        acc[mt][nh*4+3] = __builtin_amdgcn_mfma_f32_16x16x32_bf16(wh3, xl_, acc[mt][nh*4+3], 0,0,0); \
      }                                                                       \
    }                                                                         \
  }

// Epilogue: +bias, fp16 round, cst, deterministic per-block stats, C store.
#define GEMM_EPILOGUE(C_, bias_, pslot_)                                      \
  {                                                                           \
    _Pragma("unroll")                                                         \
    for (int nt=0;nt<8;++nt){                                                 \
      int n0 = nt*16 + kg*4;                                                  \
      float4 b4 = *(const float4*)(bias_ + n0);                               \
      float s1a=0.f,s1b=0.f,s1c=0.f,s1d=0.f;                                  \
      float s2a=0.f,s2b=0.f,s2c=0.f,s2d=0.f;                                  \
      _Pragma("unroll")                                                       \
      for (int mt=0;mt<2;++mt){                                               \
        int row = wrow0 + mt*16 + m16;                                        \
        us4 o;                                                                \
        o.x = f2h(acc[mt][nt][0] + b4.x);                                     \
        o.y = f2h(acc[mt][nt][1] + b4.y);                                     \
        o.z = f2h(acc[mt][nt][2] + b4.z);                                     \
        o.w = f2h(acc[mt][nt][3] + b4.w);                                     \
        *(us4*)(&cst[wid][mt][m16*136 + n0]) = o;                             \
        if (row < N){                                                         \
          float r0=h2f(o.x), r1=h2f(o.y), r2=h2f(o.z), r3=h2f(o.w);           \
          s1a+=r0; s1b+=r1; s1c+=r2; s1d+=r3;                                 \
          s2a+=r0*r0; s2b+=r1*r1; s2c+=r2*r2; s2d+=r3*r3;                     \
        }                                                                     \
      }                                                                       \
      _Pragma("unroll")                                                       \
      for (int off=1; off<16; off<<=1){                                       \
        s1a += __shfl_xor(s1a, off, 64); s1b += __shfl_xor(s1b, off, 64);     \
        s1c += __shfl_xor(s1c, off, 64); s1d += __shfl_xor(s1d, off, 64);     \
        s2a += __shfl_xor(s2a, off, 64); s2b += __shfl_xor(s2b, off, 64);     \
        s2c += __shfl_xor(s2c, off, 64); s2d += __shfl_xor(s2d, off, 64);     \
      }                                                                       \
      if (m16 == 0){                                                          \
        pw[wid][n0+0] = s1a; pw[wid][n0+1] = s1b;                             \
        pw[wid][n0+2] = s1c; pw[wid][n0+3] = s1d;                             \
        pw[wid][128+n0+0] = s2a; pw[wid][128+n0+1] = s2b;                     \
        pw[wid][128+n0+2] = s2c; pw[wid][128+n0+3] = s2d;                     \
      }                                                                       \
    }                                                                         \
    __syncthreads();                                                          \
    if (t < 256){                                                             \
      float tot = ((pw[0][t] + pw[1][t]) + pw[2][t]) + pw[3][t];              \
      (pslot_)[t] = tot;                                                      \
    }                                                                         \
    _Pragma("unroll")                                                         \
    for (int mt=0;mt<2;++mt){                                                 \
      _Pragma("unroll")                                                       \
      for (int it=0; it<4; ++it){                                             \
        int idx = it*64 + lane;                                               \
        int r = idx >> 4;                                                     \
        int c8 = (idx & 15) * 8;                                              \
        int row = wrow0 + mt*16 + r;                                          \
        if (row < N){                                                         \
          s8v v = *(const s8v*)(&cst[wid][mt][r*136 + c8]);                   \
          *(s8v*)(C_ + (size_t)row*128 + c8) = v;                             \
        }                                                                     \
      }                                                                       \
    }                                                                         \
  }

// ---------------- general streaming MFMA GEMM (bank 0) ----------------
__global__ __launch_bounds__(256, 3) void gemm_rs(
  const u16* __restrict__ A0, const u16* __restrict__ A1,
  const u16* __restrict__ A2, const u16* __restrict__ A3,
  const float* __restrict__ S0, const float* __restrict__ S1,
  const float* __restrict__ S2, const float* __restrict__ S3,
  const u16* __restrict__ wt_hi, const u16* __restrict__ wt_lo,
  const float* __restrict__ bias,
  u16* __restrict__ C, float* __restrict__ pstats,
  int N, int npart)
{
  __shared__ u16 cst[4][2][16*136];
  __shared__ float pw[4][256];
  const int t = threadIdx.x;
  const int lane = t & 63;
  const int wid = t >> 6;
  const int m16 = lane & 15;
  const int kg = lane >> 4;
  const int wrow0 = blockIdx.x*128 + wid*32;
  const int K = npart << 7;

  f4v acc[2][8];
  #pragma unroll
  for (int i=0;i<2;++i)
    #pragma unroll
    for (int j=0;j<8;++j) acc[i][j] = (f4v){0.f,0.f,0.f,0.f};

  for (int part=0; part<npart; ++part){
    const u16* A = (part==0)?A0:(part==1)?A1:(part==2)?A2:A3;
    const float* S = (part==0)?S0:(part==1)?S1:(part==2)?S2:S3;
    const u16* WHp = wt_hi + part*128;
    const u16* WLp = wt_lo + part*128;
    #pragma unroll
    for (int ks=0; ks<4; ++ks){
      int koff = ks*32 + kg*8;
      GEMM_KS_BODY(A, S, WHp, WLp, K)
    }
  }
  GEMM_EPILOGUE(C, bias, (pstats + (size_t)blockIdx.x*256))
}

// ---------------- fused 4-conv GIN GEMM (blockIdx.y = conv, K=128, in-place)
__global__ __launch_bounds__(256, 3) void gemm_gin(
  u16* __restrict__ Z0, u16* __restrict__ Z1,
  u16* __restrict__ Z2, u16* __restrict__ Z3,
  const float* __restrict__ Sbase,          // null => raw; else + k*256
  const u16* __restrict__ wt_hi, const u16* __restrict__ wt_lo, // + k*16384
  const float* __restrict__ bias,           // + k*128
  float* __restrict__ pstats, int PB,       // bank k at + k*PB*256
  int N)
{
  __shared__ u16 cst[4][2][16*136];
  __shared__ float pw[4][256];
  const int t = threadIdx.x;
  const int lane = t & 63;
  const int wid = t >> 6;
  const int m16 = lane & 15;
  const int kg = lane >> 6 ? 0 : (lane >> 4);  // dummy to keep pattern; fixed below
  (void)kg;
  const int kgr = lane >> 4;
  const int wrow0 = blockIdx.x*128 + wid*32;
  const int kb = blockIdx.y;

  u16* Zc = (kb==0)?Z0:(kb==1)?Z1:(kb==2)?Z2:Z3;
  const float* S = Sbase ? (Sbase + (size_t)kb*256) : nullptr;
  const u16* WHp = wt_hi + (size_t)kb*16384;
  const u16* WLp = wt_lo + (size_t)kb*16384;
  const float* biasp = bias + (size_t)kb*128;
  float* pslot = pstats + ((size_t)kb*PB + blockIdx.x)*256;

  f4v acc[2][8];
  #pragma unroll
  for (int i=0;i<2;++i)
    #pragma unroll
    for (int j=0;j<8;++j) acc[i][j] = (f4v){0.f,0.f,0.f,0.f};

  {
    const u16* A = Zc;
    #pragma unroll
    for (int ks=0; ks<4; ++ks){
      int koff = ks*32 + kgr*8;
      GEMM_KS_BODY(A, S, WHp, WLp, 128)
    }
  }
  {
    const int kg = kgr;
    GEMM_EPILOGUE(Zc, biasp, pslot)
  }
}

// ---------------- small-K encoder GEMM (fp32 inputs, K <= 26) ----------------
__global__ __launch_bounds__(256) void gemm_enc(
  const float* __restrict__ X0, int w0, const float* __restrict__ X1, int w1,
  const float* __restrict__ W, const float* __restrict__ bias,
  u16* __restrict__ C, float* __restrict__ pstats, int N)
{
  __shared__ float Ws[26*128];
  __shared__ float red[256];
  int K = w0 + w1;
  int t = threadIdx.x;
  for (int i=t;i<K*128;i+=256) Ws[i] = W[i];
  __syncthreads();
  int c = t & 127, rh = t >> 7;
  float b = bias[c];
  float s1=0.f, s2=0.f;
  for (int r0 = blockIdx.x*2; r0 < N; r0 += gridDim.x*2){
    int r = r0 + rh;
    if (r < N){
      float acc = b;
      for (int k=0;k<w0;++k) acc = fmaf(X0[(size_t)r*w0+k], Ws[k*128+c], acc);
      for (int k=0;k<w1;++k) acc = fmaf(X1[(size_t)r*w1+k], Ws[(w0+k)*128+c], acc);
      u16 o = f2h(acc);
      C[(size_t)r*128+c] = o;
      float rv = h2f(o);
      s1 += rv; s2 += rv*rv;
    }
  }
  red[t] = s1; __syncthreads();
  float t1 = (t < 128) ? (red[t] + red[t+128]) : 0.f;
  __syncthreads();
  red[t] = s2; __syncthreads();
  float t2 = (t < 128) ? (red[t] + red[t+128]) : 0.f;
  if (t < 128){
    pstats[(size_t)blockIdx.x*256 + t] = t1;
    pstats[(size_t)blockIdx.x*256 + 128 + t] = t2;
  }
}

// ---------------- fused GIN aggregation (blockIdx.y = conv) ----------------
__global__ __launch_bounds__(256) void aggregate4(
  const u16* __restrict__ X, const float* __restrict__ S,
  const int* __restrict__ srcs4, const int* __restrict__ offs4,
  int E, int Np1, const float* __restrict__ geps, int gi0,
  u16* __restrict__ Z0, u16* __restrict__ Z1,
  u16* __restrict__ Z2, u16* __restrict__ Z3, int N)
{
  int kb = blockIdx.y;
  const int* srcs = srcs4 + (size_t)kb*E;
  const int* offs = offs4 + (size_t)kb*Np1;
  u16* Z = (kb==0)?Z0:(kb==1)?Z1:(kb==2)?Z2:Z3;
  int i = blockIdx.x*4 + (threadIdx.x>>6);
  int ln = threadIdx.x & 63;
  int c = ln*2;
  if (i >= N) return;
  float sca = S[c], sha = S[128+c];
  float scb = S[c+1], shb = S[128+c+1];
  float eps1 = 1.0f + geps[gi0 + kb];
  us2 x0 = *(const us2*)(X + (size_t)i*128 + c);
  float acca = eps1 * fmaxf(fmaf(h2f(x0.x), sca, sha), 0.f);
  float accb = eps1 * fmaxf(fmaf(h2f(x0.y), scb, shb), 0.f);
  int e0 = offs[i], e1 = offs[i+1];
  int e = e0;
  for (; e+4 <= e1; e += 4){
    int s0 = srcs[e], s1 = srcs[e+1], s2 = srcs[e+2], s3 = srcs[e+3];
    us2 v0 = *(const us2*)(X + (size_t)s0*128 + c);
    us2 v1 = *(const us2*)(X + (size_t)s1*128 + c);
    us2 v2 = *(const us2*)(X + (size_t)s2*128 + c);
    us2 v3 = *(const us2*)(X + (size_t)s3*128 + c);
    acca += fmaxf(fmaf(h2f(v0.x), sca, sha), 0.f);
    accb += fmaxf(fmaf(h2f(v0.y), scb, shb), 0.f);
    acca += fmaxf(fmaf(h2f(v1.x), sca, sha), 0.f);
    accb += fmaxf(fmaf(h2f(v1.y), scb, shb), 0.f);
    acca += fmaxf(fmaf(h2f(v2.x), sca, sha), 0.f);
    accb += fmaxf(fmaf(h2f(v2.y), scb, shb), 0.f);
    acca += fmaxf(fmaf(h2f(v3.x), sca, sha), 0.f);
    accb += fmaxf(fmaf(h2f(v3.y), scb, shb), 0.f);
  }
  for (; e < e1; ++e){
    int s = srcs[e];
    us2 xv = *(const us2*)(X + (size_t)s*128 + c);
    acca += fmaxf(fmaf(h2f(xv.x), sca, sha), 0.f);
    accb += fmaxf(fmaf(h2f(xv.y), scb, shb), 0.f);
  }
  us2 o; o.x = f2h(acca); o.y = f2h(accb);
  *(us2*)(Z + (size_t)i*128 + c) = o;
}

// ---------------- Set2Set ----------------
__global__ __launch_bounds__(256) void lstm_step(
  float* __restrict__ q_star, float* __restrict__ h, float* __restrict__ cst,
  const float* __restrict__ Wih, const float* __restrict__ Whh,
  const float* __restrict__ bih, const float* __restrict__ bhh, int G)
{
  __shared__ float q[256], hh[128], z[512];
  int t = threadIdx.x;
  for (int g = blockIdx.x; g < G; g += gridDim.x){
    q[t] = q_star[(size_t)g*256 + t];
    if (t < 128) hh[t] = h[(size_t)g*128 + t];
    __syncthreads();
    #pragma unroll
    for (int p=0;p<2;++p){
      int j = t + 256*p;
      float acc = bih[j] + bhh[j];
      const float* wi = Wih + (size_t)j*256;
      const float* wh = Whh + (size_t)j*128;
      for (int k=0;k<256;++k) acc = fmaf(q[k], wi[k], acc);
      for (int k=0;k<128;++k) acc = fmaf(hh[k], wh[k], acc);
      z[j] = acc;
    }
    __syncthreads();
    if (t < 128){
      float i_ = z[t], f_ = z[128+t], g_ = z[256+t], o_ = z[384+t];
      float cc = sigmoidf_(f_)*cst[(size_t)g*128+t] + sigmoidf_(i_)*tanhf(g_);
      float hn = sigmoidf_(o_)*tanhf(cc);
      cst[(size_t)g*128+t] = cc;
      h[(size_t)g*128+t]  = hn;
      q_star[(size_t)g*256+t] = hn;
    }
    __syncthreads();
  }
}

__global__ __launch_bounds__(256) void dot_h_hf(
  const u16* __restrict__ X, const float* __restrict__ S,
  const float* __restrict__ h, const int* __restrict__ batch,
  float* __restrict__ e, int N)
{
  int wv = threadIdx.x >> 6, ln = threadIdx.x & 63;
  int i = blockIdx.x*4 + wv;
  if (i >= N) return;
  int g = batch[i];
  int c = ln*2;
  us2 x2 = *(const us2*)(X + (size_t)i*128 + c);
  float2 h2 = *(const float2*)(h + (size_t)g*128 + c);
  float xa = fmaxf(fmaf(h2f(x2.x), S[c],   S[128+c]),   0.f);
  float xb = fmaxf(fmaf(h2f(x2.y), S[c+1], S[128+c+1]), 0.f);
  float p = xa*h2.x + xb*h2.y;
  #pragma unroll
  for (int off=32; off; off>>=1) p += __shfl_down(p, off, 64);
  if (ln==0) e[i] = p;
}

__global__ __launch_bounds__(256) void seg_reduce(
  const float* __restrict__ e, const int* __restrict__ goff,
  float* __restrict__ emax, float* __restrict__ invden, int G)
{
  int g = blockIdx.x;
  int lo = goff[g], hi = goff[g+1];
  int t = threadIdx.x;
  __shared__ float red[256];
  float m = -3.4e38f;
  for (int i=lo+t; i<hi; i+=256) m = fmaxf(m, e[i]);
  red[t] = m; __syncthreads();
  for (int d=128; d; d>>=1){ if (t<d) red[t] = fmaxf(red[t], red[t+d]); __syncthreads(); }
  m = red[0]; __syncthreads();
  float s = 0.f;
  for (int i=lo+t; i<hi; i+=256) s += expf(e[i]-m);
  red[t] = s; __syncthreads();
  for (int d=128; d; d>>=1){ if (t<d) red[t] += red[t+d]; __syncthreads(); }
  if (t==0){
    emax[g] = m;
    invden[g] = (hi>lo && red[0]>0.f) ? 1.f/red[0] : 0.f;
  }
}

__global__ __launch_bounds__(128) void r_kernel_hf(
  const u16* __restrict__ X, const float* __restrict__ S,
  const float* __restrict__ e, const int* __restrict__ goff,
  const float* __restrict__ emax, const float* __restrict__ invden,
  float* __restrict__ q_star, int G)
{
  int g = blockIdx.x, c = threadIdx.x;
  int lo = goff[g], hi = goff[g+1];
  float m = emax[g], inv = invden[g];
  float sc = S[c], sh = S[128+c];
  float r = 0.f;
  for (int i=lo; i<hi; ++i){
    float w = expf(e[i]-m);
    r = fmaf(w, fmaxf(fmaf(h2f(X[(size_t)i*128+c]), sc, sh), 0.f), r);
  }
  q_star[(size_t)g*256 + 128 + c] = r*inv;
}

__global__ __launch_bounds__(128) void final_k(
  const float* __restrict__ q_star, const float* __restrict__ fc1W,
  const float* __restrict__ fc1b, const float* __restrict__ fc4W,
  const float* __restrict__ fc4b, float* __restrict__ out, int G)
{
  __shared__ float q[256];
  __shared__ float h1[128];
  int g = blockIdx.x, t = threadIdx.x;
  q[t]     = q_star[(size_t)g*256 + t];
  q[128+t] = q_star[(size_t)g*256 + 128 + t];
  __syncthreads();
  float acc = fc1b[t];
  for (int k=0;k<256;++k) acc = fmaf(q[k], fc1W[(size_t)k*128+t], acc);
  h1[t] = fmaxf(acc, 0.f);
  __syncthreads();
  if (t < 12){
    float o = fc4b[t];
    for (int d=0; d<128; ++d) o = fmaf(h1[d], fc4W[(size_t)d*12+t], o);
    out[(size_t)g*12+t] = o;
  }
}

// ---------------------------------------------------------------------------
extern "C" void kernel_launch(void* const* d_in, const int* in_sizes, int n_in,
                              void* d_out, int out_size, void* d_ws, size_t ws_size,
                              hipStream_t stream)
{
  (void)n_in; (void)ws_size;
  const int N = in_sizes[0] / 3;
  const int E = in_sizes[62] / 2;
  const int G = out_size / 12;

  auto P = [&](int i){ return (const float*)d_in[i]; };
  const float* gb1 = P(38); const float* gg1 = P(39); const float* gbe1 = P(40);
  const float* gb2 = P(42); const float* gg2 = P(43); const float* gbe2 = P(44);
  const float* geps = P(45);
  const float* mb1 = P(47); const float* mg1 = P(48); const float* mbe1 = P(49);
  const float* mb2 = P(51); const float* mg2 = P(52); const float* mbe2 = P(53);
  const int* ei[4] = {(const int*)d_in[62], (const int*)d_in[63],
                      (const int*)d_in[64], (const int*)d_in[65]};
  const int* batch = (const int*)d_in[66];

  const int ggrid = (N + 127)/128;
  const int ENC_GRID = 1024;
  const int PB = (ggrid > ENC_GRID) ? ggrid : ENC_GRID;  // partials per bank

  char* ws = (char*)d_ws;
  size_t off = 0;
  auto alloc = [&](size_t bytes)->char*{
    char* p = ws + off;
    off = (off + bytes + 255) & ~(size_t)255;
    return p;
  };
  u16* X = (u16*)alloc((size_t)N*128*2);
  u16* Z[4]; for (int k=0;k<4;++k) Z[k] = (u16*)alloc((size_t)N*128*2);
  float* ebuf  = (float*)alloc((size_t)N*4);
  float* pstats= (float*)alloc((size_t)4*PB*256*4);  // 4 banks
  float* out2  = (float*)alloc((size_t)4*32*256*4);
  float* Sb    = (float*)alloc(9*256*4);   // 0-3: temps, 4: SX, 5-8: SZ0-3
  int* offs4 = (int*)alloc((size_t)4*(N+1)*4);
  int* srcs4 = (int*)alloc((size_t)4*E*4);
  int* cnt4  = (int*)alloc((size_t)4*N*4);
  int* goff  = (int*)alloc((size_t)(G+1)*4);
  float* qstar = (float*)alloc((size_t)G*256*4);
  float* hbuf  = (float*)alloc((size_t)G*128*4);
  float* cbuf  = (float*)alloc((size_t)G*128*4);
  float* emax  = (float*)alloc((size_t)G*4);
  float* invden= (float*)alloc((size_t)G*4);
  const size_t WT_ELEMS = 1392640;
  u16* WTh = (u16*)alloc(WT_ELEMS*2);
  u16* WTl = (u16*)alloc(WT_ELEMS*2);

  const size_t oEnc0=0, oEnc1=16384, oEnc2=32768, oM0W1=49152, oM0W2=98304;
  const size_t oGW1=114688, oGW2=507904, oMW1=901120, oMW2=1294336;

  const float invN = 1.0f / (float)N;
  const int SX = 4, SZ0 = 5;
  auto Sl = [&](int i){ return Sb + (size_t)i*256; };

  auto prep = [&](const float* src, size_t o, int K, int count){
    int tot = count*K*128;
    split_transpose<<<(tot+255)/256,256,0,stream>>>(src, WTh+o, WTl+o, K, count);
  };
  prep(P(9),  oEnc0, 128, 1);
  prep(P(17), oEnc1, 128, 1);
  prep(P(25), oEnc2, 128, 1);
  prep(P(29), oM0W1, 384, 1);
  prep(P(33), oM0W2, 128, 1);
  prep(P(37), oGW1,  128, 24);
  prep(P(41), oGW2,  128, 24);
  prep(P(46), oMW1,  512, 6);
  prep(P(50), oMW2,  128, 6);

  // ---- CSR build (+ per-node value sort for deterministic sums) ----
  int zgrid = (4*N + 255)/256;
  zero_k<<<zgrid,256,0,stream>>>((float*)cnt4, 4*N);
  int egrid = (E + 255)/256;
  for (int l=0;l<4;++l)
    count_deg<<<egrid,256,0,stream>>>(ei[l]+E, cnt4 + (size_t)l*N, E);
  scan_excl<<<4,1024,0,stream>>>(cnt4, offs4, N);
  zero_k<<<zgrid,256,0,stream>>>((float*)cnt4, 4*N);
  for (int l=0;l<4;++l)
    fill_csr<<<egrid,256,0,stream>>>(ei[l], ei[l]+E, offs4 + (size_t)l*(N+1),
                                     cnt4 + (size_t)l*N, srcs4 + (size_t)l*E, E);
  int ngrid = (N + 255)/256;
  for (int l=0;l<4;++l)
    sort_csr<<<ngrid,256,0,stream>>>(offs4 + (size_t)l*(N+1), srcs4 + (size_t)l*E, N);
  graph_offsets<<<(G+1+255)/256,256,0,stream>>>(batch, goff, N, G);

  auto run_bn = [&](int nbank, int nb, const float* g, const float* be, float* Sbase){
    stats_reduce1<<<dim3(32,nbank),256,0,stream>>>(pstats, PB, out2, nb);
    bnfin2<<<nbank,256,0,stream>>>(out2, g, be, Sbase, invN);
  };
  auto run_gemm1 = [&](const u16* A, const float* S, size_t wo, const float* b, u16* Cc){
    gemm_rs<<<ggrid,256,0,stream>>>(A,nullptr,nullptr,nullptr, S,nullptr,nullptr,nullptr,
                                    WTh+wo, WTl+wo, b, Cc, pstats, N, 1);
  };

  // ---- encoders (X doubles as the intermediate T) ----
  gemm_enc<<<ENC_GRID,256,0,stream>>>(P(0),3, nullptr,0, P(5), P(6), X, pstats, N);
  run_bn(1, ENC_GRID, P(7), P(8), Sl(0));
  run_gemm1(X, Sl(0), oEnc0, P(10), Z[0]);
  run_bn(1, ggrid, P(11), P(12), Sl(SZ0+0));

  gemm_enc<<<ENC_GRID,256,0,stream>>>(P(1),13, P(2),13, P(13), P(14), X, pstats, N);
  run_bn(1, ENC_GRID, P(15), P(16), Sl(0));
  run_gemm1(X, Sl(0), oEnc1, P(18), Z[1]);
  run_bn(1, ggrid, P(19), P(20), Sl(SZ0+1));

  gemm_enc<<<ENC_GRID,256,0,stream>>>(P(3),4, P(4),1, P(21), P(22), X, pstats, N);
  run_bn(1, ENC_GRID, P(23), P(24), Sl(0));
  run_gemm1(X, Sl(0), oEnc2, P(26), Z[2]);
  run_bn(1, ggrid, P(27), P(28), Sl(SZ0+2));

  // m0: concat [nl, na, ea] = Z0,Z1,Z2  (K=384)
  gemm_rs<<<ggrid,256,0,stream>>>(Z[0],Z[1],Z[2],nullptr,
                                  Sl(SZ0+0),Sl(SZ0+1),Sl(SZ0+2),nullptr,
                                  WTh+oM0W1, WTl+oM0W1, P(30), X, pstats, N, 3);
  run_bn(1, ggrid, P(31), P(32), Sl(0));
  run_gemm1(X, Sl(0), oM0W2, P(34), X);
  run_bn(1, ggrid, P(35), P(36), Sl(SX));

  // ---- 6 GIN layers (4 convs fused via blockIdx.y) ----
  int agrid = (N + 3)/4;
  for (int L=0; L<6; ++L){
    aggregate4<<<dim3(agrid,4),256,0,stream>>>(X, Sl(SX), srcs4, offs4, E, N+1,
                                               geps, 4*L, Z[0],Z[1],Z[2],Z[3], N);
    // W1 (raw input), in-place Z[k] -> Z[k]
    gemm_gin<<<dim3(ggrid,4),256,0,stream>>>(Z[0],Z[1],Z[2],Z[3], nullptr,
                                             WTh+oGW1+(size_t)4*L*16384,
                                             WTl+oGW1+(size_t)4*L*16384,
                                             gb1 + (size_t)4*L*128, pstats, PB, N);
    run_bn(4, ggrid, gg1 + (size_t)4*L*128, gbe1 + (size_t)4*L*128, Sl(0));
    // W2 (bn-relu input), in-place
    gemm_gin<<<dim3(ggrid,4),256,0,stream>>>(Z[0],Z[1],Z[2],Z[3], Sl(0),
                                             WTh+oGW2+(size_t)4*L*16384,
                                             WTl+oGW2+(size_t)4*L*16384,
                                             gb2 + (size_t)4*L*128, pstats, PB, N);
    run_bn(4, ggrid, gg2 + (size_t)4*L*128, gbe2 + (size_t)4*L*128, Sl(SZ0));
    // fusion: concat [x1, x3, x2, x4] = Z0, Z2, Z1, Z3  (K=512)
    gemm_rs<<<ggrid,256,0,stream>>>(Z[0],Z[2],Z[1],Z[3],
                                    Sl(SZ0+0),Sl(SZ0+2),Sl(SZ0+1),Sl(SZ0+3),
                                    WTh+oMW1+(size_t)L*65536, WTl+oMW1+(size_t)L*65536,
                                    mb1 + (size_t)L*128, X, pstats, N, 4);
    run_bn(1, ggrid, mg1 + (size_t)L*128, mbe1 + (size_t)L*128, Sl(0));
    run_gemm1(X, Sl(0), oMW2 + (size_t)L*16384, mb2 + (size_t)L*128, X);
    run_bn(1, ggrid, mg2 + (size_t)L*128, mbe2 + (size_t)L*128, Sl(SX));
  }

  // ---- Set2Set (6 steps) ----
  zero_k<<<(G*256+255)/256,256,0,stream>>>(qstar, G*256);
  zero_k<<<(G*128+255)/256,256,0,stream>>>(hbuf, G*128);
  zero_k<<<(G*128+255)/256,256,0,stream>>>(cbuf, G*128);
  int dgrid = (N + 3)/4;
  for (int s=0;s<6;++s){
    lstm_step<<<64,256,0,stream>>>(qstar, hbuf, cbuf, P(54), P(55), P(56), P(57), G);
    dot_h_hf<<<dgrid,256,0,stream>>>(X, Sl(SX), hbuf, batch, ebuf, N);
    seg_reduce<<<G,256,0,stream>>>(ebuf, goff, emax, invden, G);
    r_kernel_hf<<<G,128,0,stream>>>(X, Sl(SX), ebuf, goff, emax, invden, qstar, G);
  }

  final_k<<<G,128,0,stream>>>(qstar, P(58), P(59), P(60), P(61), (float*)d_out, G);
}

// Round 12
// 8391.369 us; speedup vs baseline: 2.3865x; 1.0362x over previous
//
#include <hip/hip_runtime.h>
#include <math.h>

// ---------------------------------------------------------------------------
// NetGIN forward on MI355X — round 12: R10 numerics EXACTLY (certified
// absmax 0.00390625), plus bitwise-neutral optimizations only:
//  * GEMM inner loop: per-n4 W-fragment loads + nh->n4->mt MFMA order.
//    Per-acc-element MFMA sequence unchanged -> bitwise-identical C.
//    Live registers drop ~30 -> removes residual spill, enables pipelining.
//  * aggregate: 8x-unrolled gather, adds in exact edge order (identical).
// LESSON (R11): BN-stats partial-sum trees are part of the certified
// numerics — output is chaotically sensitive to ulp-level BN changes.
// Never change stats grouping without re-certifying.
// ---------------------------------------------------------------------------

#define DEV_INLINE __device__ __forceinline__
typedef unsigned short u16;

union F16U { _Float16 h; u16 u; };
DEV_INLINE float h2f(u16 v){ F16U t; t.u = v; return (float)t.h; }
DEV_INLINE u16 f2h(float f){ F16U t; t.h = (_Float16)f; return t.u; }
DEV_INLINE float bf2f(u16 h){ return __uint_as_float(((unsigned)h)<<16); }
DEV_INLINE u16 f2bf(float f){
  unsigned u = __float_as_uint(f);
  unsigned r = (u + 0x7FFFu + ((u>>16)&1u)) >> 16;
  return (u16)r;
}
DEV_INLINE float sigmoidf_(float x){ return 1.0f/(1.0f+expf(-x)); }
struct __align__(4) us2 { u16 x, y; };
struct __align__(8) us4 { u16 x, y, z, w; };

typedef __attribute__((ext_vector_type(8))) short s8v;   // 8 bf16/fp16
typedef __attribute__((ext_vector_type(4))) float f4v;   // 4 fp32 acc

DEV_INLINE void bnsplit1(float f, u16& hb, u16& lb){
  hb = f2bf(f); lb = f2bf(f - bf2f(hb));
}

// ---------------- utility ----------------
__global__ void zero_k(float* __restrict__ p, int n){
  int i = blockIdx.x*256 + threadIdx.x;
  if (i < n) p[i] = 0.f;
}

// ---------------- weight pre-transpose + bf16 split ----------------
__global__ __launch_bounds__(256) void split_transpose(
  const float* __restrict__ src, u16* __restrict__ dh, u16* __restrict__ dl,
  int K, int count)
{
  int tot = count*K*128;
  for (int i = blockIdx.x*256 + threadIdx.x; i < tot; i += gridDim.x*256){
    int k = i % K;
    int n = (i / K) & 127;
    int c = i / (K*128);
    float w = src[(size_t)c*K*128 + (size_t)k*128 + n];
    u16 hi = f2bf(w);
    u16 lo = f2bf(w - bf2f(hi));
    dh[i] = hi; dl[i] = lo;
  }
}

// ---------------- CSR build ----------------
__global__ void count_deg(const int* __restrict__ dst, int* __restrict__ cnt, int E){
  int e = blockIdx.x*256 + threadIdx.x;
  if (e < E) atomicAdd(&cnt[dst[e]], 1);
}

__global__ void scan_excl(const int* __restrict__ cnt, int* __restrict__ offs, int N){
  const int* c = cnt + (size_t)blockIdx.x * N;
  int* o = offs + (size_t)blockIdx.x * (N+1);
  __shared__ int ps[1024];
  int t = threadIdx.x;
  int chunk = (N + 1023) >> 10;
  int lo = t*chunk, hi = min(lo+chunk, N);
  int s = 0;
  for (int i=lo;i<hi;++i) s += c[i];
  ps[t] = s; __syncthreads();
  for (int d=1; d<1024; d<<=1){
    int v = (t>=d) ? ps[t-d] : 0;
    __syncthreads();
    ps[t] += v;
    __syncthreads();
  }
  int pre = (t==0) ? 0 : ps[t-1];
  for (int i=lo;i<hi;++i){ o[i]=pre; pre += c[i]; }
  if (t==1023) o[N] = ps[1023];
}

__global__ void fill_csr(const int* __restrict__ src, const int* __restrict__ dst,
                         const int* __restrict__ offs, int* __restrict__ cur,
                         int* __restrict__ out, int E){
  int e = blockIdx.x*256 + threadIdx.x;
  if (e >= E) return;
  int d = dst[e];
  int pos = offs[d] + atomicAdd(&cur[d], 1);
  out[pos] = src[e];
}

__global__ void sort_csr(const int* __restrict__ offs, int* __restrict__ srcs, int N){
  int i = blockIdx.x*256 + threadIdx.x;
  if (i >= N) return;
  int lo = offs[i], hi = offs[i+1];
  for (int a = lo+1; a < hi; ++a){
    int v = srcs[a];
    int b = a-1;
    while (b >= lo && srcs[b] > v){ srcs[b+1] = srcs[b]; --b; }
    srcs[b+1] = v;
  }
}

__global__ void graph_offsets(const int* __restrict__ batch, int* __restrict__ goff, int N, int G){
  int g = blockIdx.x*blockDim.x + threadIdx.x;
  if (g > G) return;
  int lo=0, hi=N;
  while (lo<hi){ int mid=(lo+hi)>>1; if (batch[mid] < g) lo=mid+1; else hi=mid; }
  goff[g]=lo;
}

// ---------------- two-stage deterministic BN stats ----------------
__global__ __launch_bounds__(256) void stats_reduce1(
  const float* __restrict__ pstats, int PB, float* __restrict__ out2, int nb)
{
  int c = threadIdx.x, grp = blockIdx.x, bank = blockIdx.y;
  int chunk = (nb + 31) >> 5;
  int b0 = grp*chunk, b1 = min(b0+chunk, nb);
  const float* base = pstats + (size_t)bank*PB*256;
  float s = 0.f;
  for (int b=b0; b<b1; ++b) s += base[(size_t)b*256 + c];
  out2[((size_t)bank*32 + grp)*256 + c] = s;
}
__global__ __launch_bounds__(256) void bnfin2(
  const float* __restrict__ out2, const float* __restrict__ g,
  const float* __restrict__ be, float* __restrict__ Sb, float invN)
{
  __shared__ float tot[256];
  int t = threadIdx.x, bank = blockIdx.x;
  const float* src = out2 + (size_t)bank*32*256;
  float s = 0.f;
  #pragma unroll
  for (int j=0;j<32;++j) s += src[j*256 + t];   // fixed order
  tot[t] = s; __syncthreads();
  if (t < 128){
    float m = tot[t]*invN;
    float v = tot[128+t]*invN - m*m;
    float sc = g[bank*128 + t]*rsqrtf(v + 1e-5f);
    Sb[bank*256 + t] = sc;
    Sb[bank*256 + 128 + t] = be[bank*128 + t] - m*sc;
  }
}

// ======== GEMM core macros (R10 structure; per-n4 W loads) ========
// Per-(part,ks) body. Per-acc-element MFMA order (wh*xh, wl*xh, wh*xl)
// identical to R10 -> bitwise-identical results.
#define GEMM_KS_BODY(A_, S_, WHp_, WLp_, Kel_)                                \
  {                                                                           \
    float4 sa0, sa1, sb0, sb1;                                                \
    if (S_){                                                                  \
      sa0 = *(const float4*)(S_ + koff);                                      \
      sa1 = *(const float4*)(S_ + koff + 4);                                  \
      sb0 = *(const float4*)(S_ + 128 + koff);                                \
      sb1 = *(const float4*)(S_ + 128 + koff + 4);                            \
    }                                                                         \
    s8v xh0, xl0, xh1, xl1;                                                   \
    _Pragma("unroll")                                                         \
    for (int mt=0; mt<2; ++mt){                                               \
      int row = wrow0 + mt*16 + m16;                                          \
      s8v xr = (row < N) ? *(const s8v*)(A_ + (size_t)row*128 + koff)         \
                         : (s8v){0,0,0,0,0,0,0,0};                            \
      float f0 = h2f((u16)xr[0]), f1 = h2f((u16)xr[1]);                       \
      float f2 = h2f((u16)xr[2]), f3 = h2f((u16)xr[3]);                       \
      float f4 = h2f((u16)xr[4]), f5 = h2f((u16)xr[5]);                       \
      float f6 = h2f((u16)xr[6]), f7 = h2f((u16)xr[7]);                       \
      if (S_){                                                                \
        f0 = fmaxf(fmaf(f0, sa0.x, sb0.x), 0.f);                              \
        f1 = fmaxf(fmaf(f1, sa0.y, sb0.y), 0.f);                              \
        f2 = fmaxf(fmaf(f2, sa0.z, sb0.z), 0.f);                              \
        f3 = fmaxf(fmaf(f3, sa0.w, sb0.w), 0.f);                              \
        f4 = fmaxf(fmaf(f4, sa1.x, sb1.x), 0.f);                              \
        f5 = fmaxf(fmaf(f5, sa1.y, sb1.y), 0.f);                              \
        f6 = fmaxf(fmaf(f6, sa1.z, sb1.z), 0.f);                              \
        f7 = fmaxf(fmaf(f7, sa1.w, sb1.w), 0.f);                              \
      }                                                                       \
      s8v h, l; u16 hb, lb;                                                   \
      bnsplit1(f0,hb,lb); h[0]=(short)hb; l[0]=(short)lb;                     \
      bnsplit1(f1,hb,lb); h[1]=(short)hb; l[1]=(short)lb;                     \
      bnsplit1(f2,hb,lb); h[2]=(short)hb; l[2]=(short)lb;                     \
      bnsplit1(f3,hb,lb); h[3]=(short)hb; l[3]=(short)lb;                     \
      bnsplit1(f4,hb,lb); h[4]=(short)hb; l[4]=(short)lb;                     \
      bnsplit1(f5,hb,lb); h[5]=(short)hb; l[5]=(short)lb;                     \
      bnsplit1(f6,hb,lb); h[6]=(short)hb; l[6]=(short)lb;                     \
      bnsplit1(f7,hb,lb); h[7]=(short)hb; l[7]=(short)lb;                     \
      if (mt==0){ xh0=h; xl0=l; } else { xh1=h; xl1=l; }                      \
    }                                                                         \
    _Pragma("unroll")                                                         \
    for (int nh=0; nh<2; ++nh){                                               \
      _Pragma("unroll")                                                       \
      for (int n4=0;n4<4;++n4){                                               \
        int n = (nh*4+n4)*16 + m16;                                           \
        size_t wa = (size_t)n*Kel_ + koff;                                    \
        s8v wh = *(const s8v*)(WHp_ + wa);                                    \
        s8v wl = *(const s8v*)(WLp_ + wa);                                    \
        acc[0][nh*4+n4] = __builtin_amdgcn_mfma_f32_16x16x32_bf16(wh, xh0, acc[0][nh*4+n4], 0,0,0); \
        acc[0][nh*4+n4] = __builtin_amdgcn_mfma_f32_16x16x32_bf16(wl, xh0, acc[0][nh*4+n4], 0,0,0); \
        acc[0][nh*4+n4] = __builtin_amdgcn_mfma_f32_16x16x32_bf16(wh, xl0, acc[0][nh*4+n4], 0,0,0); \
        acc[1][nh*4+n4] = __builtin_amdgcn_mfma_f32_16x16x32_bf16(wh, xh1, acc[1][nh*4+n4], 0,0,0); \
        acc[1][nh*4+n4] = __builtin_amdgcn_mfma_f32_16x16x32_bf16(wl, xh1, acc[1][nh*4+n4], 0,0,0); \
        acc[1][nh*4+n4] = __builtin_amdgcn_mfma_f32_16x16x32_bf16(wh, xl1, acc[1][nh*4+n4], 0,0,0); \
      }                                                                       \
    }                                                                         \
  }

// Epilogue: identical to R10 (certified stats tree).
#define GEMM_EPILOGUE(C_, bias_, pslot_)                                      \
  {                                                                           \
    _Pragma("unroll")                                                         \
    for (int nt=0;nt<8;++nt){                                                 \
      int n0 = nt*16 + kg*4;                                                  \
      float4 b4 = *(const float4*)(bias_ + n0);                               \
      float s1a=0.f,s1b=0.f,s1c=0.f,s1d=0.f;                                  \
      float s2a=0.f,s2b=0.f,s2c=0.f,s2d=0.f;                                  \
      _Pragma("unroll")                                                       \
      for (int mt=0;mt<2;++mt){                                               \
        int row = wrow0 + mt*16 + m16;                                        \
        us4 o;                                                                \
        o.x = f2h(acc[mt][nt][0] + b4.x);                                     \
        o.y = f2h(acc[mt][nt][1] + b4.y);                                     \
        o.z = f2h(acc[mt][nt][2] + b4.z);                                     \
        o.w = f2h(acc[mt][nt][3] + b4.w);                                     \
        *(us4*)(&cst[wid][mt][m16*136 + n0]) = o;                             \
        if (row < N){                                                         \
          float r0=h2f(o.x), r1=h2f(o.y), r2=h2f(o.z), r3=h2f(o.w);           \
          s1a+=r0; s1b+=r1; s1c+=r2; s1d+=r3;                                 \
          s2a+=r0*r0; s2b+=r1*r1; s2c+=r2*r2; s2d+=r3*r3;                     \
        }                                                                     \
      }                                                                       \
      _Pragma("unroll")                                                       \
      for (int off=1; off<16; off<<=1){                                       \
        s1a += __shfl_xor(s1a, off, 64); s1b += __shfl_xor(s1b, off, 64);     \
        s1c += __shfl_xor(s1c, off, 64); s1d += __shfl_xor(s1d, off, 64);     \
        s2a += __shfl_xor(s2a, off, 64); s2b += __shfl_xor(s2b, off, 64);     \
        s2c += __shfl_xor(s2c, off, 64); s2d += __shfl_xor(s2d, off, 64);     \
      }                                                                       \
      if (m16 == 0){                                                          \
        pw[wid][n0+0] = s1a; pw[wid][n0+1] = s1b;                             \
        pw[wid][n0+2] = s1c; pw[wid][n0+3] = s1d;                             \
        pw[wid][128+n0+0] = s2a; pw[wid][128+n0+1] = s2b;                     \
        pw[wid][128+n0+2] = s2c; pw[wid][128+n0+3] = s2d;                     \
      }                                                                       \
    }                                                                         \
    __syncthreads();                                                          \
    if (t < 256){                                                             \
      float tot = ((pw[0][t] + pw[1][t]) + pw[2][t]) + pw[3][t];              \
      (pslot_)[t] = tot;                                                      \
    }                                                                         \
    _Pragma("unroll")                                                         \
    for (int mt=0;mt<2;++mt){                                                 \
      _Pragma("unroll")                                                       \
      for (int it=0; it<4; ++it){                                             \
        int idx = it*64 + lane;                                               \
        int r = idx >> 4;                                                     \
        int c8 = (idx & 15) * 8;                                              \
        int row = wrow0 + mt*16 + r;                                          \
        if (row < N){                                                         \
          s8v v = *(const s8v*)(&cst[wid][mt][r*136 + c8]);                   \
          *(s8v*)(C_ + (size_t)row*128 + c8) = v;                             \
        }                                                                     \
      }                                                                       \
    }                                                                         \
  }

// ---------------- general streaming MFMA GEMM (bank 0) ----------------
__global__ __launch_bounds__(256, 3) void gemm_rs(
  const u16* __restrict__ A0, const u16* __restrict__ A1,
  const u16* __restrict__ A2, const u16* __restrict__ A3,
  const float* __restrict__ S0, const float* __restrict__ S1,
  const float* __restrict__ S2, const float* __restrict__ S3,
  const u16* __restrict__ wt_hi, const u16* __restrict__ wt_lo,
  const float* __restrict__ bias,
  u16* __restrict__ C, float* __restrict__ pstats,
  int N, int npart)
{
  __shared__ u16 cst[4][2][16*136];
  __shared__ float pw[4][256];
  const int t = threadIdx.x;
  const int lane = t & 63;
  const int wid = t >> 6;
  const int m16 = lane & 15;
  const int kg = lane >> 4;
  const int wrow0 = blockIdx.x*128 + wid*32;
  const int K = npart << 7;

  f4v acc[2][8];
  #pragma unroll
  for (int i=0;i<2;++i)
    #pragma unroll
    for (int j=0;j<8;++j) acc[i][j] = (f4v){0.f,0.f,0.f,0.f};

  for (int part=0; part<npart; ++part){
    const u16* A = (part==0)?A0:(part==1)?A1:(part==2)?A2:A3;
    const float* S = (part==0)?S0:(part==1)?S1:(part==2)?S2:S3;
    const u16* WHp = wt_hi + part*128;
    const u16* WLp = wt_lo + part*128;
    #pragma unroll
    for (int ks=0; ks<4; ++ks){
      int koff = ks*32 + kg*8;
      GEMM_KS_BODY(A, S, WHp, WLp, K)
    }
  }
  GEMM_EPILOGUE(C, bias, (pstats + (size_t)blockIdx.x*256))
}

// ---------------- fused 4-conv GIN GEMM (blockIdx.y = conv, K=128, in-place)
__global__ __launch_bounds__(256, 3) void gemm_gin(
  u16* __restrict__ Z0, u16* __restrict__ Z1,
  u16* __restrict__ Z2, u16* __restrict__ Z3,
  const float* __restrict__ Sbase,          // null => raw; else + k*256
  const u16* __restrict__ wt_hi, const u16* __restrict__ wt_lo, // + k*16384
  const float* __restrict__ bias,           // + k*128
  float* __restrict__ pstats, int PB,       // bank k at + k*PB*256
  int N)
{
  __shared__ u16 cst[4][2][16*136];
  __shared__ float pw[4][256];
  const int t = threadIdx.x;
  const int lane = t & 63;
  const int wid = t >> 6;
  const int m16 = lane & 15;
  const int kg = lane >> 4;
  const int wrow0 = blockIdx.x*128 + wid*32;
  const int kb = blockIdx.y;

  u16* Zc = (kb==0)?Z0:(kb==1)?Z1:(kb==2)?Z2:Z3;
  const float* S = Sbase ? (Sbase + (size_t)kb*256) : nullptr;
  const u16* WHp = wt_hi + (size_t)kb*16384;
  const u16* WLp = wt_lo + (size_t)kb*16384;
  const float* biasp = bias + (size_t)kb*128;
  float* pslot = pstats + ((size_t)kb*PB + blockIdx.x)*256;

  f4v acc[2][8];
  #pragma unroll
  for (int i=0;i<2;++i)
    #pragma unroll
    for (int j=0;j<8;++j) acc[i][j] = (f4v){0.f,0.f,0.f,0.f};

  {
    const u16* A = Zc;
    #pragma unroll
    for (int ks=0; ks<4; ++ks){
      int koff = ks*32 + kg*8;
      GEMM_KS_BODY(A, S, WHp, WLp, 128)
    }
  }
  GEMM_EPILOGUE(Zc, biasp, pslot)
}

// ---------------- small-K encoder GEMM (fp32 inputs, K <= 26) ----------------
__global__ __launch_bounds__(256) void gemm_enc(
  const float* __restrict__ X0, int w0, const float* __restrict__ X1, int w1,
  const float* __restrict__ W, const float* __restrict__ bias,
  u16* __restrict__ C, float* __restrict__ pstats, int N)
{
  __shared__ float Ws[26*128];
  __shared__ float red[256];
  int K = w0 + w1;
  int t = threadIdx.x;
  for (int i=t;i<K*128;i+=256) Ws[i] = W[i];
  __syncthreads();
  int c = t & 127, rh = t >> 7;
  float b = bias[c];
  float s1=0.f, s2=0.f;
  for (int r0 = blockIdx.x*2; r0 < N; r0 += gridDim.x*2){
    int r = r0 + rh;
    if (r < N){
      float acc = b;
      for (int k=0;k<w0;++k) acc = fmaf(X0[(size_t)r*w0+k], Ws[k*128+c], acc);
      for (int k=0;k<w1;++k) acc = fmaf(X1[(size_t)r*w1+k], Ws[(w0+k)*128+c], acc);
      u16 o = f2h(acc);
      C[(size_t)r*128+c] = o;
      float rv = h2f(o);
      s1 += rv; s2 += rv*rv;
    }
  }
  red[t] = s1; __syncthreads();
  float t1 = (t < 128) ? (red[t] + red[t+128]) : 0.f;
  __syncthreads();
  red[t] = s2; __syncthreads();
  float t2 = (t < 128) ? (red[t] + red[t+128]) : 0.f;
  if (t < 128){
    pstats[(size_t)blockIdx.x*256 + t] = t1;
    pstats[(size_t)blockIdx.x*256 + 128 + t] = t2;
  }
}

// ---------------- fused GIN aggregation (blockIdx.y = conv; 8x gather) -----
__global__ __launch_bounds__(256) void aggregate4(
  const u16* __restrict__ X, const float* __restrict__ S,
  const int* __restrict__ srcs4, const int* __restrict__ offs4,
  int E, int Np1, const float* __restrict__ geps, int gi0,
  u16* __restrict__ Z0, u16* __restrict__ Z1,
  u16* __restrict__ Z2, u16* __restrict__ Z3, int N)
{
  int kb = blockIdx.y;
  const int* srcs = srcs4 + (size_t)kb*E;
  const int* offs = offs4 + (size_t)kb*Np1;
  u16* Z = (kb==0)?Z0:(kb==1)?Z1:(kb==2)?Z2:Z3;
  int i = blockIdx.x*4 + (threadIdx.x>>6);
  int ln = threadIdx.x & 63;
  int c = ln*2;
  if (i >= N) return;
  float sca = S[c], sha = S[128+c];
  float scb = S[c+1], shb = S[128+c+1];
  float eps1 = 1.0f + geps[gi0 + kb];
  us2 x0 = *(const us2*)(X + (size_t)i*128 + c);
  float acca = eps1 * fmaxf(fmaf(h2f(x0.x), sca, sha), 0.f);
  float accb = eps1 * fmaxf(fmaf(h2f(x0.y), scb, shb), 0.f);
  int e0 = offs[i], e1 = offs[i+1];
  int e = e0;
  // 8x unroll: batch loads, add IN EDGE ORDER (bitwise-identical to serial).
  for (; e+8 <= e1; e += 8){
    int s0 = srcs[e],   s1 = srcs[e+1], s2 = srcs[e+2], s3 = srcs[e+3];
    int s4 = srcs[e+4], s5 = srcs[e+5], s6 = srcs[e+6], s7 = srcs[e+7];
    us2 v0 = *(const us2*)(X + (size_t)s0*128 + c);
    us2 v1 = *(const us2*)(X + (size_t)s1*128 + c);
    us2 v2 = *(const us2*)(X + (size_t)s2*128 + c);
    us2 v3 = *(const us2*)(X + (size_t)s3*128 + c);
    us2 v4 = *(const us2*)(X + (size_t)s4*128 + c);
    us2 v5 = *(const us2*)(X + (size_t)s5*128 + c);
    us2 v6 = *(const us2*)(X + (size_t)s6*128 + c);
    us2 v7 = *(const us2*)(X + (size_t)s7*128 + c);
    acca += fmaxf(fmaf(h2f(v0.x), sca, sha), 0.f);
    accb += fmaxf(fmaf(h2f(v0.y), scb, shb), 0.f);
    acca += fmaxf(fmaf(h2f(v1.x), sca, sha), 0.f);
    accb += fmaxf(fmaf(h2f(v1.y), scb, shb), 0.f);
    acca += fmaxf(fmaf(h2f(v2.x), sca, sha), 0.f);
    accb += fmaxf(fmaf(h2f(v2.y), scb, shb), 0.f);
    acca += fmaxf(fmaf(h2f(v3.x), sca, sha), 0.f);
    accb += fmaxf(fmaf(h2f(v3.y), scb, shb), 0.f);
    acca += fmaxf(fmaf(h2f(v4.x), sca, sha), 0.f);
    accb += fmaxf(fmaf(h2f(v4.y), scb, shb), 0.f);
    acca += fmaxf(fmaf(h2f(v5.x), sca, sha), 0.f);
    accb += fmaxf(fmaf(h2f(v5.y), scb, shb), 0.f);
    acca += fmaxf(fmaf(h2f(v6.x), sca, sha), 0.f);
    accb += fmaxf(fmaf(h2f(v6.y), scb, shb), 0.f);
    acca += fmaxf(fmaf(h2f(v7.x), sca, sha), 0.f);
    accb += fmaxf(fmaf(h2f(v7.y), scb, shb), 0.f);
  }
  for (; e+4 <= e1; e += 4){
    int s0 = srcs[e], s1 = srcs[e+1], s2 = srcs[e+2], s3 = srcs[e+3];
    us2 v0 = *(const us2*)(X + (size_t)s0*128 + c);
    us2 v1 = *(const us2*)(X + (size_t)s1*128 + c);
    us2 v2 = *(const us2*)(X + (size_t)s2*128 + c);
    us2 v3 = *(const us2*)(X + (size_t)s3*128 + c);
    acca += fmaxf(fmaf(h2f(v0.x), sca, sha), 0.f);
    accb += fmaxf(fmaf(h2f(v0.y), scb, shb), 0.f);
    acca += fmaxf(fmaf(h2f(v1.x), sca, sha), 0.f);
    accb += fmaxf(fmaf(h2f(v1.y), scb, shb), 0.f);
    acca += fmaxf(fmaf(h2f(v2.x), sca, sha), 0.f);
    accb += fmaxf(fmaf(h2f(v2.y), scb, shb), 0.f);
    acca += fmaxf(fmaf(h2f(v3.x), sca, sha), 0.f);
    accb += fmaxf(fmaf(h2f(v3.y), scb, shb), 0.f);
  }
  for (; e < e1; ++e){
    int s = srcs[e];
    us2 xv = *(const us2*)(X + (size_t)s*128 + c);
    acca += fmaxf(fmaf(h2f(xv.x), sca, sha), 0.f);
    accb += fmaxf(fmaf(h2f(xv.y), scb, shb), 0.f);
  }
  us2 o; o.x = f2h(acca); o.y = f2h(accb);
  *(us2*)(Z + (size_t)i*128 + c) = o;
}

// ---------------- Set2Set ----------------
__global__ __launch_bounds__(256) void lstm_step(
  float* __restrict__ q_star, float* __restrict__ h, float* __restrict__ cst,
  const float* __restrict__ Wih, const float* __restrict__ Whh,
  const float* __restrict__ bih, const float* __restrict__ bhh, int G)
{
  __shared__ float q[256], hh[128], z[512];
  int t = threadIdx.x;
  for (int g = blockIdx.x; g < G; g += gridDim.x){
    q[t] = q_star[(size_t)g*256 + t];
    if (t < 128) hh[t] = h[(size_t)g*128 + t];
    __syncthreads();
    #pragma unroll
    for (int p=0;p<2;++p){
      int j = t + 256*p;
      float acc = bih[j] + bhh[j];
      const float* wi = Wih + (size_t)j*256;
      const float* wh = Whh + (size_t)j*128;
      for (int k=0;k<256;++k) acc = fmaf(q[k], wi[k], acc);
      for (int k=0;k<128;++k) acc = fmaf(hh[k], wh[k], acc);
      z[j] = acc;
    }
    __syncthreads();
    if (t < 128){
      float i_ = z[t], f_ = z[128+t], g_ = z[256+t], o_ = z[384+t];
      float cc = sigmoidf_(f_)*cst[(size_t)g*128+t] + sigmoidf_(i_)*tanhf(g_);
      float hn = sigmoidf_(o_)*tanhf(cc);
      cst[(size_t)g*128+t] = cc;
      h[(size_t)g*128+t]  = hn;
      q_star[(size_t)g*256+t] = hn;
    }
    __syncthreads();
  }
}

__global__ __launch_bounds__(256) void dot_h_hf(
  const u16* __restrict__ X, const float* __restrict__ S,
  const float* __restrict__ h, const int* __restrict__ batch,
  float* __restrict__ e, int N)
{
  int wv = threadIdx.x >> 6, ln = threadIdx.x & 63;
  int i = blockIdx.x*4 + wv;
  if (i >= N) return;
  int g = batch[i];
  int c = ln*2;
  us2 x2 = *(const us2*)(X + (size_t)i*128 + c);
  float2 h2 = *(const float2*)(h + (size_t)g*128 + c);
  float xa = fmaxf(fmaf(h2f(x2.x), S[c],   S[128+c]),   0.f);
  float xb = fmaxf(fmaf(h2f(x2.y), S[c+1], S[128+c+1]), 0.f);
  float p = xa*h2.x + xb*h2.y;
  #pragma unroll
  for (int off=32; off; off>>=1) p += __shfl_down(p, off, 64);
  if (ln==0) e[i] = p;
}

__global__ __launch_bounds__(256) void seg_reduce(
  const float* __restrict__ e, const int* __restrict__ goff,
  float* __restrict__ emax, float* __restrict__ invden, int G)
{
  int g = blockIdx.x;
  int lo = goff[g], hi = goff[g+1];
  int t = threadIdx.x;
  __shared__ float red[256];
  float m = -3.4e38f;
  for (int i=lo+t; i<hi; i+=256) m = fmaxf(m, e[i]);
  red[t] = m; __syncthreads();
  for (int d=128; d; d>>=1){ if (t<d) red[t] = fmaxf(red[t], red[t+d]); __syncthreads(); }
  m = red[0]; __syncthreads();
  float s = 0.f;
  for (int i=lo+t; i<hi; i+=256) s += expf(e[i]-m);
  red[t] = s; __syncthreads();
  for (int d=128; d; d>>=1){ if (t<d) red[t] += red[t+d]; __syncthreads(); }
  if (t==0){
    emax[g] = m;
    invden[g] = (hi>lo && red[0]>0.f) ? 1.f/red[0] : 0.f;
  }
}

__global__ __launch_bounds__(128) void r_kernel_hf(
  const u16* __restrict__ X, const float* __restrict__ S,
  const float* __restrict__ e, const int* __restrict__ goff,
  const float* __restrict__ emax, const float* __restrict__ invden,
  float* __restrict__ q_star, int G)
{
  int g = blockIdx.x, c = threadIdx.x;
  int lo = goff[g], hi = goff[g+1];
  float m = emax[g], inv = invden[g];
  float sc = S[c], sh = S[128+c];
  float r = 0.f;
  for (int i=lo; i<hi; ++i){
    float w = expf(e[i]-m);
    r = fmaf(w, fmaxf(fmaf(h2f(X[(size_t)i*128+c]), sc, sh), 0.f), r);
  }
  q_star[(size_t)g*256 + 128 + c] = r*inv;
}

__global__ __launch_bounds__(128) void final_k(
  const float* __restrict__ q_star, const float* __restrict__ fc1W,
  const float* __restrict__ fc1b, const float* __restrict__ fc4W,
  const float* __restrict__ fc4b, float* __restrict__ out, int G)
{
  __shared__ float q[256];
  __shared__ float h1[128];
  int g = blockIdx.x, t = threadIdx.x;
  q[t]     = q_star[(size_t)g*256 + t];
  q[128+t] = q_star[(size_t)g*256 + 128 + t];
  __syncthreads();
  float acc = fc1b[t];
  for (int k=0;k<256;++k) acc = fmaf(q[k], fc1W[(size_t)k*128+t], acc);
  h1[t] = fmaxf(acc, 0.f);
  __syncthreads();
  if (t < 12){
    float o = fc4b[t];
    for (int d=0; d<128; ++d) o = fmaf(h1[d], fc4W[(size_t)d*12+t], o);
    out[(size_t)g*12+t] = o;
  }
}

// ---------------------------------------------------------------------------
extern "C" void kernel_launch(void* const* d_in, const int* in_sizes, int n_in,
                              void* d_out, int out_size, void* d_ws, size_t ws_size,
                              hipStream_t stream)
{
  (void)n_in; (void)ws_size;
  const int N = in_sizes[0] / 3;
  const int E = in_sizes[62] / 2;
  const int G = out_size / 12;

  auto P = [&](int i){ return (const float*)d_in[i]; };
  const float* gb1 = P(38); const float* gg1 = P(39); const float* gbe1 = P(40);
  const float* gb2 = P(42); const float* gg2 = P(43); const float* gbe2 = P(44);
  const float* geps = P(45);
  const float* mb1 = P(47); const float* mg1 = P(48); const float* mbe1 = P(49);
  const float* mb2 = P(51); const float* mg2 = P(52); const float* mbe2 = P(53);
  const int* ei[4] = {(const int*)d_in[62], (const int*)d_in[63],
                      (const int*)d_in[64], (const int*)d_in[65]};
  const int* batch = (const int*)d_in[66];

  const int ggrid = (N + 127)/128;
  const int ENC_GRID = 1024;
  const int PB = (ggrid > ENC_GRID) ? ggrid : ENC_GRID;

  char* ws = (char*)d_ws;
  size_t off = 0;
  auto alloc = [&](size_t bytes)->char*{
    char* p = ws + off;
    off = (off + bytes + 255) & ~(size_t)255;
    return p;
  };
  u16* X = (u16*)alloc((size_t)N*128*2);
  u16* Z[4]; for (int k=0;k<4;++k) Z[k] = (u16*)alloc((size_t)N*128*2);
  float* ebuf  = (float*)alloc((size_t)N*4);
  float* pstats= (float*)alloc((size_t)4*PB*256*4);
  float* out2  = (float*)alloc((size_t)4*32*256*4);
  float* Sb    = (float*)alloc(9*256*4);   // 0-3: temps, 4: SX, 5-8: SZ0-3
  int* offs4 = (int*)alloc((size_t)4*(N+1)*4);
  int* srcs4 = (int*)alloc((size_t)4*E*4);
  int* cnt4  = (int*)alloc((size_t)4*N*4);
  int* goff  = (int*)alloc((size_t)(G+1)*4);
  float* qstar = (float*)alloc((size_t)G*256*4);
  float* hbuf  = (float*)alloc((size_t)G*128*4);
  float* cbuf  = (float*)alloc((size_t)G*128*4);
  float* emax  = (float*)alloc((size_t)G*4);
  float* invden= (float*)alloc((size_t)G*4);
  const size_t WT_ELEMS = 1392640;
  u16* WTh = (u16*)alloc(WT_ELEMS*2);
  u16* WTl = (u16*)alloc(WT_ELEMS*2);

  const size_t oEnc0=0, oEnc1=16384, oEnc2=32768, oM0W1=49152, oM0W2=98304;
  const size_t oGW1=114688, oGW2=507904, oMW1=901120, oMW2=1294336;

  const float invN = 1.0f / (float)N;
  const int SX = 4, SZ0 = 5;
  auto Sl = [&](int i){ return Sb + (size_t)i*256; };

  auto prep = [&](const float* src, size_t o, int K, int count){
    int tot = count*K*128;
    split_transpose<<<(tot+255)/256,256,0,stream>>>(src, WTh+o, WTl+o, K, count);
  };
  prep(P(9),  oEnc0, 128, 1);
  prep(P(17), oEnc1, 128, 1);
  prep(P(25), oEnc2, 128, 1);
  prep(P(29), oM0W1, 384, 1);
  prep(P(33), oM0W2, 128, 1);
  prep(P(37), oGW1,  128, 24);
  prep(P(41), oGW2,  128, 24);
  prep(P(46), oMW1,  512, 6);
  prep(P(50), oMW2,  128, 6);

  // ---- CSR build (+ per-node value sort for deterministic sums) ----
  int zgrid = (4*N + 255)/256;
  zero_k<<<zgrid,256,0,stream>>>((float*)cnt4, 4*N);
  int egrid = (E + 255)/256;
  for (int l=0;l<4;++l)
    count_deg<<<egrid,256,0,stream>>>(ei[l]+E, cnt4 + (size_t)l*N, E);
  scan_excl<<<4,1024,0,stream>>>(cnt4, offs4, N);
  zero_k<<<zgrid,256,0,stream>>>((float*)cnt4, 4*N);
  for (int l=0;l<4;++l)
    fill_csr<<<egrid,256,0,stream>>>(ei[l], ei[l]+E, offs4 + (size_t)l*(N+1),
                                     cnt4 + (size_t)l*N, srcs4 + (size_t)l*E, E);
  int ngrid = (N + 255)/256;
  for (int l=0;l<4;++l)
    sort_csr<<<ngrid,256,0,stream>>>(offs4 + (size_t)l*(N+1), srcs4 + (size_t)l*E, N);
  graph_offsets<<<(G+1+255)/256,256,0,stream>>>(batch, goff, N, G);

  auto run_bn = [&](int nbank, int nb, const float* g, const float* be, float* Sbase){
    stats_reduce1<<<dim3(32,nbank),256,0,stream>>>(pstats, PB, out2, nb);
    bnfin2<<<nbank,256,0,stream>>>(out2, g, be, Sbase, invN);
  };
  auto run_gemm1 = [&](const u16* A, const float* S, size_t wo, const float* b, u16* Cc){
    gemm_rs<<<ggrid,256,0,stream>>>(A,nullptr,nullptr,nullptr, S,nullptr,nullptr,nullptr,
                                    WTh+wo, WTl+wo, b, Cc, pstats, N, 1);
  };

  // ---- encoders (X doubles as the intermediate T) ----
  gemm_enc<<<ENC_GRID,256,0,stream>>>(P(0),3, nullptr,0, P(5), P(6), X, pstats, N);
  run_bn(1, ENC_GRID, P(7), P(8), Sl(0));
  run_gemm1(X, Sl(0), oEnc0, P(10), Z[0]);
  run_bn(1, ggrid, P(11), P(12), Sl(SZ0+0));

  gemm_enc<<<ENC_GRID,256,0,stream>>>(P(1),13, P(2),13, P(13), P(14), X, pstats, N);
  run_bn(1, ENC_GRID, P(15), P(16), Sl(0));
  run_gemm1(X, Sl(0), oEnc1, P(18), Z[1]);
  run_bn(1, ggrid, P(19), P(20), Sl(SZ0+1));

  gemm_enc<<<ENC_GRID,256,0,stream>>>(P(3),4, P(4),1, P(21), P(22), X, pstats, N);
  run_bn(1, ENC_GRID, P(23), P(24), Sl(0));
  run_gemm1(X, Sl(0), oEnc2, P(26), Z[2]);
  run_bn(1, ggrid, P(27), P(28), Sl(SZ0+2));

  // m0: concat [nl, na, ea] = Z0,Z1,Z2  (K=384)
  gemm_rs<<<ggrid,256,0,stream>>>(Z[0],Z[1],Z[2],nullptr,
                                  Sl(SZ0+0),Sl(SZ0+1),Sl(SZ0+2),nullptr,
                                  WTh+oM0W1, WTl+oM0W1, P(30), X, pstats, N, 3);
  run_bn(1, ggrid, P(31), P(32), Sl(0));
  run_gemm1(X, Sl(0), oM0W2, P(34), X);
  run_bn(1, ggrid, P(35), P(36), Sl(SX));

  // ---- 6 GIN layers (4 convs fused via blockIdx.y) ----
  int agrid = (N + 3)/4;
  for (int L=0; L<6; ++L){
    aggregate4<<<dim3(agrid,4),256,0,stream>>>(X, Sl(SX), srcs4, offs4, E, N+1,
                                               geps, 4*L, Z[0],Z[1],Z[2],Z[3], N);
    gemm_gin<<<dim3(ggrid,4),256,0,stream>>>(Z[0],Z[1],Z[2],Z[3], nullptr,
                                             WTh+oGW1+(size_t)4*L*16384,
                                             WTl+oGW1+(size_t)4*L*16384,
                                             gb1 + (size_t)4*L*128, pstats, PB, N);
    run_bn(4, ggrid, gg1 + (size_t)4*L*128, gbe1 + (size_t)4*L*128, Sl(0));
    gemm_gin<<<dim3(ggrid,4),256,0,stream>>>(Z[0],Z[1],Z[2],Z[3], Sl(0),
                                             WTh+oGW2+(size_t)4*L*16384,
                                             WTl+oGW2+(size_t)4*L*16384,
                                             gb2 + (size_t)4*L*128, pstats, PB, N);
    run_bn(4, ggrid, gg2 + (size_t)4*L*128, gbe2 + (size_t)4*L*128, Sl(SZ0));
    // fusion: concat [x1, x3, x2, x4] = Z0, Z2, Z1, Z3  (K=512)
    gemm_rs<<<ggrid,256,0,stream>>>(Z[0],Z[2],Z[1],Z[3],
                                    Sl(SZ0+0),Sl(SZ0+2),Sl(SZ0+1),Sl(SZ0+3),
                                    WTh+oMW1+(size_t)L*65536, WTl+oMW1+(size_t)L*65536,
                                    mb1 + (size_t)L*128, X, pstats, N, 4);
    run_bn(1, ggrid, mg1 + (size_t)L*128, mbe1 + (size_t)L*128, Sl(0));
    run_gemm1(X, Sl(0), oMW2 + (size_t)L*16384, mb2 + (size_t)L*128, X);
    run_bn(1, ggrid, mg2 + (size_t)L*128, mbe2 + (size_t)L*128, Sl(SX));
  }

  // ---- Set2Set (6 steps) ----
  zero_k<<<(G*256+255)/256,256,0,stream>>>(qstar, G*256);
  zero_k<<<(G*128+255)/256,256,0,stream>>>(hbuf, G*128);
  zero_k<<<(G*128+255)/256,256,0,stream>>>(cbuf, G*128);
  int dgrid = (N + 3)/4;
  for (int s=0;s<6;++s){
    lstm_step<<<64,256,0,stream>>>(qstar, hbuf, cbuf, P(54), P(55), P(56), P(57), G);
    dot_h_hf<<<dgrid,256,0,stream>>>(X, Sl(SX), hbuf, batch, ebuf, N);
    seg_reduce<<<G,256,0,stream>>>(ebuf, goff, emax, invden, G);
    r_kernel_hf<<<G,128,0,stream>>>(X, Sl(SX), ebuf, goff, emax, invden, qstar, G);
  }

  final_k<<<G,128,0,stream>>>(qstar, P(58), P(59), P(60), P(61), (float*)d_out, G);
}

// Round 14
// 7821.605 us; speedup vs baseline: 2.5604x; 1.0728x over previous
//
#include <hip/hip_runtime.h>
#include <math.h>

// ---------------------------------------------------------------------------
// NetGIN forward on MI355X — round 14.
// R13 LESSON: column-splitting GEMM blocks breaks IN-PLACE safety (two
// blocks share input rows; each overwrites a half -> inter-block race).
// This round: two GEMM variants.
//  * gemm_rs_split (128 rows x 64 cols, grid (g,2)): ONLY for non-in-place
//    calls (encoder X->Z, m0-W1 Z->X, fusion-W1 Z->X). Bitwise-identical
//    per-element math + identical pstats values (disjoint halves).
//  * gemm_rs_full / gemm_gin: EXACTLY R12's kernels for in-place calls
//    (X->X W2 gemms, Z->Z GIN convs).
// Certified numerics preserved (absmax 0.00390625).
// ---------------------------------------------------------------------------

#define DEV_INLINE __device__ __forceinline__
typedef unsigned short u16;

union F16U { _Float16 h; u16 u; };
DEV_INLINE float h2f(u16 v){ F16U t; t.u = v; return (float)t.h; }
DEV_INLINE u16 f2h(float f){ F16U t; t.h = (_Float16)f; return t.u; }
DEV_INLINE float bf2f(u16 h){ return __uint_as_float(((unsigned)h)<<16); }
DEV_INLINE u16 f2bf(float f){
  unsigned u = __float_as_uint(f);
  unsigned r = (u + 0x7FFFu + ((u>>16)&1u)) >> 16;
  return (u16)r;
}
DEV_INLINE float sigmoidf_(float x){ return 1.0f/(1.0f+expf(-x)); }
struct __align__(4) us2 { u16 x, y; };
struct __align__(8) us4 { u16 x, y, z, w; };

typedef __attribute__((ext_vector_type(8))) short s8v;   // 8 bf16/fp16
typedef __attribute__((ext_vector_type(4))) float f4v;   // 4 fp32 acc

DEV_INLINE void bnsplit1(float f, u16& hb, u16& lb){
  hb = f2bf(f); lb = f2bf(f - bf2f(hb));
}

// ---------------- utility ----------------
__global__ void zero_k(float* __restrict__ p, int n){
  int i = blockIdx.x*256 + threadIdx.x;
  if (i < n) p[i] = 0.f;
}

// ---------------- weight pre-transpose + bf16 split ----------------
__global__ __launch_bounds__(256) void split_transpose(
  const float* __restrict__ src, u16* __restrict__ dh, u16* __restrict__ dl,
  int K, int count)
{
  int tot = count*K*128;
  for (int i = blockIdx.x*256 + threadIdx.x; i < tot; i += gridDim.x*256){
    int k = i % K;
    int n = (i / K) & 127;
    int c = i / (K*128);
    float w = src[(size_t)c*K*128 + (size_t)k*128 + n];
    u16 hi = f2bf(w);
    u16 lo = f2bf(w - bf2f(hi));
    dh[i] = hi; dl[i] = lo;
  }
}

// ---------------- CSR build ----------------
__global__ void count_deg(const int* __restrict__ dst, int* __restrict__ cnt, int E){
  int e = blockIdx.x*256 + threadIdx.x;
  if (e < E) atomicAdd(&cnt[dst[e]], 1);
}

__global__ void scan_excl(const int* __restrict__ cnt, int* __restrict__ offs, int N){
  const int* c = cnt + (size_t)blockIdx.x * N;
  int* o = offs + (size_t)blockIdx.x * (N+1);
  __shared__ int ps[1024];
  int t = threadIdx.x;
  int chunk = (N + 1023) >> 10;
  int lo = t*chunk, hi = min(lo+chunk, N);
  int s = 0;
  for (int i=lo;i<hi;++i) s += c[i];
  ps[t] = s; __syncthreads();
  for (int d=1; d<1024; d<<=1){
    int v = (t>=d) ? ps[t-d] : 0;
    __syncthreads();
    ps[t] += v;
    __syncthreads();
  }
  int pre = (t==0) ? 0 : ps[t-1];
  for (int i=lo;i<hi;++i){ o[i]=pre; pre += c[i]; }
  if (t==1023) o[N] = ps[1023];
}

__global__ void fill_csr(const int* __restrict__ src, const int* __restrict__ dst,
                         const int* __restrict__ offs, int* __restrict__ cur,
                         int* __restrict__ out, int E){
  int e = blockIdx.x*256 + threadIdx.x;
  if (e >= E) return;
  int d = dst[e];
  int pos = offs[d] + atomicAdd(&cur[d], 1);
  out[pos] = src[e];
}

__global__ void sort_csr(const int* __restrict__ offs, int* __restrict__ srcs, int N){
  int i = blockIdx.x*256 + threadIdx.x;
  if (i >= N) return;
  int lo = offs[i], hi = offs[i+1];
  for (int a = lo+1; a < hi; ++a){
    int v = srcs[a];
    int b = a-1;
    while (b >= lo && srcs[b] > v){ srcs[b+1] = srcs[b]; --b; }
    srcs[b+1] = v;
  }
}

__global__ void graph_offsets(const int* __restrict__ batch, int* __restrict__ goff, int N, int G){
  int g = blockIdx.x*blockDim.x + threadIdx.x;
  if (g > G) return;
  int lo=0, hi=N;
  while (lo<hi){ int mid=(lo+hi)>>1; if (batch[mid] < g) lo=mid+1; else hi=mid; }
  goff[g]=lo;
}

// ---------------- two-stage deterministic BN stats ----------------
__global__ __launch_bounds__(256) void stats_reduce1(
  const float* __restrict__ pstats, int PB, float* __restrict__ out2, int nb)
{
  int c = threadIdx.x, grp = blockIdx.x, bank = blockIdx.y;
  int chunk = (nb + 31) >> 5;
  int b0 = grp*chunk, b1 = min(b0+chunk, nb);
  const float* base = pstats + (size_t)bank*PB*256;
  float s = 0.f;
  for (int b=b0; b<b1; ++b) s += base[(size_t)b*256 + c];
  out2[((size_t)bank*32 + grp)*256 + c] = s;
}
__global__ __launch_bounds__(256) void bnfin2(
  const float* __restrict__ out2, const float* __restrict__ g,
  const float* __restrict__ be, float* __restrict__ Sb, float invN)
{
  __shared__ float tot[256];
  int t = threadIdx.x, bank = blockIdx.x;
  const float* src = out2 + (size_t)bank*32*256;
  float s = 0.f;
  #pragma unroll
  for (int j=0;j<32;++j) s += src[j*256 + t];   // fixed order
  tot[t] = s; __syncthreads();
  if (t < 128){
    float m = tot[t]*invN;
    float v = tot[128+t]*invN - m*m;
    float sc = g[bank*128 + t]*rsqrtf(v + 1e-5f);
    Sb[bank*256 + t] = sc;
    Sb[bank*256 + 128 + t] = be[bank*128 + t] - m*sc;
  }
}

// ======== FULL-WIDTH GEMM macros (R12, in-place safe) ========
#define GEMM_KS_BODY_F(A_, S_, WHp_, WLp_, Kel_)                              \
  {                                                                           \
    float4 sa0, sa1, sb0, sb1;                                                \
    if (S_){                                                                  \
      sa0 = *(const float4*)(S_ + koff);                                      \
      sa1 = *(const float4*)(S_ + koff + 4);                                  \
      sb0 = *(const float4*)(S_ + 128 + koff);                                \
      sb1 = *(const float4*)(S_ + 128 + koff + 4);                            \
    }                                                                         \
    s8v xh0, xl0, xh1, xl1;                                                   \
    _Pragma("unroll")                                                         \
    for (int mt=0; mt<2; ++mt){                                               \
      int row = wrow0 + mt*16 + m16;                                          \
      s8v xr = (row < N) ? *(const s8v*)(A_ + (size_t)row*128 + koff)         \
                         : (s8v){0,0,0,0,0,0,0,0};                            \
      float f0 = h2f((u16)xr[0]), f1 = h2f((u16)xr[1]);                       \
      float f2 = h2f((u16)xr[2]), f3 = h2f((u16)xr[3]);                       \
      float f4 = h2f((u16)xr[4]), f5 = h2f((u16)xr[5]);                       \
      float f6 = h2f((u16)xr[6]), f7 = h2f((u16)xr[7]);                       \
      if (S_){                                                                \
        f0 = fmaxf(fmaf(f0, sa0.x, sb0.x), 0.f);                              \
        f1 = fmaxf(fmaf(f1, sa0.y, sb0.y), 0.f);                              \
        f2 = fmaxf(fmaf(f2, sa0.z, sb0.z), 0.f);                              \
        f3 = fmaxf(fmaf(f3, sa0.w, sb0.w), 0.f);                              \
        f4 = fmaxf(fmaf(f4, sa1.x, sb1.x), 0.f);                              \
        f5 = fmaxf(fmaf(f5, sa1.y, sb1.y), 0.f);                              \
        f6 = fmaxf(fmaf(f6, sa1.z, sb1.z), 0.f);                              \
        f7 = fmaxf(fmaf(f7, sa1.w, sb1.w), 0.f);                              \
      }                                                                       \
      s8v h, l; u16 hb, lb;                                                   \
      bnsplit1(f0,hb,lb); h[0]=(short)hb; l[0]=(short)lb;                     \
      bnsplit1(f1,hb,lb); h[1]=(short)hb; l[1]=(short)lb;                     \
      bnsplit1(f2,hb,lb); h[2]=(short)hb; l[2]=(short)lb;                     \
      bnsplit1(f3,hb,lb); h[3]=(short)hb; l[3]=(short)lb;                     \
      bnsplit1(f4,hb,lb); h[4]=(short)hb; l[4]=(short)lb;                     \
      bnsplit1(f5,hb,lb); h[5]=(short)hb; l[5]=(short)lb;                     \
      bnsplit1(f6,hb,lb); h[6]=(short)hb; l[6]=(short)lb;                     \
      bnsplit1(f7,hb,lb); h[7]=(short)hb; l[7]=(short)lb;                     \
      if (mt==0){ xh0=h; xl0=l; } else { xh1=h; xl1=l; }                      \
    }                                                                         \
    _Pragma("unroll")                                                         \
    for (int nh=0; nh<2; ++nh){                                               \
      _Pragma("unroll")                                                       \
      for (int n4=0;n4<4;++n4){                                               \
        int n = (nh*4+n4)*16 + m16;                                           \
        size_t wa = (size_t)n*Kel_ + koff;                                    \
        s8v wh = *(const s8v*)(WHp_ + wa);                                    \
        s8v wl = *(const s8v*)(WLp_ + wa);                                    \
        acc[0][nh*4+n4] = __builtin_amdgcn_mfma_f32_16x16x32_bf16(wh, xh0, acc[0][nh*4+n4], 0,0,0); \
        acc[0][nh*4+n4] = __builtin_amdgcn_mfma_f32_16x16x32_bf16(wl, xh0, acc[0][nh*4+n4], 0,0,0); \
        acc[0][nh*4+n4] = __builtin_amdgcn_mfma_f32_16x16x32_bf16(wh, xl0, acc[0][nh*4+n4], 0,0,0); \
        acc[1][nh*4+n4] = __builtin_amdgcn_mfma_f32_16x16x32_bf16(wh, xh1, acc[1][nh*4+n4], 0,0,0); \
        acc[1][nh*4+n4] = __builtin_amdgcn_mfma_f32_16x16x32_bf16(wl, xh1, acc[1][nh*4+n4], 0,0,0); \
        acc[1][nh*4+n4] = __builtin_amdgcn_mfma_f32_16x16x32_bf16(wh, xl1, acc[1][nh*4+n4], 0,0,0); \
      }                                                                       \
    }                                                                         \
  }

#define GEMM_EPILOGUE_F(C_, bias_, pslot_)                                    \
  {                                                                           \
    _Pragma("unroll")                                                         \
    for (int nt=0;nt<8;++nt){                                                 \
      int n0 = nt*16 + kg*4;                                                  \
      float4 b4 = *(const float4*)(bias_ + n0);                               \
      float s1a=0.f,s1b=0.f,s1c=0.f,s1d=0.f;                                  \
      float s2a=0.f,s2b=0.f,s2c=0.f,s2d=0.f;                                  \
      _Pragma("unroll")                                                       \
      for (int mt=0;mt<2;++mt){                                               \
        int row = wrow0 + mt*16 + m16;                                        \
        us4 o;                                                                \
        o.x = f2h(acc[mt][nt][0] + b4.x);                                     \
        o.y = f2h(acc[mt][nt][1] + b4.y);                                     \
        o.z = f2h(acc[mt][nt][2] + b4.z);                                     \
        o.w = f2h(acc[mt][nt][3] + b4.w);                                     \
        *(us4*)(&cst[wid][mt][m16*136 + n0]) = o;                             \
        if (row < N){                                                         \
          float r0=h2f(o.x), r1=h2f(o.y), r2=h2f(o.z), r3=h2f(o.w);           \
          s1a+=r0; s1b+=r1; s1c+=r2; s1d+=r3;                                 \
          s2a+=r0*r0; s2b+=r1*r1; s2c+=r2*r2; s2d+=r3*r3;                     \
        }                                                                     \
      }                                                                       \
      _Pragma("unroll")                                                       \
      for (int off=1; off<16; off<<=1){                                       \
        s1a += __shfl_xor(s1a, off, 64); s1b += __shfl_xor(s1b, off, 64);     \
        s1c += __shfl_xor(s1c, off, 64); s1d += __shfl_xor(s1d, off, 64);     \
        s2a += __shfl_xor(s2a, off, 64); s2b += __shfl_xor(s2b, off, 64);     \
        s2c += __shfl_xor(s2c, off, 64); s2d += __shfl_xor(s2d, off, 64);     \
      }                                                                       \
      if (m16 == 0){                                                          \
        pw[wid][n0+0] = s1a; pw[wid][n0+1] = s1b;                             \
        pw[wid][n0+2] = s1c; pw[wid][n0+3] = s1d;                             \
        pw[wid][128+n0+0] = s2a; pw[wid][128+n0+1] = s2b;                     \
        pw[wid][128+n0+2] = s2c; pw[wid][128+n0+3] = s2d;                     \
      }                                                                       \
    }                                                                         \
    __syncthreads();                                                          \
    if (t < 256){                                                             \
      float tot = ((pw[0][t] + pw[1][t]) + pw[2][t]) + pw[3][t];              \
      (pslot_)[t] = tot;                                                      \
    }                                                                         \
    _Pragma("unroll")                                                         \
    for (int mt=0;mt<2;++mt){                                                 \
      _Pragma("unroll")                                                       \
      for (int it=0; it<4; ++it){                                             \
        int idx = it*64 + lane;                                               \
        int r = idx >> 4;                                                     \
        int c8 = (idx & 15) * 8;                                              \
        int row = wrow0 + mt*16 + r;                                          \
        if (row < N){                                                         \
          s8v v = *(const s8v*)(&cst[wid][mt][r*136 + c8]);                   \
          *(s8v*)(C_ + (size_t)row*128 + c8) = v;                             \
        }                                                                     \
      }                                                                       \
    }                                                                         \
  }

// ======== COLUMN-SPLIT GEMM macros (non-in-place only) ========
#define GEMM_KS_BODY_S(A_, S_, WHp_, WLp_, Kel_)                              \
  {                                                                           \
    float4 sa0, sa1, sb0, sb1;                                                \
    if (S_){                                                                  \
      sa0 = *(const float4*)(S_ + koff);                                      \
      sa1 = *(const float4*)(S_ + koff + 4);                                  \
      sb0 = *(const float4*)(S_ + 128 + koff);                                \
      sb1 = *(const float4*)(S_ + 128 + koff + 4);                            \
    }                                                                         \
    s8v xh0, xl0, xh1, xl1;                                                   \
    _Pragma("unroll")                                                         \
    for (int mt=0; mt<2; ++mt){                                               \
      int row = wrow0 + mt*16 + m16;                                          \
      s8v xr = (row < N) ? *(const s8v*)(A_ + (size_t)row*128 + koff)         \
                         : (s8v){0,0,0,0,0,0,0,0};                            \
      float f0 = h2f((u16)xr[0]), f1 = h2f((u16)xr[1]);                       \
      float f2 = h2f((u16)xr[2]), f3 = h2f((u16)xr[3]);                       \
      float f4 = h2f((u16)xr[4]), f5 = h2f((u16)xr[5]);                       \
      float f6 = h2f((u16)xr[6]), f7 = h2f((u16)xr[7]);                       \
      if (S_){                                                                \
        f0 = fmaxf(fmaf(f0, sa0.x, sb0.x), 0.f);                              \
        f1 = fmaxf(fmaf(f1, sa0.y, sb0.y), 0.f);                              \
        f2 = fmaxf(fmaf(f2, sa0.z, sb0.z), 0.f);                              \
        f3 = fmaxf(fmaf(f3, sa0.w, sb0.w), 0.f);                              \
        f4 = fmaxf(fmaf(f4, sa1.x, sb1.x), 0.f);                              \
        f5 = fmaxf(fmaf(f5, sa1.y, sb1.y), 0.f);                              \
        f6 = fmaxf(fmaf(f6, sa1.z, sb1.z), 0.f);                              \
        f7 = fmaxf(fmaf(f7, sa1.w, sb1.w), 0.f);                              \
      }                                                                       \
      s8v h, l; u16 hb, lb;                                                   \
      bnsplit1(f0,hb,lb); h[0]=(short)hb; l[0]=(short)lb;                     \
      bnsplit1(f1,hb,lb); h[1]=(short)hb; l[1]=(short)lb;                     \
      bnsplit1(f2,hb,lb); h[2]=(short)hb; l[2]=(short)lb;                     \
      bnsplit1(f3,hb,lb); h[3]=(short)hb; l[3]=(short)lb;                     \
      bnsplit1(f4,hb,lb); h[4]=(short)hb; l[4]=(short)lb;                     \
      bnsplit1(f5,hb,lb); h[5]=(short)hb; l[5]=(short)lb;                     \
      bnsplit1(f6,hb,lb); h[6]=(short)hb; l[6]=(short)lb;                     \
      bnsplit1(f7,hb,lb); h[7]=(short)hb; l[7]=(short)lb;                     \
      if (mt==0){ xh0=h; xl0=l; } else { xh1=h; xl1=l; }                      \
    }                                                                         \
    _Pragma("unroll")                                                         \
    for (int nt=0; nt<4; ++nt){                                               \
      int n = colbase + nt*16 + m16;                                          \
      size_t wa = (size_t)n*Kel_ + koff;                                      \
      s8v wh = *(const s8v*)(WHp_ + wa);                                      \
      s8v wl = *(const s8v*)(WLp_ + wa);                                      \
      acc[0][nt] = __builtin_amdgcn_mfma_f32_16x16x32_bf16(wh, xh0, acc[0][nt], 0,0,0); \
      acc[0][nt] = __builtin_amdgcn_mfma_f32_16x16x32_bf16(wl, xh0, acc[0][nt], 0,0,0); \
      acc[0][nt] = __builtin_amdgcn_mfma_f32_16x16x32_bf16(wh, xl0, acc[0][nt], 0,0,0); \
      acc[1][nt] = __builtin_amdgcn_mfma_f32_16x16x32_bf16(wh, xh1, acc[1][nt], 0,0,0); \
      acc[1][nt] = __builtin_amdgcn_mfma_f32_16x16x32_bf16(wl, xh1, acc[1][nt], 0,0,0); \
      acc[1][nt] = __builtin_amdgcn_mfma_f32_16x16x32_bf16(wh, xl1, acc[1][nt], 0,0,0); \
    }                                                                         \
  }

#define GEMM_EPILOGUE_S(C_, bias_, pslot_)                                    \
  {                                                                           \
    _Pragma("unroll")                                                         \
    for (int nt=0;nt<4;++nt){                                                 \
      int lc0 = nt*16 + kg*4;                                                 \
      int n0 = colbase + lc0;                                                 \
      float4 b4 = *(const float4*)(bias_ + n0);                               \
      float s1a=0.f,s1b=0.f,s1c=0.f,s1d=0.f;                                  \
      float s2a=0.f,s2b=0.f,s2c=0.f,s2d=0.f;                                  \
      _Pragma("unroll")                                                       \
      for (int mt=0;mt<2;++mt){                                               \
        int row = wrow0 + mt*16 + m16;                                        \
        us4 o;                                                                \
        o.x = f2h(acc[mt][nt][0] + b4.x);                                     \
        o.y = f2h(acc[mt][nt][1] + b4.y);                                     \
        o.z = f2h(acc[mt][nt][2] + b4.z);                                     \
        o.w = f2h(acc[mt][nt][3] + b4.w);                                     \
        *(us4*)(&cst[wid][mt][m16*72 + lc0]) = o;                             \
        if (row < N){                                                         \
          float r0=h2f(o.x), r1=h2f(o.y), r2=h2f(o.z), r3=h2f(o.w);           \
          s1a+=r0; s1b+=r1; s1c+=r2; s1d+=r3;                                 \
          s2a+=r0*r0; s2b+=r1*r1; s2c+=r2*r2; s2d+=r3*r3;                     \
        }                                                                     \
      }                                                                       \
      _Pragma("unroll")                                                       \
      for (int off=1; off<16; off<<=1){                                       \
        s1a += __shfl_xor(s1a, off, 64); s1b += __shfl_xor(s1b, off, 64);     \
        s1c += __shfl_xor(s1c, off, 64); s1d += __shfl_xor(s1d, off, 64);     \
        s2a += __shfl_xor(s2a, off, 64); s2b += __shfl_xor(s2b, off, 64);     \
        s2c += __shfl_xor(s2c, off, 64); s2d += __shfl_xor(s2d, off, 64);     \
      }                                                                       \
      if (m16 == 0){                                                          \
        pw[wid][lc0+0] = s1a; pw[wid][lc0+1] = s1b;                           \
        pw[wid][lc0+2] = s1c; pw[wid][lc0+3] = s1d;                           \
        pw[wid][64+lc0+0] = s2a; pw[wid][64+lc0+1] = s2b;                     \
        pw[wid][64+lc0+2] = s2c; pw[wid][64+lc0+3] = s2d;                     \
      }                                                                       \
    }                                                                         \
    __syncthreads();                                                          \
    if (t < 128){                                                             \
      int lc = t & 63, part = t >> 6;                                         \
      int li = part*64 + lc;                                                  \
      float tot = ((pw[0][li] + pw[1][li]) + pw[2][li]) + pw[3][li];          \
      (pslot_)[part*128 + colbase + lc] = tot;                                \
    }                                                                         \
    _Pragma("unroll")                                                         \
    for (int mt=0;mt<2;++mt){                                                 \
      _Pragma("unroll")                                                       \
      for (int it=0; it<2; ++it){                                             \
        int idx = it*64 + lane;                                               \
        int r = idx >> 3;                                                     \
        int c8 = (idx & 7) * 8;                                               \
        int row = wrow0 + mt*16 + r;                                          \
        if (row < N){                                                         \
          s8v v = *(const s8v*)(&cst[wid][mt][r*72 + c8]);                    \
          *(s8v*)(C_ + (size_t)row*128 + colbase + c8) = v;                   \
        }                                                                     \
      }                                                                       \
    }                                                                         \
  }

// ---------------- full-width GEMM (in-place safe; R12) ----------------
__global__ __launch_bounds__(256, 3) void gemm_rs_full(
  const u16* __restrict__ A0, const u16* __restrict__ A1,
  const u16* __restrict__ A2, const u16* __restrict__ A3,
  const float* __restrict__ S0, const float* __restrict__ S1,
  const float* __restrict__ S2, const float* __restrict__ S3,
  const u16* __restrict__ wt_hi, const u16* __restrict__ wt_lo,
  const float* __restrict__ bias,
  u16* __restrict__ C, float* __restrict__ pstats,
  int N, int npart)
{
  __shared__ u16 cst[4][2][16*136];
  __shared__ float pw[4][256];
  const int t = threadIdx.x;
  const int lane = t & 63;
  const int wid = t >> 6;
  const int m16 = lane & 15;
  const int kg = lane >> 4;
  const int wrow0 = blockIdx.x*128 + wid*32;
  const int K = npart << 7;

  f4v acc[2][8];
  #pragma unroll
  for (int i=0;i<2;++i)
    #pragma unroll
    for (int j=0;j<8;++j) acc[i][j] = (f4v){0.f,0.f,0.f,0.f};

  for (int part=0; part<npart; ++part){
    const u16* A = (part==0)?A0:(part==1)?A1:(part==2)?A2:A3;
    const float* S = (part==0)?S0:(part==1)?S1:(part==2)?S2:S3;
    const u16* WHp = wt_hi + part*128;
    const u16* WLp = wt_lo + part*128;
    #pragma unroll
    for (int ks=0; ks<4; ++ks){
      int koff = ks*32 + kg*8;
      GEMM_KS_BODY_F(A, S, WHp, WLp, K)
    }
  }
  GEMM_EPILOGUE_F(C, bias, (pstats + (size_t)blockIdx.x*256))
}

// ---------------- column-split GEMM (non-in-place only) ----------------
__global__ __launch_bounds__(256, 3) void gemm_rs_split(
  const u16* __restrict__ A0, const u16* __restrict__ A1,
  const u16* __restrict__ A2, const u16* __restrict__ A3,
  const float* __restrict__ S0, const float* __restrict__ S1,
  const float* __restrict__ S2, const float* __restrict__ S3,
  const u16* __restrict__ wt_hi, const u16* __restrict__ wt_lo,
  const float* __restrict__ bias,
  u16* __restrict__ C, float* __restrict__ pstats,
  int N, int npart)
{
  __shared__ u16 cst[4][2][16*72];
  __shared__ float pw[4][128];
  const int t = threadIdx.x;
  const int lane = t & 63;
  const int wid = t >> 6;
  const int m16 = lane & 15;
  const int kg = lane >> 4;
  const int wrow0 = blockIdx.x*128 + wid*32;
  const int colbase = blockIdx.y*64;
  const int K = npart << 7;

  f4v acc[2][4];
  #pragma unroll
  for (int i=0;i<2;++i)
    #pragma unroll
    for (int j=0;j<4;++j) acc[i][j] = (f4v){0.f,0.f,0.f,0.f};

  for (int part=0; part<npart; ++part){
    const u16* A = (part==0)?A0:(part==1)?A1:(part==2)?A2:A3;
    const float* S = (part==0)?S0:(part==1)?S1:(part==2)?S2:S3;
    const u16* WHp = wt_hi + part*128;
    const u16* WLp = wt_lo + part*128;
    #pragma unroll
    for (int ks=0; ks<4; ++ks){
      int koff = ks*32 + kg*8;
      GEMM_KS_BODY_S(A, S, WHp, WLp, K)
    }
  }
  GEMM_EPILOGUE_S(C, bias, (pstats + (size_t)blockIdx.x*256))
}

// ---------------- fused 4-conv GIN GEMM (full-width, in-place; R12) --------
__global__ __launch_bounds__(256, 3) void gemm_gin(
  u16* __restrict__ Z0, u16* __restrict__ Z1,
  u16* __restrict__ Z2, u16* __restrict__ Z3,
  const float* __restrict__ Sbase,          // null => raw; else + k*256
  const u16* __restrict__ wt_hi, const u16* __restrict__ wt_lo, // + k*16384
  const float* __restrict__ bias,           // + k*128
  float* __restrict__ pstats, int PB,       // bank k at + k*PB*256
  int N)
{
  __shared__ u16 cst[4][2][16*136];
  __shared__ float pw[4][256];
  const int t = threadIdx.x;
  const int lane = t & 63;
  const int wid = t >> 6;
  const int m16 = lane & 15;
  const int kg = lane >> 4;
  const int wrow0 = blockIdx.x*128 + wid*32;
  const int kb = blockIdx.y;

  u16* Zc = (kb==0)?Z0:(kb==1)?Z1:(kb==2)?Z2:Z3;
  const float* S = Sbase ? (Sbase + (size_t)kb*256) : nullptr;
  const u16* WHp = wt_hi + (size_t)kb*16384;
  const u16* WLp = wt_lo + (size_t)kb*16384;
  const float* biasp = bias + (size_t)kb*128;
  float* pslot = pstats + ((size_t)kb*PB + blockIdx.x)*256;

  f4v acc[2][8];
  #pragma unroll
  for (int i=0;i<2;++i)
    #pragma unroll
    for (int j=0;j<8;++j) acc[i][j] = (f4v){0.f,0.f,0.f,0.f};

  {
    const u16* A = Zc;
    #pragma unroll
    for (int ks=0; ks<4; ++ks){
      int koff = ks*32 + kg*8;
      GEMM_KS_BODY_F(A, S, WHp, WLp, 128)
    }
  }
  GEMM_EPILOGUE_F(Zc, biasp, pslot)
}

// ---------------- small-K encoder GEMM (fp32 inputs, K <= 26) ----------------
__global__ __launch_bounds__(256) void gemm_enc(
  const float* __restrict__ X0, int w0, const float* __restrict__ X1, int w1,
  const float* __restrict__ W, const float* __restrict__ bias,
  u16* __restrict__ C, float* __restrict__ pstats, int N)
{
  __shared__ float Ws[26*128];
  __shared__ float red[256];
  int K = w0 + w1;
  int t = threadIdx.x;
  for (int i=t;i<K*128;i+=256) Ws[i] = W[i];
  __syncthreads();
  int c = t & 127, rh = t >> 7;
  float b = bias[c];
  float s1=0.f, s2=0.f;
  for (int r0 = blockIdx.x*2; r0 < N; r0 += gridDim.x*2){
    int r = r0 + rh;
    if (r < N){
      float acc = b;
      for (int k=0;k<w0;++k) acc = fmaf(X0[(size_t)r*w0+k], Ws[k*128+c], acc);
      for (int k=0;k<w1;++k) acc = fmaf(X1[(size_t)r*w1+k], Ws[(w0+k)*128+c], acc);
      u16 o = f2h(acc);
      C[(size_t)r*128+c] = o;
      float rv = h2f(o);
      s1 += rv; s2 += rv*rv;
    }
  }
  red[t] = s1; __syncthreads();
  float t1 = (t < 128) ? (red[t] + red[t+128]) : 0.f;
  __syncthreads();
  red[t] = s2; __syncthreads();
  float t2 = (t < 128) ? (red[t] + red[t+128]) : 0.f;
  if (t < 128){
    pstats[(size_t)blockIdx.x*256 + t] = t1;
    pstats[(size_t)blockIdx.x*256 + 128 + t] = t2;
  }
}

// ---------------- fused GIN aggregation (blockIdx.y = conv; 8x gather) -----
__global__ __launch_bounds__(256) void aggregate4(
  const u16* __restrict__ X, const float* __restrict__ S,
  const int* __restrict__ srcs4, const int* __restrict__ offs4,
  int E, int Np1, const float* __restrict__ geps, int gi0,
  u16* __restrict__ Z0, u16* __restrict__ Z1,
  u16* __restrict__ Z2, u16* __restrict__ Z3, int N)
{
  int kb = blockIdx.y;
  const int* srcs = srcs4 + (size_t)kb*E;
  const int* offs = offs4 + (size_t)kb*Np1;
  u16* Z = (kb==0)?Z0:(kb==1)?Z1:(kb==2)?Z2:Z3;
  int i = blockIdx.x*4 + (threadIdx.x>>6);
  int ln = threadIdx.x & 63;
  int c = ln*2;
  if (i >= N) return;
  float sca = S[c], sha = S[128+c];
  float scb = S[c+1], shb = S[128+c+1];
  float eps1 = 1.0f + geps[gi0 + kb];
  us2 x0 = *(const us2*)(X + (size_t)i*128 + c);
  float acca = eps1 * fmaxf(fmaf(h2f(x0.x), sca, sha), 0.f);
  float accb = eps1 * fmaxf(fmaf(h2f(x0.y), scb, shb), 0.f);
  int e0 = offs[i], e1 = offs[i+1];
  int e = e0;
  for (; e+8 <= e1; e += 8){
    int s0 = srcs[e],   s1 = srcs[e+1], s2 = srcs[e+2], s3 = srcs[e+3];
    int s4 = srcs[e+4], s5 = srcs[e+5], s6 = srcs[e+6], s7 = srcs[e+7];
    us2 v0 = *(const us2*)(X + (size_t)s0*128 + c);
    us2 v1 = *(const us2*)(X + (size_t)s1*128 + c);
    us2 v2 = *(const us2*)(X + (size_t)s2*128 + c);
    us2 v3 = *(const us2*)(X + (size_t)s3*128 + c);
    us2 v4 = *(const us2*)(X + (size_t)s4*128 + c);
    us2 v5 = *(const us2*)(X + (size_t)s5*128 + c);
    us2 v6 = *(const us2*)(X + (size_t)s6*128 + c);
    us2 v7 = *(const us2*)(X + (size_t)s7*128 + c);
    acca += fmaxf(fmaf(h2f(v0.x), sca, sha), 0.f);
    accb += fmaxf(fmaf(h2f(v0.y), scb, shb), 0.f);
    acca += fmaxf(fmaf(h2f(v1.x), sca, sha), 0.f);
    accb += fmaxf(fmaf(h2f(v1.y), scb, shb), 0.f);
    acca += fmaxf(fmaf(h2f(v2.x), sca, sha), 0.f);
    accb += fmaxf(fmaf(h2f(v2.y), scb, shb), 0.f);
    acca += fmaxf(fmaf(h2f(v3.x), sca, sha), 0.f);
    accb += fmaxf(fmaf(h2f(v3.y), scb, shb), 0.f);
    acca += fmaxf(fmaf(h2f(v4.x), sca, sha), 0.f);
    accb += fmaxf(fmaf(h2f(v4.y), scb, shb), 0.f);
    acca += fmaxf(fmaf(h2f(v5.x), sca, sha), 0.f);
    accb += fmaxf(fmaf(h2f(v5.y), scb, shb), 0.f);
    acca += fmaxf(fmaf(h2f(v6.x), sca, sha), 0.f);
    accb += fmaxf(fmaf(h2f(v6.y), scb, shb), 0.f);
    acca += fmaxf(fmaf(h2f(v7.x), sca, sha), 0.f);
    accb += fmaxf(fmaf(h2f(v7.y), scb, shb), 0.f);
  }
  for (; e+4 <= e1; e += 4){
    int s0 = srcs[e], s1 = srcs[e+1], s2 = srcs[e+2], s3 = srcs[e+3];
    us2 v0 = *(const us2*)(X + (size_t)s0*128 + c);
    us2 v1 = *(const us2*)(X + (size_t)s1*128 + c);
    us2 v2 = *(const us2*)(X + (size_t)s2*128 + c);
    us2 v3 = *(const us2*)(X + (size_t)s3*128 + c);
    acca += fmaxf(fmaf(h2f(v0.x), sca, sha), 0.f);
    accb += fmaxf(fmaf(h2f(v0.y), scb, shb), 0.f);
    acca += fmaxf(fmaf(h2f(v1.x), sca, sha), 0.f);
    accb += fmaxf(fmaf(h2f(v1.y), scb, shb), 0.f);
    acca += fmaxf(fmaf(h2f(v2.x), sca, sha), 0.f);
    accb += fmaxf(fmaf(h2f(v2.y), scb, shb), 0.f);
    acca += fmaxf(fmaf(h2f(v3.x), sca, sha), 0.f);
    accb += fmaxf(fmaf(h2f(v3.y), scb, shb), 0.f);
  }
  for (; e < e1; ++e){
    int s = srcs[e];
    us2 xv = *(const us2*)(X + (size_t)s*128 + c);
    acca += fmaxf(fmaf(h2f(xv.x), sca, sha), 0.f);
    accb += fmaxf(fmaf(h2f(xv.y), scb, shb), 0.f);
  }
  us2 o; o.x = f2h(acca); o.y = f2h(accb);
  *(us2*)(Z + (size_t)i*128 + c) = o;
}

// ---------------- Set2Set ----------------
__global__ __launch_bounds__(256) void lstm_step(
  float* __restrict__ q_star, float* __restrict__ h, float* __restrict__ cst,
  const float* __restrict__ Wih, const float* __restrict__ Whh,
  const float* __restrict__ bih, const float* __restrict__ bhh, int G)
{
  __shared__ float q[256], hh[128], z[512];
  int t = threadIdx.x;
  for (int g = blockIdx.x; g < G; g += gridDim.x){
    q[t] = q_star[(size_t)g*256 + t];
    if (t < 128) hh[t] = h[(size_t)g*128 + t];
    __syncthreads();
    #pragma unroll
    for (int p=0;p<2;++p){
      int j = t + 256*p;
      float acc = bih[j] + bhh[j];
      const float* wi = Wih + (size_t)j*256;
      const float* wh = Whh + (size_t)j*128;
      for (int k=0;k<256;++k) acc = fmaf(q[k], wi[k], acc);
      for (int k=0;k<128;++k) acc = fmaf(hh[k], wh[k], acc);
      z[j] = acc;
    }
    __syncthreads();
    if (t < 128){
      float i_ = z[t], f_ = z[128+t], g_ = z[256+t], o_ = z[384+t];
      float cc = sigmoidf_(f_)*cst[(size_t)g*128+t] + sigmoidf_(i_)*tanhf(g_);
      float hn = sigmoidf_(o_)*tanhf(cc);
      cst[(size_t)g*128+t] = cc;
      h[(size_t)g*128+t]  = hn;
      q_star[(size_t)g*256+t] = hn;
    }
    __syncthreads();
  }
}

__global__ __launch_bounds__(256) void dot_h_hf(
  const u16* __restrict__ X, const float* __restrict__ S,
  const float* __restrict__ h, const int* __restrict__ batch,
  float* __restrict__ e, int N)
{
  int wv = threadIdx.x >> 6, ln = threadIdx.x & 63;
  int i = blockIdx.x*4 + wv;
  if (i >= N) return;
  int g = batch[i];
  int c = ln*2;
  us2 x2 = *(const us2*)(X + (size_t)i*128 + c);
  float2 h2 = *(const float2*)(h + (size_t)g*128 + c);
  float xa = fmaxf(fmaf(h2f(x2.x), S[c],   S[128+c]),   0.f);
  float xb = fmaxf(fmaf(h2f(x2.y), S[c+1], S[128+c+1]), 0.f);
  float p = xa*h2.x + xb*h2.y;
  #pragma unroll
  for (int off=32; off; off>>=1) p += __shfl_down(p, off, 64);
  if (ln==0) e[i] = p;
}

__global__ __launch_bounds__(256) void seg_reduce(
  const float* __restrict__ e, const int* __restrict__ goff,
  float* __restrict__ emax, float* __restrict__ invden, int G)
{
  int g = blockIdx.x;
  int lo = goff[g], hi = goff[g+1];
  int t = threadIdx.x;
  __shared__ float red[256];
  float m = -3.4e38f;
  for (int i=lo+t; i<hi; i+=256) m = fmaxf(m, e[i]);
  red[t] = m; __syncthreads();
  for (int d=128; d; d>>=1){ if (t<d) red[t] = fmaxf(red[t], red[t+d]); __syncthreads(); }
  m = red[0]; __syncthreads();
  float s = 0.f;
  for (int i=lo+t; i<hi; i+=256) s += expf(e[i]-m);
  red[t] = s; __syncthreads();
  for (int d=128; d; d>>=1){ if (t<d) red[t] += red[t+d]; __syncthreads(); }
  if (t==0){
    emax[g] = m;
    invden[g] = (hi>lo && red[0]>0.f) ? 1.f/red[0] : 0.f;
  }
}

__global__ __launch_bounds__(128) void r_kernel_hf(
  const u16* __restrict__ X, const float* __restrict__ S,
  const float* __restrict__ e, const int* __restrict__ goff,
  const float* __restrict__ emax, const float* __restrict__ invden,
  float* __restrict__ q_star, int G)
{
  int g = blockIdx.x, c = threadIdx.x;
  int lo = goff[g], hi = goff[g+1];
  float m = emax[g], inv = invden[g];
  float sc = S[c], sh = S[128+c];
  float r = 0.f;
  for (int i=lo; i<hi; ++i){
    float w = expf(e[i]-m);
    r = fmaf(w, fmaxf(fmaf(h2f(X[(size_t)i*128+c]), sc, sh), 0.f), r);
  }
  q_star[(size_t)g*256 + 128 + c] = r*inv;
}

__global__ __launch_bounds__(128) void final_k(
  const float* __restrict__ q_star, const float* __restrict__ fc1W,
  const float* __restrict__ fc1b, const float* __restrict__ fc4W,
  const float* __restrict__ fc4b, float* __restrict__ out, int G)
{
  __shared__ float q[256];
  __shared__ float h1[128];
  int g = blockIdx.x, t = threadIdx.x;
  q[t]     = q_star[(size_t)g*256 + t];
  q[128+t] = q_star[(size_t)g*256 + 128 + t];
  __syncthreads();
  float acc = fc1b[t];
  for (int k=0;k<256;++k) acc = fmaf(q[k], fc1W[(size_t)k*128+t], acc);
  h1[t] = fmaxf(acc, 0.f);
  __syncthreads();
  if (t < 12){
    float o = fc4b[t];
    for (int d=0; d<128; ++d) o = fmaf(h1[d], fc4W[(size_t)d*12+t], o);
    out[(size_t)g*12+t] = o;
  }
}

// ---------------------------------------------------------------------------
extern "C" void kernel_launch(void* const* d_in, const int* in_sizes, int n_in,
                              void* d_out, int out_size, void* d_ws, size_t ws_size,
                              hipStream_t stream)
{
  (void)n_in; (void)ws_size;
  const int N = in_sizes[0] / 3;
  const int E = in_sizes[62] / 2;
  const int G = out_size / 12;

  auto P = [&](int i){ return (const float*)d_in[i]; };
  const float* gb1 = P(38); const float* gg1 = P(39); const float* gbe1 = P(40);
  const float* gb2 = P(42); const float* gg2 = P(43); const float* gbe2 = P(44);
  const float* geps = P(45);
  const float* mb1 = P(47); const float* mg1 = P(48); const float* mbe1 = P(49);
  const float* mb2 = P(51); const float* mg2 = P(52); const float* mbe2 = P(53);
  const int* ei[4] = {(const int*)d_in[62], (const int*)d_in[63],
                      (const int*)d_in[64], (const int*)d_in[65]};
  const int* batch = (const int*)d_in[66];

  const int ggrid = (N + 127)/128;
  const int ENC_GRID = 1024;
  const int PB = (ggrid > ENC_GRID) ? ggrid : ENC_GRID;

  char* ws = (char*)d_ws;
  size_t off = 0;
  auto alloc = [&](size_t bytes)->char*{
    char* p = ws + off;
    off = (off + bytes + 255) & ~(size_t)255;
    return p;
  };
  u16* X = (u16*)alloc((size_t)N*128*2);
  u16* Z[4]; for (int k=0;k<4;++k) Z[k] = (u16*)alloc((size_t)N*128*2);
  float* ebuf  = (float*)alloc((size_t)N*4);
  float* pstats= (float*)alloc((size_t)4*PB*256*4);
  float* out2  = (float*)alloc((size_t)4*32*256*4);
  float* Sb    = (float*)alloc(9*256*4);   // 0-3: temps, 4: SX, 5-8: SZ0-3
  int* offs4 = (int*)alloc((size_t)4*(N+1)*4);
  int* srcs4 = (int*)alloc((size_t)4*E*4);
  int* cnt4  = (int*)alloc((size_t)4*N*4);
  int* goff  = (int*)alloc((size_t)(G+1)*4);
  float* qstar = (float*)alloc((size_t)G*256*4);
  float* hbuf  = (float*)alloc((size_t)G*128*4);
  float* cbuf  = (float*)alloc((size_t)G*128*4);
  float* emax  = (float*)alloc((size_t)G*4);
  float* invden= (float*)alloc((size_t)G*4);
  const size_t WT_ELEMS = 1392640;
  u16* WTh = (u16*)alloc(WT_ELEMS*2);
  u16* WTl = (u16*)alloc(WT_ELEMS*2);

  const size_t oEnc0=0, oEnc1=16384, oEnc2=32768, oM0W1=49152, oM0W2=98304;
  const size_t oGW1=114688, oGW2=507904, oMW1=901120, oMW2=1294336;

  const float invN = 1.0f / (float)N;
  const int SX = 4, SZ0 = 5;
  auto Sl = [&](int i){ return Sb + (size_t)i*256; };

  auto prep = [&](const float* src, size_t o, int K, int count){
    int tot = count*K*128;
    split_transpose<<<(tot+255)/256,256,0,stream>>>(src, WTh+o, WTl+o, K, count);
  };
  prep(P(9),  oEnc0, 128, 1);
  prep(P(17), oEnc1, 128, 1);
  prep(P(25), oEnc2, 128, 1);
  prep(P(29), oM0W1, 384, 1);
  prep(P(33), oM0W2, 128, 1);
  prep(P(37), oGW1,  128, 24);
  prep(P(41), oGW2,  128, 24);
  prep(P(46), oMW1,  512, 6);
  prep(P(50), oMW2,  128, 6);

  // ---- CSR build (+ per-node value sort for deterministic sums) ----
  int zgrid = (4*N + 255)/256;
  zero_k<<<zgrid,256,0,stream>>>((float*)cnt4, 4*N);
  int egrid = (E + 255)/256;
  for (int l=0;l<4;++l)
    count_deg<<<egrid,256,0,stream>>>(ei[l]+E, cnt4 + (size_t)l*N, E);
  scan_excl<<<4,1024,0,stream>>>(cnt4, offs4, N);
  zero_k<<<zgrid,256,0,stream>>>((float*)cnt4, 4*N);
  for (int l=0;l<4;++l)
    fill_csr<<<egrid,256,0,stream>>>(ei[l], ei[l]+E, offs4 + (size_t)l*(N+1),
                                     cnt4 + (size_t)l*N, srcs4 + (size_t)l*E, E);
  int ngrid = (N + 255)/256;
  for (int l=0;l<4;++l)
    sort_csr<<<ngrid,256,0,stream>>>(offs4 + (size_t)l*(N+1), srcs4 + (size_t)l*E, N);
  graph_offsets<<<(G+1+255)/256,256,0,stream>>>(batch, goff, N, G);

  auto run_bn = [&](int nbank, int nb, const float* g, const float* be, float* Sbase){
    stats_reduce1<<<dim3(32,nbank),256,0,stream>>>(pstats, PB, out2, nb);
    bnfin2<<<nbank,256,0,stream>>>(out2, g, be, Sbase, invN);
  };
  // non-in-place single-part GEMM: column-split
  auto run_gemm_split = [&](const u16* A, const float* S, size_t wo, const float* b, u16* Cc){
    gemm_rs_split<<<dim3(ggrid,2),256,0,stream>>>(A,nullptr,nullptr,nullptr, S,nullptr,nullptr,nullptr,
                                                  WTh+wo, WTl+wo, b, Cc, pstats, N, 1);
  };
  // in-place single-part GEMM: full-width
  auto run_gemm_full = [&](const u16* A, const float* S, size_t wo, const float* b, u16* Cc){
    gemm_rs_full<<<ggrid,256,0,stream>>>(A,nullptr,nullptr,nullptr, S,nullptr,nullptr,nullptr,
                                         WTh+wo, WTl+wo, b, Cc, pstats, N, 1);
  };

  // ---- encoders (X doubles as the intermediate T) ----
  gemm_enc<<<ENC_GRID,256,0,stream>>>(P(0),3, nullptr,0, P(5), P(6), X, pstats, N);
  run_bn(1, ENC_GRID, P(7), P(8), Sl(0));
  run_gemm_split(X, Sl(0), oEnc0, P(10), Z[0]);          // X->Z0: not in-place
  run_bn(1, ggrid, P(11), P(12), Sl(SZ0+0));

  gemm_enc<<<ENC_GRID,256,0,stream>>>(P(1),13, P(2),13, P(13), P(14), X, pstats, N);
  run_bn(1, ENC_GRID, P(15), P(16), Sl(0));
  run_gemm_split(X, Sl(0), oEnc1, P(18), Z[1]);
  run_bn(1, ggrid, P(19), P(20), Sl(SZ0+1));

  gemm_enc<<<ENC_GRID,256,0,stream>>>(P(3),4, P(4),1, P(21), P(22), X, pstats, N);
  run_bn(1, ENC_GRID, P(23), P(24), Sl(0));
  run_gemm_split(X, Sl(0), oEnc2, P(26), Z[2]);
  run_bn(1, ggrid, P(27), P(28), Sl(SZ0+2));

  // m0 W1: Z0,Z1,Z2 -> X  (K=384, not in-place -> split)
  gemm_rs_split<<<dim3(ggrid,2),256,0,stream>>>(Z[0],Z[1],Z[2],nullptr,
                                                Sl(SZ0+0),Sl(SZ0+1),Sl(SZ0+2),nullptr,
                                                WTh+oM0W1, WTl+oM0W1, P(30), X, pstats, N, 3);
  run_bn(1, ggrid, P(31), P(32), Sl(0));
  run_gemm_full(X, Sl(0), oM0W2, P(34), X);              // X->X in-place -> full
  run_bn(1, ggrid, P(35), P(36), Sl(SX));

  // ---- 6 GIN layers ----
  int agrid = (N + 3)/4;
  for (int L=0; L<6; ++L){
    aggregate4<<<dim3(agrid,4),256,0,stream>>>(X, Sl(SX), srcs4, offs4, E, N+1,
                                               geps, 4*L, Z[0],Z[1],Z[2],Z[3], N);
    gemm_gin<<<dim3(ggrid,4),256,0,stream>>>(Z[0],Z[1],Z[2],Z[3], nullptr,
                                             WTh+oGW1+(size_t)4*L*16384,
                                             WTl+oGW1+(size_t)4*L*16384,
                                             gb1 + (size_t)4*L*128, pstats, PB, N);
    run_bn(4, ggrid, gg1 + (size_t)4*L*128, gbe1 + (size_t)4*L*128, Sl(0));
    gemm_gin<<<dim3(ggrid,4),256,0,stream>>>(Z[0],Z[1],Z[2],Z[3], Sl(0),
                                             WTh+oGW2+(size_t)4*L*16384,
                                             WTl+oGW2+(size_t)4*L*16384,
                                             gb2 + (size_t)4*L*128, pstats, PB, N);
    run_bn(4, ggrid, gg2 + (size_t)4*L*128, gbe2 + (size_t)4*L*128, Sl(SZ0));
    // fusion W1: Z's -> X (X dead since aggregates; not in-place -> split)
    gemm_rs_split<<<dim3(ggrid,2),256,0,stream>>>(Z[0],Z[2],Z[1],Z[3],
                                                  Sl(SZ0+0),Sl(SZ0+2),Sl(SZ0+1),Sl(SZ0+3),
                                                  WTh+oMW1+(size_t)L*65536, WTl+oMW1+(size_t)L*65536,
                                                  mb1 + (size_t)L*128, X, pstats, N, 4);
    run_bn(1, ggrid, mg1 + (size_t)L*128, mbe1 + (size_t)L*128, Sl(0));
    run_gemm_full(X, Sl(0), oMW2 + (size_t)L*16384, mb2 + (size_t)L*128, X); // in-place
    run_bn(1, ggrid, mg2 + (size_t)L*128, mbe2 + (size_t)L*128, Sl(SX));
  }

  // ---- Set2Set (6 steps) ----
  zero_k<<<(G*256+255)/256,256,0,stream>>>(qstar, G*256);
  zero_k<<<(G*128+255)/256,256,0,stream>>>(hbuf, G*128);
  zero_k<<<(G*128+255)/256,256,0,stream>>>(cbuf, G*128);
  int dgrid = (N + 3)/4;
  for (int s=0;s<6;++s){
    lstm_step<<<64,256,0,stream>>>(qstar, hbuf, cbuf, P(54), P(55), P(56), P(57), G);
    dot_h_hf<<<dgrid,256,0,stream>>>(X, Sl(SX), hbuf, batch, ebuf, N);
    seg_reduce<<<G,256,0,stream>>>(ebuf, goff, emax, invden, G);
    r_kernel_hf<<<G,128,0,stream>>>(X, Sl(SX), ebuf, goff, emax, invden, qstar, G);
  }

  final_k<<<G,128,0,stream>>>(qstar, P(58), P(59), P(60), P(61), (float*)d_out, G);
}

// Round 15
// 6952.966 us; speedup vs baseline: 2.8802x; 1.1249x over previous
//
#include <hip/hip_runtime.h>
#include <math.h>

// ---------------------------------------------------------------------------
// NetGIN forward on MI355X — round 15.
// vs R14 (certified absmax 0.00390625, 7.82 ms):
//  * Buffer ping-pong: m0-W2 and fusion-W2 write a DEAD buffer and the host
//    rotates pointers -> no in-place gemms remain -> ALL gemm_rs calls use
//    the column-split kernel (2x grid). Bitwise-identical values; only the
//    ws addresses rotate (all consumers use rotated pointers).
//  * CSR build/sort fused across the 4 edge lists via blockIdx.y.
//  * lstm_step: one block per graph (grid G), per-graph math untouched.
// gemm_gin stays full-width in-place (row-owned; its 3128-block grid is OK;
// row-splitting would change the certified stats tree -> forbidden).
// ---------------------------------------------------------------------------

#define DEV_INLINE __device__ __forceinline__
typedef unsigned short u16;

union F16U { _Float16 h; u16 u; };
DEV_INLINE float h2f(u16 v){ F16U t; t.u = v; return (float)t.h; }
DEV_INLINE u16 f2h(float f){ F16U t; t.h = (_Float16)f; return t.u; }
DEV_INLINE float bf2f(u16 h){ return __uint_as_float(((unsigned)h)<<16); }
DEV_INLINE u16 f2bf(float f){
  unsigned u = __float_as_uint(f);
  unsigned r = (u + 0x7FFFu + ((u>>16)&1u)) >> 16;
  return (u16)r;
}
DEV_INLINE float sigmoidf_(float x){ return 1.0f/(1.0f+expf(-x)); }
struct __align__(4) us2 { u16 x, y; };
struct __align__(8) us4 { u16 x, y, z, w; };

typedef __attribute__((ext_vector_type(8))) short s8v;   // 8 bf16/fp16
typedef __attribute__((ext_vector_type(4))) float f4v;   // 4 fp32 acc

DEV_INLINE void bnsplit1(float f, u16& hb, u16& lb){
  hb = f2bf(f); lb = f2bf(f - bf2f(hb));
}

// ---------------- utility ----------------
__global__ void zero_k(float* __restrict__ p, int n){
  int i = blockIdx.x*256 + threadIdx.x;
  if (i < n) p[i] = 0.f;
}

// ---------------- weight pre-transpose + bf16 split ----------------
__global__ __launch_bounds__(256) void split_transpose(
  const float* __restrict__ src, u16* __restrict__ dh, u16* __restrict__ dl,
  int K, int count)
{
  int tot = count*K*128;
  for (int i = blockIdx.x*256 + threadIdx.x; i < tot; i += gridDim.x*256){
    int k = i % K;
    int n = (i / K) & 127;
    int c = i / (K*128);
    float w = src[(size_t)c*K*128 + (size_t)k*128 + n];
    u16 hi = f2bf(w);
    u16 lo = f2bf(w - bf2f(hi));
    dh[i] = hi; dl[i] = lo;
  }
}

// ---------------- CSR build (fused across 4 edge lists) ----------------
__global__ void count_deg4(const int* __restrict__ e0, const int* __restrict__ e1,
                           const int* __restrict__ e2, const int* __restrict__ e3,
                           int* __restrict__ cnt, int E, int N){
  int l = blockIdx.y;
  const int* dst = ((l==0)?e0:(l==1)?e1:(l==2)?e2:e3) + E;
  int e = blockIdx.x*256 + threadIdx.x;
  if (e < E) atomicAdd(&cnt[(size_t)l*N + dst[e]], 1);
}

__global__ void scan_excl(const int* __restrict__ cnt, int* __restrict__ offs, int N){
  const int* c = cnt + (size_t)blockIdx.x * N;
  int* o = offs + (size_t)blockIdx.x * (N+1);
  __shared__ int ps[1024];
  int t = threadIdx.x;
  int chunk = (N + 1023) >> 10;
  int lo = t*chunk, hi = min(lo+chunk, N);
  int s = 0;
  for (int i=lo;i<hi;++i) s += c[i];
  ps[t] = s; __syncthreads();
  for (int d=1; d<1024; d<<=1){
    int v = (t>=d) ? ps[t-d] : 0;
    __syncthreads();
    ps[t] += v;
    __syncthreads();
  }
  int pre = (t==0) ? 0 : ps[t-1];
  for (int i=lo;i<hi;++i){ o[i]=pre; pre += c[i]; }
  if (t==1023) o[N] = ps[1023];
}

__global__ void fill_csr4(const int* __restrict__ e0, const int* __restrict__ e1,
                          const int* __restrict__ e2, const int* __restrict__ e3,
                          const int* __restrict__ offs4, int* __restrict__ cur,
                          int* __restrict__ out, int E, int N){
  int l = blockIdx.y;
  const int* ei = (l==0)?e0:(l==1)?e1:(l==2)?e2:e3;
  const int* src = ei;
  const int* dst = ei + E;
  int e = blockIdx.x*256 + threadIdx.x;
  if (e >= E) return;
  int d = dst[e];
  int pos = offs4[(size_t)l*(N+1) + d] + atomicAdd(&cur[(size_t)l*N + d], 1);
  out[(size_t)l*E + pos] = src[e];
}

__global__ void sort_csr4(const int* __restrict__ offs4, int* __restrict__ srcs,
                          int E, int N){
  int l = blockIdx.y;
  int i = blockIdx.x*256 + threadIdx.x;
  if (i >= N) return;
  const int* offs = offs4 + (size_t)l*(N+1);
  int* s = srcs + (size_t)l*E;
  int lo = offs[i], hi = offs[i+1];
  for (int a = lo+1; a < hi; ++a){
    int v = s[a];
    int b = a-1;
    while (b >= lo && s[b] > v){ s[b+1] = s[b]; --b; }
    s[b+1] = v;
  }
}

__global__ void graph_offsets(const int* __restrict__ batch, int* __restrict__ goff, int N, int G){
  int g = blockIdx.x*blockDim.x + threadIdx.x;
  if (g > G) return;
  int lo=0, hi=N;
  while (lo<hi){ int mid=(lo+hi)>>1; if (batch[mid] < g) lo=mid+1; else hi=mid; }
  goff[g]=lo;
}

// ---------------- two-stage deterministic BN stats ----------------
__global__ __launch_bounds__(256) void stats_reduce1(
  const float* __restrict__ pstats, int PB, float* __restrict__ out2, int nb)
{
  int c = threadIdx.x, grp = blockIdx.x, bank = blockIdx.y;
  int chunk = (nb + 31) >> 5;
  int b0 = grp*chunk, b1 = min(b0+chunk, nb);
  const float* base = pstats + (size_t)bank*PB*256;
  float s = 0.f;
  for (int b=b0; b<b1; ++b) s += base[(size_t)b*256 + c];
  out2[((size_t)bank*32 + grp)*256 + c] = s;
}
__global__ __launch_bounds__(256) void bnfin2(
  const float* __restrict__ out2, const float* __restrict__ g,
  const float* __restrict__ be, float* __restrict__ Sb, float invN)
{
  __shared__ float tot[256];
  int t = threadIdx.x, bank = blockIdx.x;
  const float* src = out2 + (size_t)bank*32*256;
  float s = 0.f;
  #pragma unroll
  for (int j=0;j<32;++j) s += src[j*256 + t];   // fixed order
  tot[t] = s; __syncthreads();
  if (t < 128){
    float m = tot[t]*invN;
    float v = tot[128+t]*invN - m*m;
    float sc = g[bank*128 + t]*rsqrtf(v + 1e-5f);
    Sb[bank*256 + t] = sc;
    Sb[bank*256 + 128 + t] = be[bank*128 + t] - m*sc;
  }
}

// ======== FULL-WIDTH GEMM macros (for gemm_gin, in-place safe) ========
#define GEMM_KS_BODY_F(A_, S_, WHp_, WLp_, Kel_)                              \
  {                                                                           \
    float4 sa0, sa1, sb0, sb1;                                                \
    if (S_){                                                                  \
      sa0 = *(const float4*)(S_ + koff);                                      \
      sa1 = *(const float4*)(S_ + koff + 4);                                  \
      sb0 = *(const float4*)(S_ + 128 + koff);                                \
      sb1 = *(const float4*)(S_ + 128 + koff + 4);                            \
    }                                                                         \
    s8v xh0, xl0, xh1, xl1;                                                   \
    _Pragma("unroll")                                                         \
    for (int mt=0; mt<2; ++mt){                                               \
      int row = wrow0 + mt*16 + m16;                                          \
      s8v xr = (row < N) ? *(const s8v*)(A_ + (size_t)row*128 + koff)         \
                         : (s8v){0,0,0,0,0,0,0,0};                            \
      float f0 = h2f((u16)xr[0]), f1 = h2f((u16)xr[1]);                       \
      float f2 = h2f((u16)xr[2]), f3 = h2f((u16)xr[3]);                       \
      float f4 = h2f((u16)xr[4]), f5 = h2f((u16)xr[5]);                       \
      float f6 = h2f((u16)xr[6]), f7 = h2f((u16)xr[7]);                       \
      if (S_){                                                                \
        f0 = fmaxf(fmaf(f0, sa0.x, sb0.x), 0.f);                              \
        f1 = fmaxf(fmaf(f1, sa0.y, sb0.y), 0.f);                              \
        f2 = fmaxf(fmaf(f2, sa0.z, sb0.z), 0.f);                              \
        f3 = fmaxf(fmaf(f3, sa0.w, sb0.w), 0.f);                              \
        f4 = fmaxf(fmaf(f4, sa1.x, sb1.x), 0.f);                              \
        f5 = fmaxf(fmaf(f5, sa1.y, sb1.y), 0.f);                              \
        f6 = fmaxf(fmaf(f6, sa1.z, sb1.z), 0.f);                              \
        f7 = fmaxf(fmaf(f7, sa1.w, sb1.w), 0.f);                              \
      }                                                                       \
      s8v h, l; u16 hb, lb;                                                   \
      bnsplit1(f0,hb,lb); h[0]=(short)hb; l[0]=(short)lb;                     \
      bnsplit1(f1,hb,lb); h[1]=(short)hb; l[1]=(short)lb;                     \
      bnsplit1(f2,hb,lb); h[2]=(short)hb; l[2]=(short)lb;                     \
      bnsplit1(f3,hb,lb); h[3]=(short)hb; l[3]=(short)lb;                     \
      bnsplit1(f4,hb,lb); h[4]=(short)hb; l[4]=(short)lb;                     \
      bnsplit1(f5,hb,lb); h[5]=(short)hb; l[5]=(short)lb;                     \
      bnsplit1(f6,hb,lb); h[6]=(short)hb; l[6]=(short)lb;                     \
      bnsplit1(f7,hb,lb); h[7]=(short)hb; l[7]=(short)lb;                     \
      if (mt==0){ xh0=h; xl0=l; } else { xh1=h; xl1=l; }                      \
    }                                                                         \
    _Pragma("unroll")                                                         \
    for (int nh=0; nh<2; ++nh){                                               \
      _Pragma("unroll")                                                       \
      for (int n4=0;n4<4;++n4){                                               \
        int n = (nh*4+n4)*16 + m16;                                           \
        size_t wa = (size_t)n*Kel_ + koff;                                    \
        s8v wh = *(const s8v*)(WHp_ + wa);                                    \
        s8v wl = *(const s8v*)(WLp_ + wa);                                    \
        acc[0][nh*4+n4] = __builtin_amdgcn_mfma_f32_16x16x32_bf16(wh, xh0, acc[0][nh*4+n4], 0,0,0); \
        acc[0][nh*4+n4] = __builtin_amdgcn_mfma_f32_16x16x32_bf16(wl, xh0, acc[0][nh*4+n4], 0,0,0); \
        acc[0][nh*4+n4] = __builtin_amdgcn_mfma_f32_16x16x32_bf16(wh, xl0, acc[0][nh*4+n4], 0,0,0); \
        acc[1][nh*4+n4] = __builtin_amdgcn_mfma_f32_16x16x32_bf16(wh, xh1, acc[1][nh*4+n4], 0,0,0); \
        acc[1][nh*4+n4] = __builtin_amdgcn_mfma_f32_16x16x32_bf16(wl, xh1, acc[1][nh*4+n4], 0,0,0); \
        acc[1][nh*4+n4] = __builtin_amdgcn_mfma_f32_16x16x32_bf16(wh, xl1, acc[1][nh*4+n4], 0,0,0); \
      }                                                                       \
    }                                                                         \
  }

#define GEMM_EPILOGUE_F(C_, bias_, pslot_)                                    \
  {                                                                           \
    _Pragma("unroll")                                                         \
    for (int nt=0;nt<8;++nt){                                                 \
      int n0 = nt*16 + kg*4;                                                  \
      float4 b4 = *(const float4*)(bias_ + n0);                               \
      float s1a=0.f,s1b=0.f,s1c=0.f,s1d=0.f;                                  \
      float s2a=0.f,s2b=0.f,s2c=0.f,s2d=0.f;                                  \
      _Pragma("unroll")                                                       \
      for (int mt=0;mt<2;++mt){                                               \
        int row = wrow0 + mt*16 + m16;                                        \
        us4 o;                                                                \
        o.x = f2h(acc[mt][nt][0] + b4.x);                                     \
        o.y = f2h(acc[mt][nt][1] + b4.y);                                     \
        o.z = f2h(acc[mt][nt][2] + b4.z);                                     \
        o.w = f2h(acc[mt][nt][3] + b4.w);                                     \
        *(us4*)(&cst[wid][mt][m16*136 + n0]) = o;                             \
        if (row < N){                                                         \
          float r0=h2f(o.x), r1=h2f(o.y), r2=h2f(o.z), r3=h2f(o.w);           \
          s1a+=r0; s1b+=r1; s1c+=r2; s1d+=r3;                                 \
          s2a+=r0*r0; s2b+=r1*r1; s2c+=r2*r2; s2d+=r3*r3;                     \
        }                                                                     \
      }                                                                       \
      _Pragma("unroll")                                                       \
      for (int off=1; off<16; off<<=1){                                       \
        s1a += __shfl_xor(s1a, off, 64); s1b += __shfl_xor(s1b, off, 64);     \
        s1c += __shfl_xor(s1c, off, 64); s1d += __shfl_xor(s1d, off, 64);     \
        s2a += __shfl_xor(s2a, off, 64); s2b += __shfl_xor(s2b, off, 64);     \
        s2c += __shfl_xor(s2c, off, 64); s2d += __shfl_xor(s2d, off, 64);     \
      }                                                                       \
      if (m16 == 0){                                                          \
        pw[wid][n0+0] = s1a; pw[wid][n0+1] = s1b;                             \
        pw[wid][n0+2] = s1c; pw[wid][n0+3] = s1d;                             \
        pw[wid][128+n0+0] = s2a; pw[wid][128+n0+1] = s2b;                     \
        pw[wid][128+n0+2] = s2c; pw[wid][128+n0+3] = s2d;                     \
      }                                                                       \
    }                                                                         \
    __syncthreads();                                                          \
    if (t < 256){                                                             \
      float tot = ((pw[0][t] + pw[1][t]) + pw[2][t]) + pw[3][t];              \
      (pslot_)[t] = tot;                                                      \
    }                                                                         \
    _Pragma("unroll")                                                         \
    for (int mt=0;mt<2;++mt){                                                 \
      _Pragma("unroll")                                                       \
      for (int it=0; it<4; ++it){                                             \
        int idx = it*64 + lane;                                               \
        int r = idx >> 4;                                                     \
        int c8 = (idx & 15) * 8;                                              \
        int row = wrow0 + mt*16 + r;                                          \
        if (row < N){                                                         \
          s8v v = *(const s8v*)(&cst[wid][mt][r*136 + c8]);                   \
          *(s8v*)(C_ + (size_t)row*128 + c8) = v;                             \
        }                                                                     \
      }                                                                       \
    }                                                                         \
  }

// ======== COLUMN-SPLIT GEMM macros (non-in-place only) ========
#define GEMM_KS_BODY_S(A_, S_, WHp_, WLp_, Kel_)                              \
  {                                                                           \
    float4 sa0, sa1, sb0, sb1;                                                \
    if (S_){                                                                  \
      sa0 = *(const float4*)(S_ + koff);                                      \
      sa1 = *(const float4*)(S_ + koff + 4);                                  \
      sb0 = *(const float4*)(S_ + 128 + koff);                                \
      sb1 = *(const float4*)(S_ + 128 + koff + 4);                            \
    }                                                                         \
    s8v xh0, xl0, xh1, xl1;                                                   \
    _Pragma("unroll")                                                         \
    for (int mt=0; mt<2; ++mt){                                               \
      int row = wrow0 + mt*16 + m16;                                          \
      s8v xr = (row < N) ? *(const s8v*)(A_ + (size_t)row*128 + koff)         \
                         : (s8v){0,0,0,0,0,0,0,0};                            \
      float f0 = h2f((u16)xr[0]), f1 = h2f((u16)xr[1]);                       \
      float f2 = h2f((u16)xr[2]), f3 = h2f((u16)xr[3]);                       \
      float f4 = h2f((u16)xr[4]), f5 = h2f((u16)xr[5]);                       \
      float f6 = h2f((u16)xr[6]), f7 = h2f((u16)xr[7]);                       \
      if (S_){                                                                \
        f0 = fmaxf(fmaf(f0, sa0.x, sb0.x), 0.f);                              \
        f1 = fmaxf(fmaf(f1, sa0.y, sb0.y), 0.f);                              \
        f2 = fmaxf(fmaf(f2, sa0.z, sb0.z), 0.f);                              \
        f3 = fmaxf(fmaf(f3, sa0.w, sb0.w), 0.f);                              \
        f4 = fmaxf(fmaf(f4, sa1.x, sb1.x), 0.f);                              \
        f5 = fmaxf(fmaf(f5, sa1.y, sb1.y), 0.f);                              \
        f6 = fmaxf(fmaf(f6, sa1.z, sb1.z), 0.f);                              \
        f7 = fmaxf(fmaf(f7, sa1.w, sb1.w), 0.f);                              \
      }                                                                       \
      s8v h, l; u16 hb, lb;                                                   \
      bnsplit1(f0,hb,lb); h[0]=(short)hb; l[0]=(short)lb;                     \
      bnsplit1(f1,hb,lb); h[1]=(short)hb; l[1]=(short)lb;                     \
      bnsplit1(f2,hb,lb); h[2]=(short)hb; l[2]=(short)lb;                     \
      bnsplit1(f3,hb,lb); h[3]=(short)hb; l[3]=(short)lb;                     \
      bnsplit1(f4,hb,lb); h[4]=(short)hb; l[4]=(short)lb;                     \
      bnsplit1(f5,hb,lb); h[5]=(short)hb; l[5]=(short)lb;                     \
      bnsplit1(f6,hb,lb); h[6]=(short)hb; l[6]=(short)lb;                     \
      bnsplit1(f7,hb,lb); h[7]=(short)hb; l[7]=(short)lb;                     \
      if (mt==0){ xh0=h; xl0=l; } else { xh1=h; xl1=l; }                      \
    }                                                                         \
    _Pragma("unroll")                                                         \
    for (int nt=0; nt<4; ++nt){                                               \
      int n = colbase + nt*16 + m16;                                          \
      size_t wa = (size_t)n*Kel_ + koff;                                      \
      s8v wh = *(const s8v*)(WHp_ + wa);                                      \
      s8v wl = *(const s8v*)(WLp_ + wa);                                      \
      acc[0][nt] = __builtin_amdgcn_mfma_f32_16x16x32_bf16(wh, xh0, acc[0][nt], 0,0,0); \
      acc[0][nt] = __builtin_amdgcn_mfma_f32_16x16x32_bf16(wl, xh0, acc[0][nt], 0,0,0); \
      acc[0][nt] = __builtin_amdgcn_mfma_f32_16x16x32_bf16(wh, xl0, acc[0][nt], 0,0,0); \
      acc[1][nt] = __builtin_amdgcn_mfma_f32_16x16x32_bf16(wh, xh1, acc[1][nt], 0,0,0); \
      acc[1][nt] = __builtin_amdgcn_mfma_f32_16x16x32_bf16(wl, xh1, acc[1][nt], 0,0,0); \
      acc[1][nt] = __builtin_amdgcn_mfma_f32_16x16x32_bf16(wh, xl1, acc[1][nt], 0,0,0); \
    }                                                                         \
  }

#define GEMM_EPILOGUE_S(C_, bias_, pslot_)                                    \
  {                                                                           \
    _Pragma("unroll")                                                         \
    for (int nt=0;nt<4;++nt){                                                 \
      int lc0 = nt*16 + kg*4;                                                 \
      int n0 = colbase + lc0;                                                 \
      float4 b4 = *(const float4*)(bias_ + n0);                               \
      float s1a=0.f,s1b=0.f,s1c=0.f,s1d=0.f;                                  \
      float s2a=0.f,s2b=0.f,s2c=0.f,s2d=0.f;                                  \
      _Pragma("unroll")                                                       \
      for (int mt=0;mt<2;++mt){                                               \
        int row = wrow0 + mt*16 + m16;                                        \
        us4 o;                                                                \
        o.x = f2h(acc[mt][nt][0] + b4.x);                                     \
        o.y = f2h(acc[mt][nt][1] + b4.y);                                     \
        o.z = f2h(acc[mt][nt][2] + b4.z);                                     \
        o.w = f2h(acc[mt][nt][3] + b4.w);                                     \
        *(us4*)(&cst[wid][mt][m16*72 + lc0]) = o;                             \
        if (row < N){                                                         \
          float r0=h2f(o.x), r1=h2f(o.y), r2=h2f(o.z), r3=h2f(o.w);           \
          s1a+=r0; s1b+=r1; s1c+=r2; s1d+=r3;                                 \
          s2a+=r0*r0; s2b+=r1*r1; s2c+=r2*r2; s2d+=r3*r3;                     \
        }                                                                     \
      }                                                                       \
      _Pragma("unroll")                                                       \
      for (int off=1; off<16; off<<=1){                                       \
        s1a += __shfl_xor(s1a, off, 64); s1b += __shfl_xor(s1b, off, 64);     \
        s1c += __shfl_xor(s1c, off, 64); s1d += __shfl_xor(s1d, off, 64);     \
        s2a += __shfl_xor(s2a, off, 64); s2b += __shfl_xor(s2b, off, 64);     \
        s2c += __shfl_xor(s2c, off, 64); s2d += __shfl_xor(s2d, off, 64);     \
      }                                                                       \
      if (m16 == 0){                                                          \
        pw[wid][lc0+0] = s1a; pw[wid][lc0+1] = s1b;                           \
        pw[wid][lc0+2] = s1c; pw[wid][lc0+3] = s1d;                           \
        pw[wid][64+lc0+0] = s2a; pw[wid][64+lc0+1] = s2b;                     \
        pw[wid][64+lc0+2] = s2c; pw[wid][64+lc0+3] = s2d;                     \
      }                                                                       \
    }                                                                         \
    __syncthreads();                                                          \
    if (t < 128){                                                             \
      int lc = t & 63, part = t >> 6;                                         \
      int li = part*64 + lc;                                                  \
      float tot = ((pw[0][li] + pw[1][li]) + pw[2][li]) + pw[3][li];          \
      (pslot_)[part*128 + colbase + lc] = tot;                                \
    }                                                                         \
    _Pragma("unroll")                                                         \
    for (int mt=0;mt<2;++mt){                                                 \
      _Pragma("unroll")                                                       \
      for (int it=0; it<2; ++it){                                             \
        int idx = it*64 + lane;                                               \
        int r = idx >> 3;                                                     \
        int c8 = (idx & 7) * 8;                                               \
        int row = wrow0 + mt*16 + r;                                          \
        if (row < N){                                                         \
          s8v v = *(const s8v*)(&cst[wid][mt][r*72 + c8]);                    \
          *(s8v*)(C_ + (size_t)row*128 + colbase + c8) = v;                   \
        }                                                                     \
      }                                                                       \
    }                                                                         \
  }

// ---------------- column-split GEMM (all gemm_rs calls; non-in-place) ------
__global__ __launch_bounds__(256, 3) void gemm_rs_split(
  const u16* __restrict__ A0, const u16* __restrict__ A1,
  const u16* __restrict__ A2, const u16* __restrict__ A3,
  const float* __restrict__ S0, const float* __restrict__ S1,
  const float* __restrict__ S2, const float* __restrict__ S3,
  const u16* __restrict__ wt_hi, const u16* __restrict__ wt_lo,
  const float* __restrict__ bias,
  u16* __restrict__ C, float* __restrict__ pstats,
  int N, int npart)
{
  __shared__ u16 cst[4][2][16*72];
  __shared__ float pw[4][128];
  const int t = threadIdx.x;
  const int lane = t & 63;
  const int wid = t >> 6;
  const int m16 = lane & 15;
  const int kg = lane >> 4;
  const int wrow0 = blockIdx.x*128 + wid*32;
  const int colbase = blockIdx.y*64;
  const int K = npart << 7;

  f4v acc[2][4];
  #pragma unroll
  for (int i=0;i<2;++i)
    #pragma unroll
    for (int j=0;j<4;++j) acc[i][j] = (f4v){0.f,0.f,0.f,0.f};

  for (int part=0; part<npart; ++part){
    const u16* A = (part==0)?A0:(part==1)?A1:(part==2)?A2:A3;
    const float* S = (part==0)?S0:(part==1)?S1:(part==2)?S2:S3;
    const u16* WHp = wt_hi + part*128;
    const u16* WLp = wt_lo + part*128;
    #pragma unroll
    for (int ks=0; ks<4; ++ks){
      int koff = ks*32 + kg*8;
      GEMM_KS_BODY_S(A, S, WHp, WLp, K)
    }
  }
  GEMM_EPILOGUE_S(C, bias, (pstats + (size_t)blockIdx.x*256))
}

// ---------------- fused 4-conv GIN GEMM (full-width, in-place) -------------
__global__ __launch_bounds__(256, 3) void gemm_gin(
  u16* __restrict__ Z0, u16* __restrict__ Z1,
  u16* __restrict__ Z2, u16* __restrict__ Z3,
  const float* __restrict__ Sbase,          // null => raw; else + k*256
  const u16* __restrict__ wt_hi, const u16* __restrict__ wt_lo, // + k*16384
  const float* __restrict__ bias,           // + k*128
  float* __restrict__ pstats, int PB,       // bank k at + k*PB*256
  int N)
{
  __shared__ u16 cst[4][2][16*136];
  __shared__ float pw[4][256];
  const int t = threadIdx.x;
  const int lane = t & 63;
  const int wid = t >> 6;
  const int m16 = lane & 15;
  const int kg = lane >> 4;
  const int wrow0 = blockIdx.x*128 + wid*32;
  const int kb = blockIdx.y;

  u16* Zc = (kb==0)?Z0:(kb==1)?Z1:(kb==2)?Z2:Z3;
  const float* S = Sbase ? (Sbase + (size_t)kb*256) : nullptr;
  const u16* WHp = wt_hi + (size_t)kb*16384;
  const u16* WLp = wt_lo + (size_t)kb*16384;
  const float* biasp = bias + (size_t)kb*128;
  float* pslot = pstats + ((size_t)kb*PB + blockIdx.x)*256;

  f4v acc[2][8];
  #pragma unroll
  for (int i=0;i<2;++i)
    #pragma unroll
    for (int j=0;j<8;++j) acc[i][j] = (f4v){0.f,0.f,0.f,0.f};

  {
    const u16* A = Zc;
    #pragma unroll
    for (int ks=0; ks<4; ++ks){
      int koff = ks*32 + kg*8;
      GEMM_KS_BODY_F(A, S, WHp, WLp, 128)
    }
  }
  GEMM_EPILOGUE_F(Zc, biasp, pslot)
}

// ---------------- small-K encoder GEMM (fp32 inputs, K <= 26) ----------------
__global__ __launch_bounds__(256) void gemm_enc(
  const float* __restrict__ X0, int w0, const float* __restrict__ X1, int w1,
  const float* __restrict__ W, const float* __restrict__ bias,
  u16* __restrict__ C, float* __restrict__ pstats, int N)
{
  __shared__ float Ws[26*128];
  __shared__ float red[256];
  int K = w0 + w1;
  int t = threadIdx.x;
  for (int i=t;i<K*128;i+=256) Ws[i] = W[i];
  __syncthreads();
  int c = t & 127, rh = t >> 7;
  float b = bias[c];
  float s1=0.f, s2=0.f;
  for (int r0 = blockIdx.x*2; r0 < N; r0 += gridDim.x*2){
    int r = r0 + rh;
    if (r < N){
      float acc = b;
      for (int k=0;k<w0;++k) acc = fmaf(X0[(size_t)r*w0+k], Ws[k*128+c], acc);
      for (int k=0;k<w1;++k) acc = fmaf(X1[(size_t)r*w1+k], Ws[(w0+k)*128+c], acc);
      u16 o = f2h(acc);
      C[(size_t)r*128+c] = o;
      float rv = h2f(o);
      s1 += rv; s2 += rv*rv;
    }
  }
  red[t] = s1; __syncthreads();
  float t1 = (t < 128) ? (red[t] + red[t+128]) : 0.f;
  __syncthreads();
  red[t] = s2; __syncthreads();
  float t2 = (t < 128) ? (red[t] + red[t+128]) : 0.f;
  if (t < 128){
    pstats[(size_t)blockIdx.x*256 + t] = t1;
    pstats[(size_t)blockIdx.x*256 + 128 + t] = t2;
  }
}

// ---------------- fused GIN aggregation (blockIdx.y = conv; 8x gather) -----
__global__ __launch_bounds__(256) void aggregate4(
  const u16* __restrict__ X, const float* __restrict__ S,
  const int* __restrict__ srcs4, const int* __restrict__ offs4,
  int E, int Np1, const float* __restrict__ geps, int gi0,
  u16* __restrict__ Z0, u16* __restrict__ Z1,
  u16* __restrict__ Z2, u16* __restrict__ Z3, int N)
{
  int kb = blockIdx.y;
  const int* srcs = srcs4 + (size_t)kb*E;
  const int* offs = offs4 + (size_t)kb*Np1;
  u16* Z = (kb==0)?Z0:(kb==1)?Z1:(kb==2)?Z2:Z3;
  int i = blockIdx.x*4 + (threadIdx.x>>6);
  int ln = threadIdx.x & 63;
  int c = ln*2;
  if (i >= N) return;
  float sca = S[c], sha = S[128+c];
  float scb = S[c+1], shb = S[128+c+1];
  float eps1 = 1.0f + geps[gi0 + kb];
  us2 x0 = *(const us2*)(X + (size_t)i*128 + c);
  float acca = eps1 * fmaxf(fmaf(h2f(x0.x), sca, sha), 0.f);
  float accb = eps1 * fmaxf(fmaf(h2f(x0.y), scb, shb), 0.f);
  int e0 = offs[i], e1 = offs[i+1];
  int e = e0;
  for (; e+8 <= e1; e += 8){
    int s0 = srcs[e],   s1 = srcs[e+1], s2 = srcs[e+2], s3 = srcs[e+3];
    int s4 = srcs[e+4], s5 = srcs[e+5], s6 = srcs[e+6], s7 = srcs[e+7];
    us2 v0 = *(const us2*)(X + (size_t)s0*128 + c);
    us2 v1 = *(const us2*)(X + (size_t)s1*128 + c);
    us2 v2 = *(const us2*)(X + (size_t)s2*128 + c);
    us2 v3 = *(const us2*)(X + (size_t)s3*128 + c);
    us2 v4 = *(const us2*)(X + (size_t)s4*128 + c);
    us2 v5 = *(const us2*)(X + (size_t)s5*128 + c);
    us2 v6 = *(const us2*)(X + (size_t)s6*128 + c);
    us2 v7 = *(const us2*)(X + (size_t)s7*128 + c);
    acca += fmaxf(fmaf(h2f(v0.x), sca, sha), 0.f);
    accb += fmaxf(fmaf(h2f(v0.y), scb, shb), 0.f);
    acca += fmaxf(fmaf(h2f(v1.x), sca, sha), 0.f);
    accb += fmaxf(fmaf(h2f(v1.y), scb, shb), 0.f);
    acca += fmaxf(fmaf(h2f(v2.x), sca, sha), 0.f);
    accb += fmaxf(fmaf(h2f(v2.y), scb, shb), 0.f);
    acca += fmaxf(fmaf(h2f(v3.x), sca, sha), 0.f);
    accb += fmaxf(fmaf(h2f(v3.y), scb, shb), 0.f);
    acca += fmaxf(fmaf(h2f(v4.x), sca, sha), 0.f);
    accb += fmaxf(fmaf(h2f(v4.y), scb, shb), 0.f);
    acca += fmaxf(fmaf(h2f(v5.x), sca, sha), 0.f);
    accb += fmaxf(fmaf(h2f(v5.y), scb, shb), 0.f);
    acca += fmaxf(fmaf(h2f(v6.x), sca, sha), 0.f);
    accb += fmaxf(fmaf(h2f(v6.y), scb, shb), 0.f);
    acca += fmaxf(fmaf(h2f(v7.x), sca, sha), 0.f);
    accb += fmaxf(fmaf(h2f(v7.y), scb, shb), 0.f);
  }
  for (; e+4 <= e1; e += 4){
    int s0 = srcs[e], s1 = srcs[e+1], s2 = srcs[e+2], s3 = srcs[e+3];
    us2 v0 = *(const us2*)(X + (size_t)s0*128 + c);
    us2 v1 = *(const us2*)(X + (size_t)s1*128 + c);
    us2 v2 = *(const us2*)(X + (size_t)s2*128 + c);
    us2 v3 = *(const us2*)(X + (size_t)s3*128 + c);
    acca += fmaxf(fmaf(h2f(v0.x), sca, sha), 0.f);
    accb += fmaxf(fmaf(h2f(v0.y), scb, shb), 0.f);
    acca += fmaxf(fmaf(h2f(v1.x), sca, sha), 0.f);
    accb += fmaxf(fmaf(h2f(v1.y), scb, shb), 0.f);
    acca += fmaxf(fmaf(h2f(v2.x), sca, sha), 0.f);
    accb += fmaxf(fmaf(h2f(v2.y), scb, shb), 0.f);
    acca += fmaxf(fmaf(h2f(v3.x), sca, sha), 0.f);
    accb += fmaxf(fmaf(h2f(v3.y), scb, shb), 0.f);
  }
  for (; e < e1; ++e){
    int s = srcs[e];
    us2 xv = *(const us2*)(X + (size_t)s*128 + c);
    acca += fmaxf(fmaf(h2f(xv.x), sca, sha), 0.f);
    accb += fmaxf(fmaf(h2f(xv.y), scb, shb), 0.f);
  }
  us2 o; o.x = f2h(acca); o.y = f2h(accb);
  *(us2*)(Z + (size_t)i*128 + c) = o;
}

// ---------------- Set2Set ----------------
__global__ __launch_bounds__(256) void lstm_step(
  float* __restrict__ q_star, float* __restrict__ h, float* __restrict__ cst,
  const float* __restrict__ Wih, const float* __restrict__ Whh,
  const float* __restrict__ bih, const float* __restrict__ bhh, int G)
{
  __shared__ float q[256], hh[128], z[512];
  int t = threadIdx.x;
  for (int g = blockIdx.x; g < G; g += gridDim.x){
    q[t] = q_star[(size_t)g*256 + t];
    if (t < 128) hh[t] = h[(size_t)g*128 + t];
    __syncthreads();
    #pragma unroll
    for (int p=0;p<2;++p){
      int j = t + 256*p;
      float acc = bih[j] + bhh[j];
      const float* wi = Wih + (size_t)j*256;
      const float* wh = Whh + (size_t)j*128;
      for (int k=0;k<256;++k) acc = fmaf(q[k], wi[k], acc);
      for (int k=0;k<128;++k) acc = fmaf(hh[k], wh[k], acc);
      z[j] = acc;
    }
    __syncthreads();
    if (t < 128){
      float i_ = z[t], f_ = z[128+t], g_ = z[256+t], o_ = z[384+t];
      float cc = sigmoidf_(f_)*cst[(size_t)g*128+t] + sigmoidf_(i_)*tanhf(g_);
      float hn = sigmoidf_(o_)*tanhf(cc);
      cst[(size_t)g*128+t] = cc;
      h[(size_t)g*128+t]  = hn;
      q_star[(size_t)g*256+t] = hn;
    }
    __syncthreads();
  }
}

__global__ __launch_bounds__(256) void dot_h_hf(
  const u16* __restrict__ X, const float* __restrict__ S,
  const float* __restrict__ h, const int* __restrict__ batch,
  float* __restrict__ e, int N)
{
  int wv = threadIdx.x >> 6, ln = threadIdx.x & 63;
  int i = blockIdx.x*4 + wv;
  if (i >= N) return;
  int g = batch[i];
  int c = ln*2;
  us2 x2 = *(const us2*)(X + (size_t)i*128 + c);
  float2 h2 = *(const float2*)(h + (size_t)g*128 + c);
  float xa = fmaxf(fmaf(h2f(x2.x), S[c],   S[128+c]),   0.f);
  float xb = fmaxf(fmaf(h2f(x2.y), S[c+1], S[128+c+1]), 0.f);
  float p = xa*h2.x + xb*h2.y;
  #pragma unroll
  for (int off=32; off; off>>=1) p += __shfl_down(p, off, 64);
  if (ln==0) e[i] = p;
}

__global__ __launch_bounds__(256) void seg_reduce(
  const float* __restrict__ e, const int* __restrict__ goff,
  float* __restrict__ emax, float* __restrict__ invden, int G)
{
  int g = blockIdx.x;
  int lo = goff[g], hi = goff[g+1];
  int t = threadIdx.x;
  __shared__ float red[256];
  float m = -3.4e38f;
  for (int i=lo+t; i<hi; i+=256) m = fmaxf(m, e[i]);
  red[t] = m; __syncthreads();
  for (int d=128; d; d>>=1){ if (t<d) red[t] = fmaxf(red[t], red[t+d]); __syncthreads(); }
  m = red[0]; __syncthreads();
  float s = 0.f;
  for (int i=lo+t; i<hi; i+=256) s += expf(e[i]-m);
  red[t] = s; __syncthreads();
  for (int d=128; d; d>>=1){ if (t<d) red[t] += red[t+d]; __syncthreads(); }
  if (t==0){
    emax[g] = m;
    invden[g] = (hi>lo && red[0]>0.f) ? 1.f/red[0] : 0.f;
  }
}

__global__ __launch_bounds__(128) void r_kernel_hf(
  const u16* __restrict__ X, const float* __restrict__ S,
  const float* __restrict__ e, const int* __restrict__ goff,
  const float* __restrict__ emax, const float* __restrict__ invden,
  float* __restrict__ q_star, int G)
{
  int g = blockIdx.x, c = threadIdx.x;
  int lo = goff[g], hi = goff[g+1];
  float m = emax[g], inv = invden[g];
  float sc = S[c], sh = S[128+c];
  float r = 0.f;
  for (int i=lo; i<hi; ++i){
    float w = expf(e[i]-m);
    r = fmaf(w, fmaxf(fmaf(h2f(X[(size_t)i*128+c]), sc, sh), 0.f), r);
  }
  q_star[(size_t)g*256 + 128 + c] = r*inv;
}

__global__ __launch_bounds__(128) void final_k(
  const float* __restrict__ q_star, const float* __restrict__ fc1W,
  const float* __restrict__ fc1b, const float* __restrict__ fc4W,
  const float* __restrict__ fc4b, float* __restrict__ out, int G)
{
  __shared__ float q[256];
  __shared__ float h1[128];
  int g = blockIdx.x, t = threadIdx.x;
  q[t]     = q_star[(size_t)g*256 + t];
  q[128+t] = q_star[(size_t)g*256 + 128 + t];
  __syncthreads();
  float acc = fc1b[t];
  for (int k=0;k<256;++k) acc = fmaf(q[k], fc1W[(size_t)k*128+t], acc);
  h1[t] = fmaxf(acc, 0.f);
  __syncthreads();
  if (t < 12){
    float o = fc4b[t];
    for (int d=0; d<128; ++d) o = fmaf(h1[d], fc4W[(size_t)d*12+t], o);
    out[(size_t)g*12+t] = o;
  }
}

// ---------------------------------------------------------------------------
extern "C" void kernel_launch(void* const* d_in, const int* in_sizes, int n_in,
                              void* d_out, int out_size, void* d_ws, size_t ws_size,
                              hipStream_t stream)
{
  (void)n_in; (void)ws_size;
  const int N = in_sizes[0] / 3;
  const int E = in_sizes[62] / 2;
  const int G = out_size / 12;

  auto P = [&](int i){ return (const float*)d_in[i]; };
  const float* gb1 = P(38); const float* gg1 = P(39); const float* gbe1 = P(40);
  const float* gb2 = P(42); const float* gg2 = P(43); const float* gbe2 = P(44);
  const float* geps = P(45);
  const float* mb1 = P(47); const float* mg1 = P(48); const float* mbe1 = P(49);
  const float* mb2 = P(51); const float* mg2 = P(52); const float* mbe2 = P(53);
  const int* ei[4] = {(const int*)d_in[62], (const int*)d_in[63],
                      (const int*)d_in[64], (const int*)d_in[65]};
  const int* batch = (const int*)d_in[66];

  const int ggrid = (N + 127)/128;
  const int ENC_GRID = 1024;
  const int PB = (ggrid > ENC_GRID) ? ggrid : ENC_GRID;

  char* ws = (char*)d_ws;
  size_t off = 0;
  auto alloc = [&](size_t bytes)->char*{
    char* p = ws + off;
    off = (off + bytes + 255) & ~(size_t)255;
    return p;
  };
  // 5 activation buffers; xp / zp[] rotate over them (host-side, fixed
  // schedule -> deterministic).
  u16* B[5]; for (int k=0;k<5;++k) B[k] = (u16*)alloc((size_t)N*128*2);
  float* ebuf  = (float*)alloc((size_t)N*4);
  float* pstats= (float*)alloc((size_t)4*PB*256*4);
  float* out2  = (float*)alloc((size_t)4*32*256*4);
  float* Sb    = (float*)alloc(9*256*4);   // 0-3: temps, 4: SX, 5-8: SZ0-3
  int* offs4 = (int*)alloc((size_t)4*(N+1)*4);
  int* srcs4 = (int*)alloc((size_t)4*E*4);
  int* cnt4  = (int*)alloc((size_t)4*N*4);
  int* goff  = (int*)alloc((size_t)(G+1)*4);
  float* qstar = (float*)alloc((size_t)G*256*4);
  float* hbuf  = (float*)alloc((size_t)G*128*4);
  float* cbuf  = (float*)alloc((size_t)G*128*4);
  float* emax  = (float*)alloc((size_t)G*4);
  float* invden= (float*)alloc((size_t)G*4);
  const size_t WT_ELEMS = 1392640;
  u16* WTh = (u16*)alloc(WT_ELEMS*2);
  u16* WTl = (u16*)alloc(WT_ELEMS*2);

  const size_t oEnc0=0, oEnc1=16384, oEnc2=32768, oM0W1=49152, oM0W2=98304;
  const size_t oGW1=114688, oGW2=507904, oMW1=901120, oMW2=1294336;

  const float invN = 1.0f / (float)N;
  const int SX = 4, SZ0 = 5;
  auto Sl = [&](int i){ return Sb + (size_t)i*256; };

  u16* xp = B[0];
  u16* zp[4] = {B[1], B[2], B[3], B[4]};

  auto prep = [&](const float* src, size_t o, int K, int count){
    int tot = count*K*128;
    split_transpose<<<(tot+255)/256,256,0,stream>>>(src, WTh+o, WTl+o, K, count);
  };
  prep(P(9),  oEnc0, 128, 1);
  prep(P(17), oEnc1, 128, 1);
  prep(P(25), oEnc2, 128, 1);
  prep(P(29), oM0W1, 384, 1);
  prep(P(33), oM0W2, 128, 1);
  prep(P(37), oGW1,  128, 24);
  prep(P(41), oGW2,  128, 24);
  prep(P(46), oMW1,  512, 6);
  prep(P(50), oMW2,  128, 6);

  // ---- CSR build (fused across 4 lists; per-node sort for determinism) ----
  int zgrid = (4*N + 255)/256;
  zero_k<<<zgrid,256,0,stream>>>((float*)cnt4, 4*N);
  int egrid = (E + 255)/256;
  count_deg4<<<dim3(egrid,4),256,0,stream>>>(ei[0],ei[1],ei[2],ei[3], cnt4, E, N);
  scan_excl<<<4,1024,0,stream>>>(cnt4, offs4, N);
  zero_k<<<zgrid,256,0,stream>>>((float*)cnt4, 4*N);
  fill_csr4<<<dim3(egrid,4),256,0,stream>>>(ei[0],ei[1],ei[2],ei[3], offs4, cnt4, srcs4, E, N);
  int ngrid = (N + 255)/256;
  sort_csr4<<<dim3(ngrid,4),256,0,stream>>>(offs4, srcs4, E, N);
  graph_offsets<<<(G+1+255)/256,256,0,stream>>>(batch, goff, N, G);

  auto run_bn = [&](int nbank, int nb, const float* g, const float* be, float* Sbase){
    stats_reduce1<<<dim3(32,nbank),256,0,stream>>>(pstats, PB, out2, nb);
    bnfin2<<<nbank,256,0,stream>>>(out2, g, be, Sbase, invN);
  };
  auto run_gemm = [&](const u16* A, const float* S, size_t wo, const float* b, u16* Cc){
    gemm_rs_split<<<dim3(ggrid,2),256,0,stream>>>(A,nullptr,nullptr,nullptr, S,nullptr,nullptr,nullptr,
                                                  WTh+wo, WTl+wo, b, Cc, pstats, N, 1);
  };

  // ---- encoders (xp doubles as the intermediate T) ----
  gemm_enc<<<ENC_GRID,256,0,stream>>>(P(0),3, nullptr,0, P(5), P(6), xp, pstats, N);
  run_bn(1, ENC_GRID, P(7), P(8), Sl(0));
  run_gemm(xp, Sl(0), oEnc0, P(10), zp[0]);
  run_bn(1, ggrid, P(11), P(12), Sl(SZ0+0));

  gemm_enc<<<ENC_GRID,256,0,stream>>>(P(1),13, P(2),13, P(13), P(14), xp, pstats, N);
  run_bn(1, ENC_GRID, P(15), P(16), Sl(0));
  run_gemm(xp, Sl(0), oEnc1, P(18), zp[1]);
  run_bn(1, ggrid, P(19), P(20), Sl(SZ0+1));

  gemm_enc<<<ENC_GRID,256,0,stream>>>(P(3),4, P(4),1, P(21), P(22), xp, pstats, N);
  run_bn(1, ENC_GRID, P(23), P(24), Sl(0));
  run_gemm(xp, Sl(0), oEnc2, P(26), zp[2]);
  run_bn(1, ggrid, P(27), P(28), Sl(SZ0+2));

  // m0 W1: zp0,zp1,zp2 -> xp (xp dead; split)
  gemm_rs_split<<<dim3(ggrid,2),256,0,stream>>>(zp[0],zp[1],zp[2],nullptr,
                                                Sl(SZ0+0),Sl(SZ0+1),Sl(SZ0+2),nullptr,
                                                WTh+oM0W1, WTl+oM0W1, P(30), xp, pstats, N, 3);
  run_bn(1, ggrid, P(31), P(32), Sl(0));
  // m0 W2: xp -> zp[3] (B4, never written -> dead); rotate xp <-> zp[3]
  run_gemm(xp, Sl(0), oM0W2, P(34), zp[3]);
  { u16* tmp = zp[3]; zp[3] = xp; xp = tmp; }
  run_bn(1, ggrid, P(35), P(36), Sl(SX));

  // ---- 6 GIN layers ----
  int agrid = (N + 3)/4;
  for (int L=0; L<6; ++L){
    aggregate4<<<dim3(agrid,4),256,0,stream>>>(xp, Sl(SX), srcs4, offs4, E, N+1,
                                               geps, 4*L, zp[0],zp[1],zp[2],zp[3], N);
    gemm_gin<<<dim3(ggrid,4),256,0,stream>>>(zp[0],zp[1],zp[2],zp[3], nullptr,
                                             WTh+oGW1+(size_t)4*L*16384,
                                             WTl+oGW1+(size_t)4*L*16384,
                                             gb1 + (size_t)4*L*128, pstats, PB, N);
    run_bn(4, ggrid, gg1 + (size_t)4*L*128, gbe1 + (size_t)4*L*128, Sl(0));
    gemm_gin<<<dim3(ggrid,4),256,0,stream>>>(zp[0],zp[1],zp[2],zp[3], Sl(0),
                                             WTh+oGW2+(size_t)4*L*16384,
                                             WTl+oGW2+(size_t)4*L*16384,
                                             gb2 + (size_t)4*L*128, pstats, PB, N);
    run_bn(4, ggrid, gg2 + (size_t)4*L*128, gbe2 + (size_t)4*L*128, Sl(SZ0));
    // fusion W1: concat [x1,x3,x2,x4] = zp0, zp2, zp1, zp3 -> xp (dead; split)
    gemm_rs_split<<<dim3(ggrid,2),256,0,stream>>>(zp[0],zp[2],zp[1],zp[3],
                                                  Sl(SZ0+0),Sl(SZ0+2),Sl(SZ0+1),Sl(SZ0+3),
                                                  WTh+oMW1+(size_t)L*65536, WTl+oMW1+(size_t)L*65536,
                                                  mb1 + (size_t)L*128, xp, pstats, N, 4);
    run_bn(1, ggrid, mg1 + (size_t)L*128, mbe1 + (size_t)L*128, Sl(0));
    // fusion W2: xp -> zp[0] (dead after fusion W1); rotate xp <-> zp[0]
    run_gemm(xp, Sl(0), oMW2 + (size_t)L*16384, mb2 + (size_t)L*128, zp[0]);
    { u16* tmp = zp[0]; zp[0] = xp; xp = tmp; }
    run_bn(1, ggrid, mg2 + (size_t)L*128, mbe2 + (size_t)L*128, Sl(SX));
  }

  // ---- Set2Set (6 steps) ----
  zero_k<<<(G*256+255)/256,256,0,stream>>>(qstar, G*256);
  zero_k<<<(G*128+255)/256,256,0,stream>>>(hbuf, G*128);
  zero_k<<<(G*128+255)/256,256,0,stream>>>(cbuf, G*128);
  int dgrid = (N + 3)/4;
  for (int s=0;s<6;++s){
    lstm_step<<<G,256,0,stream>>>(qstar, hbuf, cbuf, P(54), P(55), P(56), P(57), G);
    dot_h_hf<<<dgrid,256,0,stream>>>(xp, Sl(SX), hbuf, batch, ebuf, N);
    seg_reduce<<<G,256,0,stream>>>(ebuf, goff, emax, invden, G);
    r_kernel_hf<<<G,128,0,stream>>>(xp, Sl(SX), ebuf, goff, emax, invden, qstar, G);
  }

  final_k<<<G,128,0,stream>>>(qstar, P(58), P(59), P(60), P(61), (float*)d_out, G);
}